// Round 17
// baseline (205.079 us; speedup 1.0000x reference)
//
#include <hip/hip_runtime.h>
#include <math.h>

// MambaLiteUNet — round 16: bf16 U and XM2 intermediates (consumers already
// round at staging; scan's u-perturbation is linear). ~20MB traffic saved.

namespace {
constexpr int NB_ = 4, DM_ = 64, DIN_ = 128, DS_ = 16, DTR_ = 4;
constexpr int C_ = 256, N_ = 1024, B_ = 4, HD_ = 32;
constexpr int NCH = 16, LCH = 64;          // scan: 16 time-chunks of 64
constexpr int NSTATE = 16 * 128 * 16;      // nbb * DIN * DS = 32768
}

typedef __attribute__((ext_vector_type(8))) short bf16x8;
typedef __attribute__((ext_vector_type(4))) float f32x4;
typedef __attribute__((ext_vector_type(8))) unsigned short ushort8v;
typedef __attribute__((ext_vector_type(4))) unsigned short ushort4v;

// ---------- helpers ----------
__device__ __forceinline__ unsigned short f2b(float f) {  // fp32 -> bf16 RNE
  unsigned int u = __float_as_uint(f);
  unsigned int r = u + 0x7FFFu + ((u >> 16) & 1u);
  return (unsigned short)(r >> 16);
}
__device__ __forceinline__ float b2f(unsigned short u) {
  return __uint_as_float(((unsigned int)u) << 16);
}

__device__ __forceinline__ float2 blockReduce2(float a, float b, float* red) {
#pragma unroll
  for (int m = 1; m < 64; m <<= 1) {
    a += __shfl_xor(a, m, 64);
    b += __shfl_xor(b, m, 64);
  }
  int w = threadIdx.x >> 6;
  if ((threadIdx.x & 63) == 0) { red[2 * w] = a; red[2 * w + 1] = b; }
  __syncthreads();
  float ra = red[0] + red[2] + red[4] + red[6];
  float rb = red[1] + red[3] + red[5] + red[7];
  return make_float2(ra, rb);
}

__device__ __forceinline__ float siluf(float x) { return x / (1.f + expf(-x)); }
__device__ __forceinline__ float sigmf(float x) { return 1.f / (1.f + expf(-x)); }
__device__ __forceinline__ float softplusf(float x) {
  return fmaxf(x, 0.f) + log1pf(expf(-fabsf(x)));
}

// ---------- K1: LN over C of (B,C,N) -> (B,N,C), coalesced LDS-tile ----------
__global__ __launch_bounds__(256) void k_ln_t2(const float* __restrict__ in,
                                               const float* __restrict__ w,
                                               const float* __restrict__ bias,
                                               float* __restrict__ out_ln) {
  __shared__ float tile[256][17];
  __shared__ float redp[16][16][2];
  __shared__ float stats[16][2];
  int bx = blockIdx.x;
  int b = bx >> 6, n0 = (bx & 63) * 16;
  int c = threadIdx.x;
  {
    const float* p = in + ((long)(b * C_ + c)) * N_ + n0;
#pragma unroll
    for (int j = 0; j < 16; ++j) tile[c][j] = p[j];
  }
  __syncthreads();
  {
    int n = c & 15, g = c >> 4;
    float a = 0.f, q = 0.f;
#pragma unroll
    for (int i = 0; i < 16; ++i) {
      float v = tile[g * 16 + i][n];
      a += v; q += v * v;
    }
    redp[g][n][0] = a; redp[g][n][1] = q;
  }
  __syncthreads();
  if (c < 16) {
    float a = 0.f, q = 0.f;
#pragma unroll
    for (int g2 = 0; g2 < 16; ++g2) { a += redp[g2][c][0]; q += redp[g2][c][1]; }
    float mu = a * (1.f / C_);
    float rs = rsqrtf(q * (1.f / C_) - mu * mu + 1e-5f);
    stats[c][0] = mu; stats[c][1] = rs;
  }
  __syncthreads();
  float wv = w[c], bv = bias[c];
#pragma unroll
  for (int j = 0; j < 16; ++j) {
    float v = tile[c][j];
    long o = ((long)(b * N_ + n0 + j)) * C_ + c;
    out_ln[o] = (v - stats[j][0]) * stats[j][1] * wv + bv;
  }
}

// ---------- K2: mamba in-proj (MFMA) with fused causal conv + silu; U out bf16 ----------
__global__ __launch_bounds__(256) void k_inproj_conv(const float* __restrict__ xn,
                                                     const float* __restrict__ inw,
                                                     const float* __restrict__ cw,
                                                     const float* __restrict__ cb,
                                                     unsigned short* __restrict__ U,
                                                     float* __restrict__ Z) {
  __shared__ unsigned short xa[64][72];
  __shared__ unsigned short wb[64][72];
  __shared__ float ut[67][65];
  int r0 = blockIdx.x * 64;
  int nb = blockIdx.y >> 2, q = blockIdx.y & 3, c0 = q * 64;
  int t = threadIdx.x;
  int wv = t >> 6, lane = t & 63, g = lane >> 4, ql = lane & 15;
  const f32x4 zf = {0.f, 0.f, 0.f, 0.f};
  f32x4 acc[4] = {zf, zf, zf, zf};
  int rr = t >> 2, kq = (t & 3) * 16;
  {
    const float* xsrc = xn + (long)(r0 + rr) * C_ + nb * 64 + kq;
#pragma unroll
    for (int j = 0; j < 4; ++j) {
      float4 v = *(const float4*)(xsrc + 4 * j);
      ushort4v u = {f2b(v.x), f2b(v.y), f2b(v.z), f2b(v.w)};
      *(ushort4v*)&xa[rr][kq + 4 * j] = u;
    }
    const float* wsrc = inw + ((long)nb * 256 + c0 + rr) * 64 + kq;
#pragma unroll
    for (int j = 0; j < 4; ++j) {
      float4 v = *(const float4*)(wsrc + 4 * j);
      ushort4v u = {f2b(v.x), f2b(v.y), f2b(v.z), f2b(v.w)};
      *(ushort4v*)&wb[rr][kq + 4 * j] = u;
    }
  }
  __syncthreads();
#pragma unroll
  for (int ks = 0; ks < 2; ++ks) {
    bf16x8 a = *(const bf16x8*)&xa[wv * 16 + ql][ks * 32 + g * 8];
#pragma unroll
    for (int ct = 0; ct < 4; ++ct) {
      bf16x8 b = *(const bf16x8*)&wb[ct * 16 + ql][ks * 32 + g * 8];
      acc[ct] = __builtin_amdgcn_mfma_f32_16x16x32_bf16(a, b, acc[ct], 0, 0, 0);
    }
  }
  if (q < 2) {
#pragma unroll
    for (int ct = 0; ct < 4; ++ct)
#pragma unroll
      for (int reg = 0; reg < 4; ++reg)
        ut[3 + wv * 16 + g * 4 + reg][ct * 16 + ql] = acc[ct][reg];
    if (t < 192) {
      int hr = t >> 6, lc = t & 63;
      float hv = 0.f;
      if ((r0 & 1023) != 0) {
        const float* xrow = xn + (long)(r0 - 3 + hr) * C_ + nb * 64;
        const float* wrow = inw + ((long)nb * 256 + c0 + lc) * 64;
#pragma unroll 8
        for (int k = 0; k < 64; ++k) hv += xrow[k] * wrow[k];
      }
      ut[hr][lc] = hv;
    }
    __syncthreads();
#pragma unroll
    for (int ct = 0; ct < 4; ++ct) {
      int lc = ct * 16 + ql;
      int d = c0 + lc;
      const float* cwp = cw + (nb * DIN_ + d) * 4;
      float w0 = cwp[0], w1 = cwp[1], w2 = cwp[2], w3 = cwp[3];
      float bv = cb[nb * DIN_ + d];
#pragma unroll
      for (int reg = 0; reg < 4; ++reg) {
        int lr = wv * 16 + g * 4 + reg;
        float a = bv + w3 * ut[3 + lr][lc] + w2 * ut[2 + lr][lc] +
                  w1 * ut[1 + lr][lc] + w0 * ut[lr][lc];
        long row = (long)nb * 4096 + r0 + lr;
        U[row * DIN_ + d] = f2b(siluf(a));
      }
    }
  } else {
#pragma unroll
    for (int ct = 0; ct < 4; ++ct) {
      int col = c0 - 128 + ct * 16 + ql;
#pragma unroll
      for (int reg = 0; reg < 4; ++reg) {
        long row = (long)nb * 4096 + r0 + wv * 16 + g * 4 + reg;
        Z[row * DIN_ + col] = acc[ct][reg];
      }
    }
  }
}

// ---------- K4: xdbc (MFMA, bf16 U in) + dt/Bm/Cm epilogue + fused scan phase A ----------
__global__ __launch_bounds__(256) void k_xdbc_scanA(const unsigned short* __restrict__ U,
                                                    const float* __restrict__ xpw,
                                                    const float* __restrict__ dtw,
                                                    const float* __restrict__ dtb,
                                                    const float* __restrict__ alog,
                                                    float* __restrict__ DT,
                                                    float* __restrict__ BMb,
                                                    float* __restrict__ CMb,
                                                    float* __restrict__ Aprod,
                                                    float* __restrict__ Hend) {
  __shared__ unsigned short xa[64][72];
  __shared__ unsigned short wb[48][72];
  __shared__ float xd_s[64][40];
  __shared__ float dtw_s[128][4];
  __shared__ float dtb_s[128];
  __shared__ float dt_s[64][132];
  __shared__ float u_s[64][132];
  __shared__ float bm_s[64][20];
  int t = threadIdx.x;
  long row0 = (long)blockIdx.x * 64;
  int nb = blockIdx.x >> 6;
  int nbb = blockIdx.x >> 4, chunk = blockIdx.x & 15;
  for (int i = t; i < 512; i += 256) dtw_s[i >> 2][i & 3] = dtw[nb * 512 + i];
  if (t < 128) dtb_s[t] = dtb[nb * DIN_ + t];
  int wv = t >> 6, lane = t & 63, g = lane >> 4, ql = lane & 15;
  const f32x4 zf = {0.f, 0.f, 0.f, 0.f};
  f32x4 acc[3] = {zf, zf, zf};
  int rr = t >> 2, kq = (t & 3) * 16;
  for (int k0 = 0; k0 < 128; k0 += 64) {
    __syncthreads();
    const unsigned short* xsrc = U + (row0 + rr) * DIN_ + k0 + kq;
#pragma unroll
    for (int j = 0; j < 2; ++j) {
      ushort8v u8 = *(const ushort8v*)(xsrc + 8 * j);
      *(ushort8v*)&xa[rr][kq + 8 * j] = u8;
#pragma unroll
      for (int e = 0; e < 8; ++e) u_s[rr][k0 + kq + 8 * j + e] = b2f(u8[e]);
    }
    if (rr < 48) {
      if (rr < 36) {
        const float* wsrc = xpw + (long)nb * 36 * 128 + rr * 128 + k0 + kq;
#pragma unroll
        for (int j = 0; j < 4; ++j) {
          float4 v = *(const float4*)(wsrc + 4 * j);
          ushort4v u = {f2b(v.x), f2b(v.y), f2b(v.z), f2b(v.w)};
          *(ushort4v*)&wb[rr][kq + 4 * j] = u;
        }
      } else {
        ushort4v z = {0, 0, 0, 0};
#pragma unroll
        for (int j = 0; j < 4; ++j) *(ushort4v*)&wb[rr][kq + 4 * j] = z;
      }
    }
    __syncthreads();
#pragma unroll
    for (int ks = 0; ks < 2; ++ks) {
      bf16x8 a = *(const bf16x8*)&xa[wv * 16 + ql][ks * 32 + g * 8];
#pragma unroll
      for (int ct = 0; ct < 3; ++ct) {
        bf16x8 b = *(const bf16x8*)&wb[ct * 16 + ql][ks * 32 + g * 8];
        acc[ct] = __builtin_amdgcn_mfma_f32_16x16x32_bf16(a, b, acc[ct], 0, 0, 0);
      }
    }
  }
#pragma unroll
  for (int ct = 0; ct < 3; ++ct) {
    int col = ct * 16 + ql;
    if (col < 36) {
#pragma unroll
      for (int reg = 0; reg < 4; ++reg)
        xd_s[wv * 16 + g * 4 + reg][col] = acc[ct][reg];
    }
  }
  __syncthreads();
  {
    int r = t >> 2, sq = (t & 3) * 4;
    float4 bm4 = make_float4(xd_s[r][4 + sq], xd_s[r][5 + sq],
                             xd_s[r][6 + sq], xd_s[r][7 + sq]);
    *(float4*)&BMb[(row0 + r) * DS_ + sq] = bm4;
    *(float4*)&bm_s[r][sq] = bm4;
    float4 cm4 = make_float4(xd_s[r][20 + sq], xd_s[r][21 + sq],
                             xd_s[r][22 + sq], xd_s[r][23 + sq]);
    *(float4*)&CMb[(row0 + r) * DS_ + sq] = cm4;
  }
  {
    int r = t >> 2, dg = t & 3;
    float x0 = xd_s[r][0], x1 = xd_s[r][1], x2 = xd_s[r][2], x3 = xd_s[r][3];
    float* dst = DT + (row0 + r) * DIN_ + dg * 32;
#pragma unroll
    for (int j = 0; j < 8; ++j) {
      float o[4];
#pragma unroll
      for (int e = 0; e < 4; ++e) {
        int d = dg * 32 + j * 4 + e;
        float a = dtb_s[d] + x0 * dtw_s[d][0] + x1 * dtw_s[d][1] +
                  x2 * dtw_s[d][2] + x3 * dtw_s[d][3];
        o[e] = softplusf(a);
      }
      float4 o4 = make_float4(o[0], o[1], o[2], o[3]);
      *(float4*)(dst + j * 4) = o4;
      *(float4*)&dt_s[r][dg * 32 + j * 4] = o4;
    }
  }
  __syncthreads();
  {
    int dl = t >> 2, sg = t & 3;
#pragma unroll
    for (int dh = 0; dh < 2; ++dh) {
      int d = dh * 64 + dl;
      float A[4];
#pragma unroll
      for (int i = 0; i < 4; ++i)
        A[i] = -expf(alog[(nb * DIN_ + d) * DS_ + sg * 4 + i]);
      float h[4] = {0.f, 0.f, 0.f, 0.f};
      float ap[4] = {1.f, 1.f, 1.f, 1.f};
      for (int tt = 0; tt < LCH; ++tt) {
        float dtv = dt_s[tt][d];
        float uv  = u_s[tt][d];
        float cc = dtv * uv;
        float4 bm4 = *(const float4*)&bm_s[tt][sg * 4];
        float bmv[4] = {bm4.x, bm4.y, bm4.z, bm4.w};
#pragma unroll
        for (int i = 0; i < 4; ++i) {
          float dA = __expf(dtv * A[i]);
          h[i] = dA * h[i] + cc * bmv[i];
          ap[i] *= dA;
        }
      }
      long st = (long)chunk * NSTATE + ((nbb << 7) + d) * 16 + sg * 4;
      *(float4*)&Aprod[st] = make_float4(ap[0], ap[1], ap[2], ap[3]);
      *(float4*)&Hend[st]  = make_float4(h[0], h[1], h[2], h[3]);
    }
  }
}

// ---------- K5c: scan phase C — inline carry composition, emit y over DT ----------
__global__ __launch_bounds__(256) void k_scanC(float* __restrict__ DT,
                                               const unsigned short* __restrict__ U,
                                               const float* __restrict__ BMb,
                                               const float* __restrict__ CMb,
                                               const float* __restrict__ alog,
                                               const float* __restrict__ Dp,
                                               const float* __restrict__ Aprod,
                                               const float* __restrict__ Hend) {
  __shared__ float dt_s[64][64];
  __shared__ float u_s[64][64];
  __shared__ float bm_s[64][16];
  __shared__ float cm_s[64][16];
  int bx = blockIdx.x;
  int chunk = bx >> 5, rem = bx & 31, nbb = rem >> 1, dh = rem & 1;
  int nb = nbb >> 2;
  int t = threadIdx.x;
  int dl = t >> 2, sg = t & 3;
  int d = dh * 64 + dl;
  long base = (long)nbb * N_ + chunk * LCH;
#pragma unroll
  for (int j = 0; j < 4; ++j) {
    int f = t + 256 * j;
    int tt = f >> 4, dq = (f & 15) * 4;
    long src = (base + tt) * DIN_ + dh * 64 + dq;
    *(float4*)&dt_s[tt][dq] = *(const float4*)&DT[src];
    ushort4v u4 = *(const ushort4v*)&U[src];
    u_s[tt][dq + 0] = b2f(u4[0]);
    u_s[tt][dq + 1] = b2f(u4[1]);
    u_s[tt][dq + 2] = b2f(u4[2]);
    u_s[tt][dq + 3] = b2f(u4[3]);
  }
  {
    int tt = t >> 2, sq = (t & 3) * 4;
    *(float4*)&bm_s[tt][sq] = *(const float4*)&BMb[(base + tt) * DS_ + sq];
    *(float4*)&cm_s[tt][sq] = *(const float4*)&CMb[(base + tt) * DS_ + sq];
  }
  float A[4];
#pragma unroll
  for (int i = 0; i < 4; ++i)
    A[i] = -expf(alog[(nb * DIN_ + d) * DS_ + sg * 4 + i]);
  float Dv = Dp[nb * DIN_ + d];
  float h[4] = {0.f, 0.f, 0.f, 0.f};
  {
    long state4 = ((nbb << 7) + d) * 16 + sg * 4;
    for (int c = 0; c < chunk; ++c) {
      float4 a4 = *(const float4*)&Aprod[(long)c * NSTATE + state4];
      float4 e4 = *(const float4*)&Hend[(long)c * NSTATE + state4];
      h[0] = e4.x + a4.x * h[0];
      h[1] = e4.y + a4.y * h[1];
      h[2] = e4.z + a4.z * h[2];
      h[3] = e4.w + a4.w * h[3];
    }
  }
  __syncthreads();
  for (int tt = 0; tt < LCH; ++tt) {
    float dtv = dt_s[tt][dl];
    float uv  = u_s[tt][dl];
    float cc = dtv * uv;
    float4 bm4 = *(const float4*)&bm_s[tt][sg * 4];
    float4 cm4 = *(const float4*)&cm_s[tt][sg * 4];
    float bmv[4] = {bm4.x, bm4.y, bm4.z, bm4.w};
    float cmv[4] = {cm4.x, cm4.y, cm4.z, cm4.w};
    float p = 0.f;
#pragma unroll
    for (int i = 0; i < 4; ++i) {
      float dA = __expf(dtv * A[i]);
      h[i] = dA * h[i] + cc * bmv[i];
      p += h[i] * cmv[i];
    }
    p += __shfl_xor(p, 1, 64);
    p += __shfl_xor(p, 2, 64);
    if (sg == 0) DT[(base + tt) * DIN_ + d] = p + Dv * uv;
  }
}

// ---------- K6: out-proj (MFMA): xm = (y*silu(z)) @ outw^T + skip*xn ----------
__global__ __launch_bounds__(256) void k_outproj_mfma(const float* __restrict__ Y,
                                                      const float* __restrict__ Zb,
                                                      const float* __restrict__ outw,
                                                      const float* __restrict__ xn,
                                                      const float* __restrict__ skip,
                                                      float* __restrict__ XMC) {
  __shared__ unsigned short xa[64][72];
  __shared__ unsigned short wb[64][72];
  int r0 = blockIdx.x * 64;
  int nb = blockIdx.y;
  int t = threadIdx.x;
  int wv = t >> 6, lane = t & 63, g = lane >> 4, ql = lane & 15;
  const f32x4 zf = {0.f, 0.f, 0.f, 0.f};
  f32x4 acc[4] = {zf, zf, zf, zf};
  int rr = t >> 2, kq = (t & 3) * 16;
  for (int k0 = 0; k0 < 128; k0 += 64) {
    __syncthreads();
    long row = (long)nb * 4096 + r0 + rr;
    const float* ysrc = Y + row * DIN_ + k0 + kq;
    const float* zsrc = Zb + row * DIN_ + k0 + kq;
#pragma unroll
    for (int j = 0; j < 4; ++j) {
      float4 yv = *(const float4*)(ysrc + 4 * j);
      float4 zv = *(const float4*)(zsrc + 4 * j);
      ushort4v u = {f2b(yv.x * siluf(zv.x)), f2b(yv.y * siluf(zv.y)),
                    f2b(yv.z * siluf(zv.z)), f2b(yv.w * siluf(zv.w))};
      *(ushort4v*)&xa[rr][kq + 4 * j] = u;
    }
    const float* wsrc = outw + ((long)nb * 64 + rr) * 128 + k0 + kq;
#pragma unroll
    for (int j = 0; j < 4; ++j) {
      float4 v = *(const float4*)(wsrc + 4 * j);
      ushort4v u = {f2b(v.x), f2b(v.y), f2b(v.z), f2b(v.w)};
      *(ushort4v*)&wb[rr][kq + 4 * j] = u;
    }
    __syncthreads();
#pragma unroll
    for (int ks = 0; ks < 2; ++ks) {
      bf16x8 a = *(const bf16x8*)&xa[wv * 16 + ql][ks * 32 + g * 8];
#pragma unroll
      for (int ct = 0; ct < 4; ++ct) {
        bf16x8 b = *(const bf16x8*)&wb[ct * 16 + ql][ks * 32 + g * 8];
        acc[ct] = __builtin_amdgcn_mfma_f32_16x16x32_bf16(a, b, acc[ct], 0, 0, 0);
      }
    }
  }
  float sk = skip[0];
#pragma unroll
  for (int ct = 0; ct < 4; ++ct) {
    int col = ct * 16 + ql;
#pragma unroll
    for (int reg = 0; reg < 4; ++reg) {
      int bn = r0 + wv * 16 + g * 4 + reg;
      long oc = (long)bn * C_ + nb * 64 + col;
      XMC[oc] = acc[ct][reg] + sk * xn[oc];
    }
  }
}

// ---------- K7: gate ----------
__global__ __launch_bounds__(256) void k_gate(const float* __restrict__ XMC,
                                              const float* __restrict__ qdw_w,
                                              const float* __restrict__ qdw_b,
                                              const float* __restrict__ qpw_w,
                                              const float* __restrict__ qpw_b,
                                              float* __restrict__ G) {
  int t = threadIdx.x;
  int gid = (blockIdx.x * 256 + t) >> 4;     // b*N + n
  int cq = t & 3, p = (t >> 2) & 3;
  int b = gid >> 10, n = gid & 1023;
  float a = 0.f;
#pragma unroll
  for (int k = 0; k < 3; ++k) {
    int nn = n + k - 1;
    if (nn < 0 || nn >= N_) continue;
    const float* xr = XMC + ((long)b * N_ + nn) * C_ + p * 64 + cq * 16;
    const float* wr = qdw_w + (p * 64 + cq * 16) * 3 + k;
    float xv[16];
    *(float4*)&xv[0]  = *(const float4*)(xr);
    *(float4*)&xv[4]  = *(const float4*)(xr + 4);
    *(float4*)&xv[8]  = *(const float4*)(xr + 8);
    *(float4*)&xv[12] = *(const float4*)(xr + 12);
#pragma unroll
    for (int i = 0; i < 16; ++i) a += xv[i] * wr[i * 3];
  }
  a += __shfl_xor(a, 1, 64);
  a += __shfl_xor(a, 2, 64);
  float q1 = a + qdw_b[p];
  int lane = t & 63;
  float q1g[4];
#pragma unroll
  for (int pp = 0; pp < 4; ++pp) q1g[pp] = __shfl(q1, (lane & ~12) | (pp << 2), 64);
  int o = p;
  float r = qpw_b[o];
#pragma unroll
  for (int pp = 0; pp < 4; ++pp) r += qpw_w[o * 4 + pp] * q1g[pp];
  if (cq == 0) G[((long)b * 4 + o) * N_ + n] = sigmf(r);
}

// ---------- K8: xg (B,C,N) = g * xm — LDS tile transpose ----------
__global__ __launch_bounds__(256) void k_xg(const float* __restrict__ XMC,
                                            const float* __restrict__ G,
                                            float* __restrict__ XG) {
  __shared__ float tile[64][65];
  int bx = blockIdx.x;
  int b = bx >> 6, ct = (bx >> 4) & 3, nt = bx & 15;
  int c0 = ct * 64, n0 = nt * 64;
  int t = threadIdx.x;
  {
    int cc = t & 63, nq = t >> 6;
#pragma unroll
    for (int j = 0; j < 16; ++j) {
      int nn = nq * 16 + j;
      tile[cc][nn] = XMC[((long)(b * N_ + n0 + nn)) * C_ + c0 + cc];
    }
  }
  __syncthreads();
  {
    int nl = t & 63, cq = t >> 6;
    float g = G[((long)(b * 4 + ct)) * N_ + n0 + nl];
#pragma unroll
    for (int j = 0; j < 16; ++j) {
      int cl = cq * 16 + j;
      XG[((long)(b * C_ + c0 + cl)) * N_ + n0 + nl] = g * tile[cl][nl];
    }
  }
}

// ---------- MFMA GEMM, channel-major, 3-tap dw conv fused; optional bf16 RM out ----------
template <int KD>
__global__ __launch_bounds__(256) void k_gemm_cm_dw(const float* __restrict__ inA,
                                                    const float* __restrict__ inB,
                                                    const float* __restrict__ dww,
                                                    const float* __restrict__ dwb,
                                                    const float* __restrict__ w,
                                                    const float* __restrict__ bias,
                                                    const float* __restrict__ residCM,
                                                    const float* __restrict__ residXCM,
                                                    float* __restrict__ outCM,
                                                    unsigned short* __restrict__ outRMb) {
  __shared__ unsigned short xa[64][72];  // [n][k]
  __shared__ unsigned short wb[64][72];  // [cout][k]
  int rb = blockIdx.x;
  int b = rb >> 4, n0 = (rb & 15) * 64;
  int c0 = blockIdx.y * 64;
  int t = threadIdx.x;
  int wv = t >> 6, lane = t & 63, g = lane >> 4, ql = lane & 15;
  const f32x4 zf = {0.f, 0.f, 0.f, 0.f};
  f32x4 acc[4] = {zf, zf, zf, zf};
  int rr = t >> 2, kq = (t & 3) * 16;
  for (int k0 = 0; k0 < KD; k0 += 64) {
    __syncthreads();
    {
      int k = k0 + rr;
      const float* src = (inB != nullptr && k >= 256)
                             ? inB + ((long)(b * 256 + k - 256)) * 1024
                             : inA + ((long)(b * 256 + k)) * 1024;
      float w0 = dww[k * 3], w1 = dww[k * 3 + 1], w2 = dww[k * 3 + 2], bv = dwb[k];
#pragma unroll
      for (int j = 0; j < 4; ++j) {
        int nb4 = n0 + kq + 4 * j;
        float4 v = *(const float4*)&src[nb4];
        float vm1 = (nb4 > 0) ? src[nb4 - 1] : 0.f;
        float vp4 = (nb4 + 4 < 1024) ? src[nb4 + 4] : 0.f;
        xa[kq + 4 * j + 0][rr] = f2b(bv + w0 * vm1 + w1 * v.x + w2 * v.y);
        xa[kq + 4 * j + 1][rr] = f2b(bv + w0 * v.x + w1 * v.y + w2 * v.z);
        xa[kq + 4 * j + 2][rr] = f2b(bv + w0 * v.y + w1 * v.z + w2 * v.w);
        xa[kq + 4 * j + 3][rr] = f2b(bv + w0 * v.z + w1 * v.w + w2 * vp4);
      }
    }
    const float* wsrc = w + (long)(c0 + rr) * KD + k0 + kq;
#pragma unroll
    for (int j = 0; j < 4; ++j) {
      float4 v = *(const float4*)(wsrc + 4 * j);
      ushort4v u = {f2b(v.x), f2b(v.y), f2b(v.z), f2b(v.w)};
      *(ushort4v*)&wb[rr][kq + 4 * j] = u;
    }
    __syncthreads();
#pragma unroll
    for (int ks = 0; ks < 2; ++ks) {
      bf16x8 a = *(const bf16x8*)&xa[wv * 16 + ql][ks * 32 + g * 8];
#pragma unroll
      for (int ct = 0; ct < 4; ++ct) {
        bf16x8 bfr = *(const bf16x8*)&wb[ct * 16 + ql][ks * 32 + g * 8];
        acc[ct] = __builtin_amdgcn_mfma_f32_16x16x32_bf16(a, bfr, acc[ct], 0, 0, 0);
      }
    }
  }
#pragma unroll
  for (int ct = 0; ct < 4; ++ct) {
    int col = c0 + ct * 16 + ql;
    float bv = bias[col];
    if (outCM) {
      long base = ((long)(b * 256 + col)) * 1024 + n0 + wv * 16 + g * 4;
      float4 r4 = *(const float4*)(residCM + base);
      float4 o = make_float4(acc[ct][0] + bv + r4.x, acc[ct][1] + bv + r4.y,
                             acc[ct][2] + bv + r4.z, acc[ct][3] + bv + r4.w);
      *(float4*)(outCM + base) = o;
    } else {
      int nbase = n0 + wv * 16 + g * 4;
      float4 r4 = *(const float4*)&residXCM[((long)(b * 256 + col)) * 1024 + nbase];
      float rv[4] = {r4.x, r4.y, r4.z, r4.w};
#pragma unroll
      for (int reg = 0; reg < 4; ++reg) {
        long row = (long)b * 1024 + nbase + reg;
        outRMb[row * 256 + col] = f2b(acc[ct][reg] + bv + rv[reg]);
      }
    }
  }
}

// ---------- K13: QKV GEMM — bf16 XM2 in, bf16 out ----------
__global__ __launch_bounds__(256) void k_gemm_qkv(const unsigned short* __restrict__ in,
                                                  const float* __restrict__ w,
                                                  const float* __restrict__ bias,
                                                  unsigned short* __restrict__ out) {
  __shared__ unsigned short xa[64][72];
  __shared__ unsigned short wb[64][72];
  int r0 = blockIdx.x * 64;
  int c0 = blockIdx.y * 64;
  int t = threadIdx.x;
  int wv = t >> 6, lane = t & 63, g = lane >> 4, ql = lane & 15;
  const f32x4 zf = {0.f, 0.f, 0.f, 0.f};
  f32x4 acc[4] = {zf, zf, zf, zf};
  int rr = t >> 2, kq = (t & 3) * 16;
  for (int k0 = 0; k0 < 256; k0 += 64) {
    __syncthreads();
    const unsigned short* xsrc = in + (long)(r0 + rr) * 256 + k0 + kq;
#pragma unroll
    for (int j = 0; j < 2; ++j)
      *(ushort8v*)&xa[rr][kq + 8 * j] = *(const ushort8v*)(xsrc + 8 * j);
    const float* wsrc = w + (long)(c0 + rr) * 256 + k0 + kq;
#pragma unroll
    for (int j = 0; j < 4; ++j) {
      float4 v = *(const float4*)(wsrc + 4 * j);
      ushort4v u = {f2b(v.x), f2b(v.y), f2b(v.z), f2b(v.w)};
      *(ushort4v*)&wb[rr][kq + 4 * j] = u;
    }
    __syncthreads();
#pragma unroll
    for (int ks = 0; ks < 2; ++ks) {
      bf16x8 a = *(const bf16x8*)&xa[wv * 16 + ql][ks * 32 + g * 8];
#pragma unroll
      for (int ct = 0; ct < 4; ++ct) {
        bf16x8 b = *(const bf16x8*)&wb[ct * 16 + ql][ks * 32 + g * 8];
        acc[ct] = __builtin_amdgcn_mfma_f32_16x16x32_bf16(a, b, acc[ct], 0, 0, 0);
      }
    }
  }
#pragma unroll
  for (int ct = 0; ct < 4; ++ct) {
    int col = c0 + ct * 16 + ql;
    float bv = bias[col];
#pragma unroll
    for (int reg = 0; reg < 4; ++reg) {
      long row = r0 + wv * 16 + g * 4 + reg;
      out[row * 768 + col] = f2b(acc[ct][reg] + bv);
    }
  }
}

// ---------- K15: attn-out GEMM — bf16 in (O), bf16 out (XGL) ----------
__global__ __launch_bounds__(256) void k_gemm_attnout(const unsigned short* __restrict__ inA,
                                                      const float* __restrict__ w,
                                                      const float* __restrict__ bias,
                                                      unsigned short* __restrict__ out) {
  __shared__ unsigned short xa[64][72];
  __shared__ unsigned short wb[64][72];
  int r0 = blockIdx.x * 64;
  int c0 = blockIdx.y * 64;
  int t = threadIdx.x;
  int wv = t >> 6, lane = t & 63, g = lane >> 4, ql = lane & 15;
  const f32x4 zf = {0.f, 0.f, 0.f, 0.f};
  f32x4 acc[4] = {zf, zf, zf, zf};
  int rr = t >> 2, kq = (t & 3) * 16;
  for (int k0 = 0; k0 < 256; k0 += 64) {
    __syncthreads();
    const unsigned short* xsrc = inA + (long)(r0 + rr) * 256 + k0 + kq;
#pragma unroll
    for (int j = 0; j < 2; ++j)
      *(ushort8v*)&xa[rr][kq + 8 * j] = *(const ushort8v*)(xsrc + 8 * j);
    const float* wsrc = w + (long)(c0 + rr) * 256 + k0 + kq;
#pragma unroll
    for (int j = 0; j < 4; ++j) {
      float4 v = *(const float4*)(wsrc + 4 * j);
      ushort4v u = {f2b(v.x), f2b(v.y), f2b(v.z), f2b(v.w)};
      *(ushort4v*)&wb[rr][kq + 4 * j] = u;
    }
    __syncthreads();
#pragma unroll
    for (int ks = 0; ks < 2; ++ks) {
      bf16x8 a = *(const bf16x8*)&xa[wv * 16 + ql][ks * 32 + g * 8];
#pragma unroll
      for (int ct = 0; ct < 4; ++ct) {
        bf16x8 b = *(const bf16x8*)&wb[ct * 16 + ql][ks * 32 + g * 8];
        acc[ct] = __builtin_amdgcn_mfma_f32_16x16x32_bf16(a, b, acc[ct], 0, 0, 0);
      }
    }
  }
#pragma unroll
  for (int ct = 0; ct < 4; ++ct) {
    int col = c0 + ct * 16 + ql;
    float bv = bias[col];
#pragma unroll
    for (int reg = 0; reg < 4; ++reg) {
      long row = r0 + wv * 16 + g * 4 + reg;
      out[row * 256 + col] = f2b(acc[ct][reg] + bv);
    }
  }
}

// ---------- K16: fc GEMM with x_local row-conv fused; bf16 XM2 + bf16 XGL in ----------
__global__ __launch_bounds__(256) void k_gemm_fc(const unsigned short* __restrict__ XM2,
                                                 const unsigned short* __restrict__ XGL,
                                                 const float* __restrict__ lcw,
                                                 const float* __restrict__ lcb,
                                                 const float* __restrict__ w,
                                                 const float* __restrict__ bias,
                                                 float* __restrict__ out) {
  __shared__ unsigned short xa[64][72];
  __shared__ unsigned short wb[64][72];
  int r0 = blockIdx.x * 64;
  int c0 = blockIdx.y * 64;
  int t = threadIdx.x;
  int wv = t >> 6, lane = t & 63, g = lane >> 4, ql = lane & 15;
  const f32x4 zf = {0.f, 0.f, 0.f, 0.f};
  f32x4 acc[4] = {zf, zf, zf, zf};
  int rr = t >> 2, kq = (t & 3) * 16;
  for (int k0 = 0; k0 < 512; k0 += 64) {
    __syncthreads();
    int kk = k0 + kq;
    long row = r0 + rr;
    if (kk < 256) {
      int n = (int)(row & 1023);
      const unsigned short* pc = XM2 + row * 256 + kk;
      bool hm = n > 0, hp = n < 1023;
#pragma unroll
      for (int j = 0; j < 4; ++j) {
        ushort4v v4 = *(const ushort4v*)(pc + 4 * j);
        ushort4v zm = {0, 0, 0, 0};
        ushort4v vm4 = hm ? *(const ushort4v*)(pc - 256 + 4 * j) : zm;
        ushort4v vp4 = hp ? *(const ushort4v*)(pc + 256 + 4 * j) : zm;
        int c = kk + 4 * j;
#pragma unroll
        for (int e = 0; e < 4; ++e) {
          float vv = b2f(v4[e]);
          float vmv = hm ? b2f(vm4[e]) : 0.f;
          float vpv = hp ? b2f(vp4[e]) : 0.f;
          xa[rr][kq + 4 * j + e] = f2b(lcb[c + e] + lcw[(c + e) * 3] * vmv +
                                       lcw[(c + e) * 3 + 1] * vv +
                                       lcw[(c + e) * 3 + 2] * vpv);
        }
      }
    } else {
      const unsigned short* xsrc = XGL + row * 256 + (kk - 256);
#pragma unroll
      for (int j = 0; j < 2; ++j)
        *(ushort8v*)&xa[rr][kq + 8 * j] = *(const ushort8v*)(xsrc + 8 * j);
    }
    const float* wsrc = w + (long)(c0 + rr) * 512 + kk;
#pragma unroll
    for (int j = 0; j < 4; ++j) {
      float4 v = *(const float4*)(wsrc + 4 * j);
      ushort4v u = {f2b(v.x), f2b(v.y), f2b(v.z), f2b(v.w)};
      *(ushort4v*)&wb[rr][kq + 4 * j] = u;
    }
    __syncthreads();
#pragma unroll
    for (int ks = 0; ks < 2; ++ks) {
      bf16x8 a = *(const bf16x8*)&xa[wv * 16 + ql][ks * 32 + g * 8];
#pragma unroll
      for (int ct = 0; ct < 4; ++ct) {
        bf16x8 b = *(const bf16x8*)&wb[ct * 16 + ql][ks * 32 + g * 8];
        acc[ct] = __builtin_amdgcn_mfma_f32_16x16x32_bf16(a, b, acc[ct], 0, 0, 0);
      }
    }
  }
#pragma unroll
  for (int ct = 0; ct < 4; ++ct) {
    int col = c0 + ct * 16 + ql;
    float bv = bias[col];
#pragma unroll
    for (int reg = 0; reg < 4; ++reg) {
      long row = r0 + wv * 16 + g * 4 + reg;
      out[row * 256 + col] = acc[ct][reg] + bv;
    }
  }
}

// ---------- K14: MFMA bf16 flash attention (bf16 QKV input, bf16 O output) ----------
__global__ __launch_bounds__(256) void k_attn_mfma(const unsigned short* __restrict__ qkvb,
                                                   unsigned short* __restrict__ Ob) {
  __shared__ unsigned short K_lds[64 * 40];
  __shared__ unsigned short Vt_lds[32 * 72];
  __shared__ unsigned short P_lds[4][16 * 72];
  int bx = blockIdx.x;
  int bh = bx >> 4, qt = bx & 15;
  int b = bh >> 3, h = bh & 7;
  int t = threadIdx.x;
  int w = t >> 6, lane = t & 63;
  int g = lane >> 4, ql = lane & 15;
  const float qscale = 0.17677669529663687f * 1.44269504088896341f;  // 1/sqrt(32)*log2(e)

  bf16x8 q_frag = *(const bf16x8*)(qkvb + ((long)(b * N_ + qt * 64 + w * 16 + ql)) * 768 + h * HD_ + g * 8);
  float m = -1e30f, l = 0.f;
  f32x4 o_acc[2];
  const f32x4 zf = {0.f, 0.f, 0.f, 0.f};
  o_acc[0] = zf; o_acc[1] = zf;

  for (int kt = 0; kt < 16; ++kt) {
    __syncthreads();
    {
      int kr = t >> 2, d0 = (t & 3) * 8;
      const unsigned short* gp = qkvb + ((long)(b * N_ + kt * 64 + kr)) * 768 + 256 + h * HD_ + d0;
      ushort8v kv = *(const ushort8v*)gp;
      *(ushort8v*)&K_lds[kr * 40 + d0] = kv;
      ushort8v vv = *(const ushort8v*)(gp + 256);
#pragma unroll
      for (int i = 0; i < 8; ++i) Vt_lds[(d0 + i) * 72 + kr] = vv[i];
    }
    __syncthreads();
    f32x4 s_frag[4];
#pragma unroll
    for (int s = 0; s < 4; ++s) {
      bf16x8 k_frag = *(const bf16x8*)&K_lds[(s * 16 + ql) * 40 + g * 8];
      s_frag[s] = __builtin_amdgcn_mfma_f32_16x16x32_bf16(k_frag, q_frag, zf, 0, 0, 0);
    }
    float sv[16];
#pragma unroll
    for (int s = 0; s < 4; ++s)
#pragma unroll
      for (int r = 0; r < 4; ++r) sv[s * 4 + r] = s_frag[s][r] * qscale;
    float tmax = sv[0];
#pragma unroll
    for (int i = 1; i < 16; ++i) tmax = fmaxf(tmax, sv[i]);
    tmax = fmaxf(tmax, __shfl_xor(tmax, 16));
    tmax = fmaxf(tmax, __shfl_xor(tmax, 32));
    float mn = fmaxf(m, tmax);
    float corr = exp2f(m - mn);
    float psum = 0.f;
    unsigned short pb[16];
#pragma unroll
    for (int i = 0; i < 16; ++i) {
      float p = exp2f(sv[i] - mn);
      psum += p;
      pb[i] = f2b(p);
    }
    psum += __shfl_xor(psum, 16);
    psum += __shfl_xor(psum, 32);
    l = l * corr + psum;
    m = mn;
#pragma unroll
    for (int mt = 0; mt < 2; ++mt)
#pragma unroll
      for (int r = 0; r < 4; ++r) o_acc[mt][r] *= corr;
#pragma unroll
    for (int s = 0; s < 4; ++s) {
      ushort4v p4 = {pb[s * 4], pb[s * 4 + 1], pb[s * 4 + 2], pb[s * 4 + 3]};
      *(ushort4v*)&P_lds[w][ql * 72 + s * 16 + g * 4] = p4;
    }
#pragma unroll
    for (int c = 0; c < 2; ++c) {
      bf16x8 p_frag = *(const bf16x8*)&P_lds[w][ql * 72 + c * 32 + g * 8];
#pragma unroll
      for (int mt = 0; mt < 2; ++mt) {
        bf16x8 v_frag = *(const bf16x8*)&Vt_lds[(mt * 16 + ql) * 72 + c * 32 + g * 8];
        o_acc[mt] = __builtin_amdgcn_mfma_f32_16x16x32_bf16(v_frag, p_frag, o_acc[mt], 0, 0, 0);
      }
    }
  }
  float inv = 1.f / l;
  unsigned short* op = Ob + ((long)(b * N_ + qt * 64 + w * 16 + ql)) * C_ + h * HD_;
#pragma unroll
  for (int mt = 0; mt < 2; ++mt) {
    ushort4v o4 = {f2b(o_acc[mt][0] * inv), f2b(o_acc[mt][1] * inv),
                   f2b(o_acc[mt][2] * inv), f2b(o_acc[mt][3] * inv)};
    *(ushort4v*)(op + mt * 16 + g * 4) = o4;
  }
}

// ---------- K17: LN(lgn) + exact GELU -> (B,C,N), tiled coalesced ----------
__global__ __launch_bounds__(256) void k_lngelu(const float* __restrict__ XO,
                                                const float* __restrict__ lw,
                                                const float* __restrict__ lb,
                                                float* __restrict__ XI) {
  __shared__ float tile[256][17];
  __shared__ float redp[16][16][2];
  __shared__ float stats[16][2];
  int bx = blockIdx.x;
  int b = bx >> 6, n0 = (bx & 63) * 16;
  int c = threadIdx.x;
#pragma unroll
  for (int j = 0; j < 16; ++j)
    tile[c][j] = XO[((long)(b * N_ + n0 + j)) * C_ + c];
  __syncthreads();
  {
    int n = c & 15, g = c >> 4;
    float a = 0.f, q = 0.f;
#pragma unroll
    for (int i = 0; i < 16; ++i) {
      float v = tile[g * 16 + i][n];
      a += v; q += v * v;
    }
    redp[g][n][0] = a; redp[g][n][1] = q;
  }
  __syncthreads();
  if (c < 16) {
    float a = 0.f, q = 0.f;
#pragma unroll
    for (int g2 = 0; g2 < 16; ++g2) { a += redp[g2][c][0]; q += redp[g2][c][1]; }
    float mu = a * (1.f / C_);
    float rs = rsqrtf(q * (1.f / C_) - mu * mu + 1e-5f);
    stats[c][0] = mu; stats[c][1] = rs;
  }
  __syncthreads();
  float wv = lw[c], bv = lb[c];
  float o[16];
#pragma unroll
  for (int j = 0; j < 16; ++j) {
    float x = (tile[c][j] - stats[j][0]) * stats[j][1] * wv + bv;
    o[j] = 0.5f * x * (1.f + erff(x * 0.70710678118654752f));
  }
  float* dst = &XI[((long)(b * C_ + c)) * N_ + n0];
#pragma unroll
  for (int j4 = 0; j4 < 4; ++j4)
    *(float4*)(dst + j4 * 4) = make_float4(o[4 * j4], o[4 * j4 + 1], o[4 * j4 + 2], o[4 * j4 + 3]);
}

// ---------- K18+K19 fused: ln over (H,W) + depthwise 3x3 per (b,c) plane ----------
__global__ __launch_bounds__(256) void k_lnhw_dwc(const float* __restrict__ XIin,
                                                  const float* __restrict__ w,
                                                  const float* __restrict__ bias,
                                                  float* __restrict__ XD) {
  __shared__ float pl[32][33];
  __shared__ float red[8];
  long base = (long)blockIdx.x * 1024;
  int c = blockIdx.x & 255;
  int t = threadIdx.x;
  float4 v = *(const float4*)&XIin[base + t * 4];
  float a = v.x + v.y + v.z + v.w;
  float q = v.x * v.x + v.y * v.y + v.z * v.z + v.w * v.w;
  float2 s = blockReduce2(a, q, red);
  float mu = s.x * (1.f / 1024.f);
  float rs = rsqrtf(s.y * (1.f / 1024.f) - mu * mu + 1e-5f);
  int hh = t >> 3, w0 = (t & 7) * 4;
  pl[hh][w0 + 0] = (v.x - mu) * rs;
  pl[hh][w0 + 1] = (v.y - mu) * rs;
  pl[hh][w0 + 2] = (v.z - mu) * rs;
  pl[hh][w0 + 3] = (v.w - mu) * rs;
  __syncthreads();
  float wk[9];
#pragma unroll
  for (int i = 0; i < 9; ++i) wk[i] = w[c * 9 + i];
  float bv = bias[c];
  float o[4];
#pragma unroll
  for (int j = 0; j < 4; ++j) {
    int ww = w0 + j;
    float acc = bv;
#pragma unroll
    for (int kh = 0; kh < 3; ++kh) {
      int h2 = hh + kh - 1;
      if (h2 < 0 || h2 >= 32) continue;
#pragma unroll
      for (int kw = 0; kw < 3; ++kw) {
        int w2 = ww + kw - 1;
        if (w2 < 0 || w2 >= 32) continue;
        acc += wk[kh * 3 + kw] * pl[h2][w2];
      }
    }
    o[j] = acc;
  }
  *(float4*)&XD[base + t * 4] = make_float4(o[0], o[1], o[2], o[3]);
}

// ---------- K20: fused final LN + projection (cm 2-pass GEMM, direct (B,C,N) out) ----------
__global__ __launch_bounds__(256) void k_lnproj(const float* __restrict__ XD,
                                                const float* __restrict__ nw,
                                                const float* __restrict__ nbias,
                                                const float* __restrict__ w,
                                                const float* __restrict__ bias,
                                                float* __restrict__ out) {
  __shared__ unsigned short xa[64][72];
  __shared__ unsigned short wb[64][72];
  __shared__ float ps[4][64], pq[4][64];
  __shared__ float mu_s[64], rs_s[64];
  int rb = blockIdx.x;
  int b = rb >> 4, n0 = (rb & 15) * 64;
  int c0 = blockIdx.y * 64;
  int t = threadIdx.x;
  {
    int nl = t & 63, cq = t >> 6;
    const float* src = XD + ((long)(b * 256 + cq * 64)) * 1024 + n0 + nl;
    float s = 0.f, q = 0.f;
    for (int i = 0; i < 64; ++i) {
      float v = src[(long)i * 1024];
      s += v; q += v * v;
    }
    ps[cq][nl] = s; pq[cq][nl] = q;
  }
  __syncthreads();
  if (t < 64) {
    float s = ps[0][t] + ps[1][t] + ps[2][t] + ps[3][t];
    float q = pq[0][t] + pq[1][t] + pq[2][t] + pq[3][t];
    float mu = s * (1.f / 256.f);
    float rs = rsqrtf(q * (1.f / 256.f) - mu * mu + 1e-5f);
    mu_s[t] = mu; rs_s[t] = rs;
  }
  int wv = t >> 6, lane = t & 63, g = lane >> 4, ql = lane & 15;
  const f32x4 zf = {0.f, 0.f, 0.f, 0.f};
  f32x4 acc[4] = {zf, zf, zf, zf};
  int rr = t >> 2, kq = (t & 3) * 16;
  for (int k0 = 0; k0 < 256; k0 += 64) {
    __syncthreads();
    {
      int ch = k0 + rr;
      const float* src = XD + ((long)(b * 256 + ch)) * 1024 + n0 + kq;
      float wv_ = nw[ch], bv_ = nbias[ch];
#pragma unroll
      for (int j = 0; j < 4; ++j) {
        float4 v = *(const float4*)(src + 4 * j);
        int n = kq + 4 * j;
        xa[n + 0][rr] = f2b((v.x - mu_s[n + 0]) * rs_s[n + 0] * wv_ + bv_);
        xa[n + 1][rr] = f2b((v.y - mu_s[n + 1]) * rs_s[n + 1] * wv_ + bv_);
        xa[n + 2][rr] = f2b((v.z - mu_s[n + 2]) * rs_s[n + 2] * wv_ + bv_);
        xa[n + 3][rr] = f2b((v.w - mu_s[n + 3]) * rs_s[n + 3] * wv_ + bv_);
      }
      const float* wsrc = w + (long)(c0 + rr) * 256 + k0 + kq;
#pragma unroll
      for (int j = 0; j < 4; ++j) {
        float4 v = *(const float4*)(wsrc + 4 * j);
        ushort4v u = {f2b(v.x), f2b(v.y), f2b(v.z), f2b(v.w)};
        *(ushort4v*)&wb[rr][kq + 4 * j] = u;
      }
    }
    __syncthreads();
#pragma unroll
    for (int ks = 0; ks < 2; ++ks) {
      bf16x8 a = *(const bf16x8*)&xa[wv * 16 + ql][ks * 32 + g * 8];
#pragma unroll
      for (int ct = 0; ct < 4; ++ct) {
        bf16x8 bfr = *(const bf16x8*)&wb[ct * 16 + ql][ks * 32 + g * 8];
        acc[ct] = __builtin_amdgcn_mfma_f32_16x16x32_bf16(a, bfr, acc[ct], 0, 0, 0);
      }
    }
  }
#pragma unroll
  for (int ct = 0; ct < 4; ++ct) {
    int col = c0 + ct * 16 + ql;
    float bv = bias[col];
    long basei = ((long)(b * 256 + col)) * 1024 + n0 + wv * 16 + g * 4;
    *(float4*)(out + basei) = make_float4(acc[ct][0] + bv, acc[ct][1] + bv,
                                          acc[ct][2] + bv, acc[ct][3] + bv);
  }
}

extern "C" void kernel_launch(void* const* d_in, const int* in_sizes, int n_in,
                              void* d_out, int out_size, void* d_ws, size_t ws_size,
                              hipStream_t stream) {
  const float* x        = (const float*)d_in[0];
  const float* norm_w   = (const float*)d_in[1];
  const float* norm_b   = (const float*)d_in[2];
  const float* skip     = (const float*)d_in[3];
  const float* m_inw    = (const float*)d_in[4];
  const float* m_convw  = (const float*)d_in[5];
  const float* m_convb  = (const float*)d_in[6];
  const float* m_xpw    = (const float*)d_in[7];
  const float* m_dtw    = (const float*)d_in[8];
  const float* m_dtb    = (const float*)d_in[9];
  const float* m_alog   = (const float*)d_in[10];
  const float* m_d      = (const float*)d_in[11];
  const float* m_outw   = (const float*)d_in[12];
  const float* qdw_w    = (const float*)d_in[13];
  const float* qdw_b    = (const float*)d_in[14];
  const float* qpw_w    = (const float*)d_in[15];
  const float* qpw_b    = (const float*)d_in[16];
  const float* rdw_w    = (const float*)d_in[17];
  const float* rdw_b    = (const float*)d_in[18];
  const float* rpw_w    = (const float*)d_in[19];
  const float* rpw_b    = (const float*)d_in[20];
  const float* fdw_w    = (const float*)d_in[21];
  const float* fdw_b    = (const float*)d_in[22];
  const float* fpw_w    = (const float*)d_in[23];
  const float* fpw_b    = (const float*)d_in[24];
  const float* lc_w     = (const float*)d_in[25];
  const float* lc_b     = (const float*)d_in[26];
  const float* attn_inw = (const float*)d_in[27];
  const float* attn_inb = (const float*)d_in[28];
  const float* attn_outw= (const float*)d_in[29];
  const float* attn_outb= (const float*)d_in[30];
  const float* lgn_w    = (const float*)d_in[31];
  const float* lgn_b    = (const float*)d_in[32];
  const float* fc_w     = (const float*)d_in[33];
  const float* fc_b     = (const float*)d_in[34];
  const float* dwc_w    = (const float*)d_in[35];
  const float* dwc_b    = (const float*)d_in[36];
  const float* proj_w   = (const float*)d_in[37];
  const float* proj_b   = (const float*)d_in[38];
  float* out = (float*)d_out;

  float* ws = (float*)d_ws;
  const size_t F = 1048576;  // B*N*C
  float* XN  = ws + 1 * F;
  unsigned short* UB = (unsigned short*)(ws + 2 * F);     // bf16 U (1F region)
  float* Z   = ws + 4 * F;
  float* DT  = ws + 6 * F;
  float* BM  = ws + 8 * F;
  float* CM  = ws + 8 * F + F / 4;
  float* XMC = ws + 8 * F + F / 2;
  float* SC_APROD = ws + 8 * F + F / 2;   // scan scratch (XMC region, dead then)
  float* SC_HEND  = ws + 9 * F;
  float* G   = ws + 0 * F;                // small (16K floats)
  float* XG  = ws + 2 * F;                // U dead after scanC
  float* RB  = ws + 4 * F;                // Z dead after outproj
  unsigned short* XM2B = (unsigned short*)(ws + 5 * F);   // bf16 XM2
  unsigned short* QKVB = (unsigned short*)(ws + 1 * F);   // XN dead after outproj
  unsigned short* OB   = (unsigned short*)(ws + 4 * F);   // RB dead after fpw
  unsigned short* XGLB = (unsigned short*)(ws + 6 * F);   // DT dead after outproj
  float* XO  = ws + 7 * F;
  float* XI  = ws + 8 * F;
  float* XD  = ws + 0 * F;                // G dead after xg
  (void)ws_size; (void)in_sizes; (void)n_in; (void)out_size;

  k_ln_t2<<<256, 256, 0, stream>>>(x, norm_w, norm_b, XN);
  k_inproj_conv<<<dim3(64, 16), 256, 0, stream>>>(XN, m_inw, m_convw, m_convb, UB, Z);
  k_xdbc_scanA<<<256, 256, 0, stream>>>(UB, m_xpw, m_dtw, m_dtb, m_alog,
                                        DT, BM, CM, SC_APROD, SC_HEND);
  k_scanC<<<512, 256, 0, stream>>>(DT, UB, BM, CM, m_alog, m_d, SC_APROD, SC_HEND);
  k_outproj_mfma<<<dim3(64, 4), 256, 0, stream>>>(DT, Z, m_outw, XN, skip, XMC);
  k_gate<<<256, 256, 0, stream>>>(XMC, qdw_w, qdw_b, qpw_w, qpw_b, G);
  k_xg<<<256, 256, 0, stream>>>(XMC, G, XG);
  k_gemm_cm_dw<256><<<dim3(64, 4), 256, 0, stream>>>(XG, nullptr, rdw_w, rdw_b,
                                                     rpw_w, rpw_b, XG, nullptr, RB, nullptr);
  k_gemm_cm_dw<512><<<dim3(64, 4), 256, 0, stream>>>(x, RB, fdw_w, fdw_b,
                                                     fpw_w, fpw_b, nullptr, x, nullptr, XM2B);
  k_gemm_qkv<<<dim3(64, 12), 256, 0, stream>>>(XM2B, attn_inw, attn_inb, QKVB);
  k_attn_mfma<<<512, 256, 0, stream>>>(QKVB, OB);
  k_gemm_attnout<<<dim3(64, 4), 256, 0, stream>>>(OB, attn_outw, attn_outb, XGLB);
  k_gemm_fc<<<dim3(64, 4), 256, 0, stream>>>(XM2B, XGLB, lc_w, lc_b, fc_w, fc_b, XO);
  k_lngelu<<<256, 256, 0, stream>>>(XO, lgn_w, lgn_b, XI);
  k_lnhw_dwc<<<1024, 256, 0, stream>>>(XI, dwc_w, dwc_b, XD);
  k_lnproj<<<dim3(64, 4), 256, 0, stream>>>(XD, norm_w, norm_b, proj_w, proj_b, out);
}

// Round 18
// 193.084 us; speedup vs baseline: 1.0621x; 1.0621x over previous
//
#include <hip/hip_runtime.h>
#include <math.h>

// MambaLiteUNet — round 17: row-split the 1-block/CU GEMMs (outproj, cm_dw x2,
// attnout, fc) to 32-row tiles -> 2 blocks/CU for cross-block phase overlap.

namespace {
constexpr int NB_ = 4, DM_ = 64, DIN_ = 128, DS_ = 16, DTR_ = 4;
constexpr int C_ = 256, N_ = 1024, B_ = 4, HD_ = 32;
constexpr int NCH = 16, LCH = 64;          // scan: 16 time-chunks of 64
constexpr int NSTATE = 16 * 128 * 16;      // nbb * DIN * DS = 32768
}

typedef __attribute__((ext_vector_type(8))) short bf16x8;
typedef __attribute__((ext_vector_type(4))) float f32x4;
typedef __attribute__((ext_vector_type(8))) unsigned short ushort8v;
typedef __attribute__((ext_vector_type(4))) unsigned short ushort4v;

// ---------- helpers ----------
__device__ __forceinline__ unsigned short f2b(float f) {  // fp32 -> bf16 RNE
  unsigned int u = __float_as_uint(f);
  unsigned int r = u + 0x7FFFu + ((u >> 16) & 1u);
  return (unsigned short)(r >> 16);
}
__device__ __forceinline__ float b2f(unsigned short u) {
  return __uint_as_float(((unsigned int)u) << 16);
}

__device__ __forceinline__ float2 blockReduce2(float a, float b, float* red) {
#pragma unroll
  for (int m = 1; m < 64; m <<= 1) {
    a += __shfl_xor(a, m, 64);
    b += __shfl_xor(b, m, 64);
  }
  int w = threadIdx.x >> 6;
  if ((threadIdx.x & 63) == 0) { red[2 * w] = a; red[2 * w + 1] = b; }
  __syncthreads();
  float ra = red[0] + red[2] + red[4] + red[6];
  float rb = red[1] + red[3] + red[5] + red[7];
  return make_float2(ra, rb);
}

__device__ __forceinline__ float siluf(float x) { return x / (1.f + expf(-x)); }
__device__ __forceinline__ float sigmf(float x) { return 1.f / (1.f + expf(-x)); }
__device__ __forceinline__ float softplusf(float x) {
  return fmaxf(x, 0.f) + log1pf(expf(-fabsf(x)));
}

// ---------- K1: LN over C of (B,C,N) -> (B,N,C), coalesced LDS-tile ----------
__global__ __launch_bounds__(256) void k_ln_t2(const float* __restrict__ in,
                                               const float* __restrict__ w,
                                               const float* __restrict__ bias,
                                               float* __restrict__ out_ln) {
  __shared__ float tile[256][17];
  __shared__ float redp[16][16][2];
  __shared__ float stats[16][2];
  int bx = blockIdx.x;
  int b = bx >> 6, n0 = (bx & 63) * 16;
  int c = threadIdx.x;
  {
    const float* p = in + ((long)(b * C_ + c)) * N_ + n0;
#pragma unroll
    for (int j = 0; j < 16; ++j) tile[c][j] = p[j];
  }
  __syncthreads();
  {
    int n = c & 15, g = c >> 4;
    float a = 0.f, q = 0.f;
#pragma unroll
    for (int i = 0; i < 16; ++i) {
      float v = tile[g * 16 + i][n];
      a += v; q += v * v;
    }
    redp[g][n][0] = a; redp[g][n][1] = q;
  }
  __syncthreads();
  if (c < 16) {
    float a = 0.f, q = 0.f;
#pragma unroll
    for (int g2 = 0; g2 < 16; ++g2) { a += redp[g2][c][0]; q += redp[g2][c][1]; }
    float mu = a * (1.f / C_);
    float rs = rsqrtf(q * (1.f / C_) - mu * mu + 1e-5f);
    stats[c][0] = mu; stats[c][1] = rs;
  }
  __syncthreads();
  float wv = w[c], bv = bias[c];
#pragma unroll
  for (int j = 0; j < 16; ++j) {
    float v = tile[c][j];
    long o = ((long)(b * N_ + n0 + j)) * C_ + c;
    out_ln[o] = (v - stats[j][0]) * stats[j][1] * wv + bv;
  }
}

// ---------- K2: mamba in-proj (MFMA) with fused causal conv + silu; U out bf16 ----------
__global__ __launch_bounds__(256) void k_inproj_conv(const float* __restrict__ xn,
                                                     const float* __restrict__ inw,
                                                     const float* __restrict__ cw,
                                                     const float* __restrict__ cb,
                                                     unsigned short* __restrict__ U,
                                                     float* __restrict__ Z) {
  __shared__ unsigned short xa[64][72];
  __shared__ unsigned short wb[64][72];
  __shared__ float ut[67][65];
  int r0 = blockIdx.x * 64;
  int nb = blockIdx.y >> 2, q = blockIdx.y & 3, c0 = q * 64;
  int t = threadIdx.x;
  int wv = t >> 6, lane = t & 63, g = lane >> 4, ql = lane & 15;
  const f32x4 zf = {0.f, 0.f, 0.f, 0.f};
  f32x4 acc[4] = {zf, zf, zf, zf};
  int rr = t >> 2, kq = (t & 3) * 16;
  {
    const float* xsrc = xn + (long)(r0 + rr) * C_ + nb * 64 + kq;
#pragma unroll
    for (int j = 0; j < 4; ++j) {
      float4 v = *(const float4*)(xsrc + 4 * j);
      ushort4v u = {f2b(v.x), f2b(v.y), f2b(v.z), f2b(v.w)};
      *(ushort4v*)&xa[rr][kq + 4 * j] = u;
    }
    const float* wsrc = inw + ((long)nb * 256 + c0 + rr) * 64 + kq;
#pragma unroll
    for (int j = 0; j < 4; ++j) {
      float4 v = *(const float4*)(wsrc + 4 * j);
      ushort4v u = {f2b(v.x), f2b(v.y), f2b(v.z), f2b(v.w)};
      *(ushort4v*)&wb[rr][kq + 4 * j] = u;
    }
  }
  __syncthreads();
#pragma unroll
  for (int ks = 0; ks < 2; ++ks) {
    bf16x8 a = *(const bf16x8*)&xa[wv * 16 + ql][ks * 32 + g * 8];
#pragma unroll
    for (int ct = 0; ct < 4; ++ct) {
      bf16x8 b = *(const bf16x8*)&wb[ct * 16 + ql][ks * 32 + g * 8];
      acc[ct] = __builtin_amdgcn_mfma_f32_16x16x32_bf16(a, b, acc[ct], 0, 0, 0);
    }
  }
  if (q < 2) {
#pragma unroll
    for (int ct = 0; ct < 4; ++ct)
#pragma unroll
      for (int reg = 0; reg < 4; ++reg)
        ut[3 + wv * 16 + g * 4 + reg][ct * 16 + ql] = acc[ct][reg];
    if (t < 192) {
      int hr = t >> 6, lc = t & 63;
      float hv = 0.f;
      if ((r0 & 1023) != 0) {
        const float* xrow = xn + (long)(r0 - 3 + hr) * C_ + nb * 64;
        const float* wrow = inw + ((long)nb * 256 + c0 + lc) * 64;
#pragma unroll 8
        for (int k = 0; k < 64; ++k) hv += xrow[k] * wrow[k];
      }
      ut[hr][lc] = hv;
    }
    __syncthreads();
#pragma unroll
    for (int ct = 0; ct < 4; ++ct) {
      int lc = ct * 16 + ql;
      int d = c0 + lc;
      const float* cwp = cw + (nb * DIN_ + d) * 4;
      float w0 = cwp[0], w1 = cwp[1], w2 = cwp[2], w3 = cwp[3];
      float bv = cb[nb * DIN_ + d];
#pragma unroll
      for (int reg = 0; reg < 4; ++reg) {
        int lr = wv * 16 + g * 4 + reg;
        float a = bv + w3 * ut[3 + lr][lc] + w2 * ut[2 + lr][lc] +
                  w1 * ut[1 + lr][lc] + w0 * ut[lr][lc];
        long row = (long)nb * 4096 + r0 + lr;
        U[row * DIN_ + d] = f2b(siluf(a));
      }
    }
  } else {
#pragma unroll
    for (int ct = 0; ct < 4; ++ct) {
      int col = c0 - 128 + ct * 16 + ql;
#pragma unroll
      for (int reg = 0; reg < 4; ++reg) {
        long row = (long)nb * 4096 + r0 + wv * 16 + g * 4 + reg;
        Z[row * DIN_ + col] = acc[ct][reg];
      }
    }
  }
}

// ---------- K4: xdbc (MFMA, bf16 U in) + dt/Bm/Cm epilogue + fused scan phase A ----------
__global__ __launch_bounds__(256) void k_xdbc_scanA(const unsigned short* __restrict__ U,
                                                    const float* __restrict__ xpw,
                                                    const float* __restrict__ dtw,
                                                    const float* __restrict__ dtb,
                                                    const float* __restrict__ alog,
                                                    float* __restrict__ DT,
                                                    float* __restrict__ BMb,
                                                    float* __restrict__ CMb,
                                                    float* __restrict__ Aprod,
                                                    float* __restrict__ Hend) {
  __shared__ unsigned short xa[64][72];
  __shared__ unsigned short wb[48][72];
  __shared__ float xd_s[64][40];
  __shared__ float dtw_s[128][4];
  __shared__ float dtb_s[128];
  __shared__ float dt_s[64][132];
  __shared__ float u_s[64][132];
  __shared__ float bm_s[64][20];
  int t = threadIdx.x;
  long row0 = (long)blockIdx.x * 64;
  int nb = blockIdx.x >> 6;
  int nbb = blockIdx.x >> 4, chunk = blockIdx.x & 15;
  for (int i = t; i < 512; i += 256) dtw_s[i >> 2][i & 3] = dtw[nb * 512 + i];
  if (t < 128) dtb_s[t] = dtb[nb * DIN_ + t];
  int wv = t >> 6, lane = t & 63, g = lane >> 4, ql = lane & 15;
  const f32x4 zf = {0.f, 0.f, 0.f, 0.f};
  f32x4 acc[3] = {zf, zf, zf};
  int rr = t >> 2, kq = (t & 3) * 16;
  for (int k0 = 0; k0 < 128; k0 += 64) {
    __syncthreads();
    const unsigned short* xsrc = U + (row0 + rr) * DIN_ + k0 + kq;
#pragma unroll
    for (int j = 0; j < 2; ++j) {
      ushort8v u8 = *(const ushort8v*)(xsrc + 8 * j);
      *(ushort8v*)&xa[rr][kq + 8 * j] = u8;
#pragma unroll
      for (int e = 0; e < 8; ++e) u_s[rr][k0 + kq + 8 * j + e] = b2f(u8[e]);
    }
    if (rr < 48) {
      if (rr < 36) {
        const float* wsrc = xpw + (long)nb * 36 * 128 + rr * 128 + k0 + kq;
#pragma unroll
        for (int j = 0; j < 4; ++j) {
          float4 v = *(const float4*)(wsrc + 4 * j);
          ushort4v u = {f2b(v.x), f2b(v.y), f2b(v.z), f2b(v.w)};
          *(ushort4v*)&wb[rr][kq + 4 * j] = u;
        }
      } else {
        ushort4v z = {0, 0, 0, 0};
#pragma unroll
        for (int j = 0; j < 4; ++j) *(ushort4v*)&wb[rr][kq + 4 * j] = z;
      }
    }
    __syncthreads();
#pragma unroll
    for (int ks = 0; ks < 2; ++ks) {
      bf16x8 a = *(const bf16x8*)&xa[wv * 16 + ql][ks * 32 + g * 8];
#pragma unroll
      for (int ct = 0; ct < 3; ++ct) {
        bf16x8 b = *(const bf16x8*)&wb[ct * 16 + ql][ks * 32 + g * 8];
        acc[ct] = __builtin_amdgcn_mfma_f32_16x16x32_bf16(a, b, acc[ct], 0, 0, 0);
      }
    }
  }
#pragma unroll
  for (int ct = 0; ct < 3; ++ct) {
    int col = ct * 16 + ql;
    if (col < 36) {
#pragma unroll
      for (int reg = 0; reg < 4; ++reg)
        xd_s[wv * 16 + g * 4 + reg][col] = acc[ct][reg];
    }
  }
  __syncthreads();
  {
    int r = t >> 2, sq = (t & 3) * 4;
    float4 bm4 = make_float4(xd_s[r][4 + sq], xd_s[r][5 + sq],
                             xd_s[r][6 + sq], xd_s[r][7 + sq]);
    *(float4*)&BMb[(row0 + r) * DS_ + sq] = bm4;
    *(float4*)&bm_s[r][sq] = bm4;
    float4 cm4 = make_float4(xd_s[r][20 + sq], xd_s[r][21 + sq],
                             xd_s[r][22 + sq], xd_s[r][23 + sq]);
    *(float4*)&CMb[(row0 + r) * DS_ + sq] = cm4;
  }
  {
    int r = t >> 2, dg = t & 3;
    float x0 = xd_s[r][0], x1 = xd_s[r][1], x2 = xd_s[r][2], x3 = xd_s[r][3];
    float* dst = DT + (row0 + r) * DIN_ + dg * 32;
#pragma unroll
    for (int j = 0; j < 8; ++j) {
      float o[4];
#pragma unroll
      for (int e = 0; e < 4; ++e) {
        int d = dg * 32 + j * 4 + e;
        float a = dtb_s[d] + x0 * dtw_s[d][0] + x1 * dtw_s[d][1] +
                  x2 * dtw_s[d][2] + x3 * dtw_s[d][3];
        o[e] = softplusf(a);
      }
      float4 o4 = make_float4(o[0], o[1], o[2], o[3]);
      *(float4*)(dst + j * 4) = o4;
      *(float4*)&dt_s[r][dg * 32 + j * 4] = o4;
    }
  }
  __syncthreads();
  {
    int dl = t >> 2, sg = t & 3;
#pragma unroll
    for (int dh = 0; dh < 2; ++dh) {
      int d = dh * 64 + dl;
      float A[4];
#pragma unroll
      for (int i = 0; i < 4; ++i)
        A[i] = -expf(alog[(nb * DIN_ + d) * DS_ + sg * 4 + i]);
      float h[4] = {0.f, 0.f, 0.f, 0.f};
      float ap[4] = {1.f, 1.f, 1.f, 1.f};
      for (int tt = 0; tt < LCH; ++tt) {
        float dtv = dt_s[tt][d];
        float uv  = u_s[tt][d];
        float cc = dtv * uv;
        float4 bm4 = *(const float4*)&bm_s[tt][sg * 4];
        float bmv[4] = {bm4.x, bm4.y, bm4.z, bm4.w};
#pragma unroll
        for (int i = 0; i < 4; ++i) {
          float dA = __expf(dtv * A[i]);
          h[i] = dA * h[i] + cc * bmv[i];
          ap[i] *= dA;
        }
      }
      long st = (long)chunk * NSTATE + ((nbb << 7) + d) * 16 + sg * 4;
      *(float4*)&Aprod[st] = make_float4(ap[0], ap[1], ap[2], ap[3]);
      *(float4*)&Hend[st]  = make_float4(h[0], h[1], h[2], h[3]);
    }
  }
}

// ---------- K5c: scan phase C — inline carry composition, emit y over DT ----------
__global__ __launch_bounds__(256) void k_scanC(float* __restrict__ DT,
                                               const unsigned short* __restrict__ U,
                                               const float* __restrict__ BMb,
                                               const float* __restrict__ CMb,
                                               const float* __restrict__ alog,
                                               const float* __restrict__ Dp,
                                               const float* __restrict__ Aprod,
                                               const float* __restrict__ Hend) {
  __shared__ float dt_s[64][64];
  __shared__ float u_s[64][64];
  __shared__ float bm_s[64][16];
  __shared__ float cm_s[64][16];
  int bx = blockIdx.x;
  int chunk = bx >> 5, rem = bx & 31, nbb = rem >> 1, dh = rem & 1;
  int nb = nbb >> 2;
  int t = threadIdx.x;
  int dl = t >> 2, sg = t & 3;
  int d = dh * 64 + dl;
  long base = (long)nbb * N_ + chunk * LCH;
#pragma unroll
  for (int j = 0; j < 4; ++j) {
    int f = t + 256 * j;
    int tt = f >> 4, dq = (f & 15) * 4;
    long src = (base + tt) * DIN_ + dh * 64 + dq;
    *(float4*)&dt_s[tt][dq] = *(const float4*)&DT[src];
    ushort4v u4 = *(const ushort4v*)&U[src];
    u_s[tt][dq + 0] = b2f(u4[0]);
    u_s[tt][dq + 1] = b2f(u4[1]);
    u_s[tt][dq + 2] = b2f(u4[2]);
    u_s[tt][dq + 3] = b2f(u4[3]);
  }
  {
    int tt = t >> 2, sq = (t & 3) * 4;
    *(float4*)&bm_s[tt][sq] = *(const float4*)&BMb[(base + tt) * DS_ + sq];
    *(float4*)&cm_s[tt][sq] = *(const float4*)&CMb[(base + tt) * DS_ + sq];
  }
  float A[4];
#pragma unroll
  for (int i = 0; i < 4; ++i)
    A[i] = -expf(alog[(nb * DIN_ + d) * DS_ + sg * 4 + i]);
  float Dv = Dp[nb * DIN_ + d];
  float h[4] = {0.f, 0.f, 0.f, 0.f};
  {
    long state4 = ((nbb << 7) + d) * 16 + sg * 4;
    for (int c = 0; c < chunk; ++c) {
      float4 a4 = *(const float4*)&Aprod[(long)c * NSTATE + state4];
      float4 e4 = *(const float4*)&Hend[(long)c * NSTATE + state4];
      h[0] = e4.x + a4.x * h[0];
      h[1] = e4.y + a4.y * h[1];
      h[2] = e4.z + a4.z * h[2];
      h[3] = e4.w + a4.w * h[3];
    }
  }
  __syncthreads();
  for (int tt = 0; tt < LCH; ++tt) {
    float dtv = dt_s[tt][dl];
    float uv  = u_s[tt][dl];
    float cc = dtv * uv;
    float4 bm4 = *(const float4*)&bm_s[tt][sg * 4];
    float4 cm4 = *(const float4*)&cm_s[tt][sg * 4];
    float bmv[4] = {bm4.x, bm4.y, bm4.z, bm4.w};
    float cmv[4] = {cm4.x, cm4.y, cm4.z, cm4.w};
    float p = 0.f;
#pragma unroll
    for (int i = 0; i < 4; ++i) {
      float dA = __expf(dtv * A[i]);
      h[i] = dA * h[i] + cc * bmv[i];
      p += h[i] * cmv[i];
    }
    p += __shfl_xor(p, 1, 64);
    p += __shfl_xor(p, 2, 64);
    if (sg == 0) DT[(base + tt) * DIN_ + d] = p + Dv * uv;
  }
}

// ---------- K6: out-proj (MFMA, 32-row tile): xm = (y*silu(z)) @ outw^T + skip*xn ----------
// grid dim3(128, 4): 32-row tiles x nb. 4 waves = 2 row-groups x 2 col-pairs.
__global__ __launch_bounds__(256) void k_outproj_mfma(const float* __restrict__ Y,
                                                      const float* __restrict__ Zb,
                                                      const float* __restrict__ outw,
                                                      const float* __restrict__ xn,
                                                      const float* __restrict__ skip,
                                                      float* __restrict__ XMC) {
  __shared__ unsigned short xa[32][72];
  __shared__ unsigned short wb[64][72];
  int r0 = blockIdx.x * 32;
  int nb = blockIdx.y;
  int t = threadIdx.x;
  int w = t >> 6, lane = t & 63, g = lane >> 4, ql = lane & 15;
  int rg = w & 1, cp = w >> 1;
  const f32x4 zf = {0.f, 0.f, 0.f, 0.f};
  f32x4 acc[2] = {zf, zf};
  int ar = t >> 3, ak = (t & 7) * 8;
  int wr = t >> 2, wk = (t & 3) * 16;
  for (int k0 = 0; k0 < 128; k0 += 64) {
    __syncthreads();
    long row = (long)nb * 4096 + r0 + ar;
    const float* ysrc = Y + row * DIN_ + k0 + ak;
    const float* zsrc = Zb + row * DIN_ + k0 + ak;
#pragma unroll
    for (int j = 0; j < 2; ++j) {
      float4 yv = *(const float4*)(ysrc + 4 * j);
      float4 zv = *(const float4*)(zsrc + 4 * j);
      ushort4v u = {f2b(yv.x * siluf(zv.x)), f2b(yv.y * siluf(zv.y)),
                    f2b(yv.z * siluf(zv.z)), f2b(yv.w * siluf(zv.w))};
      *(ushort4v*)&xa[ar][ak + 4 * j] = u;
    }
    const float* wsrc = outw + ((long)nb * 64 + wr) * 128 + k0 + wk;
#pragma unroll
    for (int j = 0; j < 4; ++j) {
      float4 v = *(const float4*)(wsrc + 4 * j);
      ushort4v u = {f2b(v.x), f2b(v.y), f2b(v.z), f2b(v.w)};
      *(ushort4v*)&wb[wr][wk + 4 * j] = u;
    }
    __syncthreads();
#pragma unroll
    for (int ks = 0; ks < 2; ++ks) {
      bf16x8 a = *(const bf16x8*)&xa[rg * 16 + ql][ks * 32 + g * 8];
#pragma unroll
      for (int ct = 0; ct < 2; ++ct) {
        bf16x8 b = *(const bf16x8*)&wb[(cp * 2 + ct) * 16 + ql][ks * 32 + g * 8];
        acc[ct] = __builtin_amdgcn_mfma_f32_16x16x32_bf16(a, b, acc[ct], 0, 0, 0);
      }
    }
  }
  float sk = skip[0];
#pragma unroll
  for (int ct = 0; ct < 2; ++ct) {
    int col = (cp * 2 + ct) * 16 + ql;
#pragma unroll
    for (int reg = 0; reg < 4; ++reg) {
      int bn = r0 + rg * 16 + g * 4 + reg;
      long oc = (long)bn * C_ + nb * 64 + col;
      XMC[oc] = acc[ct][reg] + sk * xn[oc];
    }
  }
}

// ---------- K7: gate ----------
__global__ __launch_bounds__(256) void k_gate(const float* __restrict__ XMC,
                                              const float* __restrict__ qdw_w,
                                              const float* __restrict__ qdw_b,
                                              const float* __restrict__ qpw_w,
                                              const float* __restrict__ qpw_b,
                                              float* __restrict__ G) {
  int t = threadIdx.x;
  int gid = (blockIdx.x * 256 + t) >> 4;     // b*N + n
  int cq = t & 3, p = (t >> 2) & 3;
  int b = gid >> 10, n = gid & 1023;
  float a = 0.f;
#pragma unroll
  for (int k = 0; k < 3; ++k) {
    int nn = n + k - 1;
    if (nn < 0 || nn >= N_) continue;
    const float* xr = XMC + ((long)b * N_ + nn) * C_ + p * 64 + cq * 16;
    const float* wr = qdw_w + (p * 64 + cq * 16) * 3 + k;
    float xv[16];
    *(float4*)&xv[0]  = *(const float4*)(xr);
    *(float4*)&xv[4]  = *(const float4*)(xr + 4);
    *(float4*)&xv[8]  = *(const float4*)(xr + 8);
    *(float4*)&xv[12] = *(const float4*)(xr + 12);
#pragma unroll
    for (int i = 0; i < 16; ++i) a += xv[i] * wr[i * 3];
  }
  a += __shfl_xor(a, 1, 64);
  a += __shfl_xor(a, 2, 64);
  float q1 = a + qdw_b[p];
  int lane = t & 63;
  float q1g[4];
#pragma unroll
  for (int pp = 0; pp < 4; ++pp) q1g[pp] = __shfl(q1, (lane & ~12) | (pp << 2), 64);
  int o = p;
  float r = qpw_b[o];
#pragma unroll
  for (int pp = 0; pp < 4; ++pp) r += qpw_w[o * 4 + pp] * q1g[pp];
  if (cq == 0) G[((long)b * 4 + o) * N_ + n] = sigmf(r);
}

// ---------- K8: xg (B,C,N) = g * xm — LDS tile transpose ----------
__global__ __launch_bounds__(256) void k_xg(const float* __restrict__ XMC,
                                            const float* __restrict__ G,
                                            float* __restrict__ XG) {
  __shared__ float tile[64][65];
  int bx = blockIdx.x;
  int b = bx >> 6, ct = (bx >> 4) & 3, nt = bx & 15;
  int c0 = ct * 64, n0 = nt * 64;
  int t = threadIdx.x;
  {
    int cc = t & 63, nq = t >> 6;
#pragma unroll
    for (int j = 0; j < 16; ++j) {
      int nn = nq * 16 + j;
      tile[cc][nn] = XMC[((long)(b * N_ + n0 + nn)) * C_ + c0 + cc];
    }
  }
  __syncthreads();
  {
    int nl = t & 63, cq = t >> 6;
    float g = G[((long)(b * 4 + ct)) * N_ + n0 + nl];
#pragma unroll
    for (int j = 0; j < 16; ++j) {
      int cl = cq * 16 + j;
      XG[((long)(b * C_ + c0 + cl)) * N_ + n0 + nl] = g * tile[cl][nl];
    }
  }
}

// ---------- MFMA GEMM (32-n tile), channel-major, 3-tap dw conv fused ----------
// grid dim3(128, 4): b(4) x ntile(32), c0 = y*64.
template <int KD>
__global__ __launch_bounds__(256) void k_gemm_cm_dw(const float* __restrict__ inA,
                                                    const float* __restrict__ inB,
                                                    const float* __restrict__ dww,
                                                    const float* __restrict__ dwb,
                                                    const float* __restrict__ w,
                                                    const float* __restrict__ bias,
                                                    const float* __restrict__ residCM,
                                                    const float* __restrict__ residXCM,
                                                    float* __restrict__ outCM,
                                                    unsigned short* __restrict__ outRMb) {
  __shared__ unsigned short xa[32][72];  // [n][k]
  __shared__ unsigned short wb[64][72];  // [cout][k]
  int rb = blockIdx.x;
  int b = rb >> 5, n0 = (rb & 31) * 32;
  int c0 = blockIdx.y * 64;
  int t = threadIdx.x;
  int w8 = t >> 6, lane = t & 63, g = lane >> 4, ql = lane & 15;
  int rg = w8 & 1, cp = w8 >> 1;
  const f32x4 zf = {0.f, 0.f, 0.f, 0.f};
  f32x4 acc[2] = {zf, zf};
  int cr = t >> 2, nq = (t & 3) * 8;
  int wr = t >> 2, wk = (t & 3) * 16;
  for (int k0 = 0; k0 < KD; k0 += 64) {
    __syncthreads();
    {
      int k = k0 + cr;
      const float* src = (inB != nullptr && k >= 256)
                             ? inB + ((long)(b * 256 + k - 256)) * 1024
                             : inA + ((long)(b * 256 + k)) * 1024;
      float w0 = dww[k * 3], w1 = dww[k * 3 + 1], w2 = dww[k * 3 + 2], bv = dwb[k];
#pragma unroll
      for (int j = 0; j < 2; ++j) {
        int nb4 = n0 + nq + 4 * j;
        float4 v = *(const float4*)&src[nb4];
        float vm1 = (nb4 > 0) ? src[nb4 - 1] : 0.f;
        float vp4 = (nb4 + 4 < 1024) ? src[nb4 + 4] : 0.f;
        xa[nq + 4 * j + 0][cr] = f2b(bv + w0 * vm1 + w1 * v.x + w2 * v.y);
        xa[nq + 4 * j + 1][cr] = f2b(bv + w0 * v.x + w1 * v.y + w2 * v.z);
        xa[nq + 4 * j + 2][cr] = f2b(bv + w0 * v.y + w1 * v.z + w2 * v.w);
        xa[nq + 4 * j + 3][cr] = f2b(bv + w0 * v.z + w1 * v.w + w2 * vp4);
      }
    }
    const float* wsrc = w + (long)(c0 + wr) * KD + k0 + wk;
#pragma unroll
    for (int j = 0; j < 4; ++j) {
      float4 v = *(const float4*)(wsrc + 4 * j);
      ushort4v u = {f2b(v.x), f2b(v.y), f2b(v.z), f2b(v.w)};
      *(ushort4v*)&wb[wr][wk + 4 * j] = u;
    }
    __syncthreads();
#pragma unroll
    for (int ks = 0; ks < 2; ++ks) {
      bf16x8 a = *(const bf16x8*)&xa[rg * 16 + ql][ks * 32 + g * 8];
#pragma unroll
      for (int ct = 0; ct < 2; ++ct) {
        bf16x8 bfr = *(const bf16x8*)&wb[(cp * 2 + ct) * 16 + ql][ks * 32 + g * 8];
        acc[ct] = __builtin_amdgcn_mfma_f32_16x16x32_bf16(a, bfr, acc[ct], 0, 0, 0);
      }
    }
  }
#pragma unroll
  for (int ct = 0; ct < 2; ++ct) {
    int col = c0 + (cp * 2 + ct) * 16 + ql;
    float bv = bias[col];
    if (outCM) {
      long base = ((long)(b * 256 + col)) * 1024 + n0 + rg * 16 + g * 4;
      float4 r4 = *(const float4*)(residCM + base);
      float4 o = make_float4(acc[ct][0] + bv + r4.x, acc[ct][1] + bv + r4.y,
                             acc[ct][2] + bv + r4.z, acc[ct][3] + bv + r4.w);
      *(float4*)(outCM + base) = o;
    } else {
      int nbase = n0 + rg * 16 + g * 4;
      float4 r4 = *(const float4*)&residXCM[((long)(b * 256 + col)) * 1024 + nbase];
      float rv[4] = {r4.x, r4.y, r4.z, r4.w};
#pragma unroll
      for (int reg = 0; reg < 4; ++reg) {
        long row = (long)b * 1024 + nbase + reg;
        outRMb[row * 256 + col] = f2b(acc[ct][reg] + bv + rv[reg]);
      }
    }
  }
}

// ---------- K13: QKV GEMM — bf16 XM2 in, bf16 out ----------
__global__ __launch_bounds__(256) void k_gemm_qkv(const unsigned short* __restrict__ in,
                                                  const float* __restrict__ w,
                                                  const float* __restrict__ bias,
                                                  unsigned short* __restrict__ out) {
  __shared__ unsigned short xa[64][72];
  __shared__ unsigned short wb[64][72];
  int r0 = blockIdx.x * 64;
  int c0 = blockIdx.y * 64;
  int t = threadIdx.x;
  int wv = t >> 6, lane = t & 63, g = lane >> 4, ql = lane & 15;
  const f32x4 zf = {0.f, 0.f, 0.f, 0.f};
  f32x4 acc[4] = {zf, zf, zf, zf};
  int rr = t >> 2, kq = (t & 3) * 16;
  for (int k0 = 0; k0 < 256; k0 += 64) {
    __syncthreads();
    const unsigned short* xsrc = in + (long)(r0 + rr) * 256 + k0 + kq;
#pragma unroll
    for (int j = 0; j < 2; ++j)
      *(ushort8v*)&xa[rr][kq + 8 * j] = *(const ushort8v*)(xsrc + 8 * j);
    const float* wsrc = w + (long)(c0 + rr) * 256 + k0 + kq;
#pragma unroll
    for (int j = 0; j < 4; ++j) {
      float4 v = *(const float4*)(wsrc + 4 * j);
      ushort4v u = {f2b(v.x), f2b(v.y), f2b(v.z), f2b(v.w)};
      *(ushort4v*)&wb[rr][kq + 4 * j] = u;
    }
    __syncthreads();
#pragma unroll
    for (int ks = 0; ks < 2; ++ks) {
      bf16x8 a = *(const bf16x8*)&xa[wv * 16 + ql][ks * 32 + g * 8];
#pragma unroll
      for (int ct = 0; ct < 4; ++ct) {
        bf16x8 b = *(const bf16x8*)&wb[ct * 16 + ql][ks * 32 + g * 8];
        acc[ct] = __builtin_amdgcn_mfma_f32_16x16x32_bf16(a, b, acc[ct], 0, 0, 0);
      }
    }
  }
#pragma unroll
  for (int ct = 0; ct < 4; ++ct) {
    int col = c0 + ct * 16 + ql;
    float bv = bias[col];
#pragma unroll
    for (int reg = 0; reg < 4; ++reg) {
      long row = r0 + wv * 16 + g * 4 + reg;
      out[row * 768 + col] = f2b(acc[ct][reg] + bv);
    }
  }
}

// ---------- K15: attn-out GEMM (32-row tile) — bf16 in/out ----------
__global__ __launch_bounds__(256) void k_gemm_attnout(const unsigned short* __restrict__ inA,
                                                      const float* __restrict__ w,
                                                      const float* __restrict__ bias,
                                                      unsigned short* __restrict__ out) {
  __shared__ unsigned short xa[32][72];
  __shared__ unsigned short wb[64][72];
  int r0 = blockIdx.x * 32;
  int c0 = blockIdx.y * 64;
  int t = threadIdx.x;
  int w8 = t >> 6, lane = t & 63, g = lane >> 4, ql = lane & 15;
  int rg = w8 & 1, cp = w8 >> 1;
  const f32x4 zf = {0.f, 0.f, 0.f, 0.f};
  f32x4 acc[2] = {zf, zf};
  int ar = t >> 3, ak = (t & 7) * 8;
  int wr = t >> 2, wk = (t & 3) * 16;
  for (int k0 = 0; k0 < 256; k0 += 64) {
    __syncthreads();
    const unsigned short* xsrc = inA + (long)(r0 + ar) * 256 + k0 + ak;
    *(ushort8v*)&xa[ar][ak] = *(const ushort8v*)xsrc;
    const float* wsrc = w + (long)(c0 + wr) * 256 + k0 + wk;
#pragma unroll
    for (int j = 0; j < 4; ++j) {
      float4 v = *(const float4*)(wsrc + 4 * j);
      ushort4v u = {f2b(v.x), f2b(v.y), f2b(v.z), f2b(v.w)};
      *(ushort4v*)&wb[wr][wk + 4 * j] = u;
    }
    __syncthreads();
#pragma unroll
    for (int ks = 0; ks < 2; ++ks) {
      bf16x8 a = *(const bf16x8*)&xa[rg * 16 + ql][ks * 32 + g * 8];
#pragma unroll
      for (int ct = 0; ct < 2; ++ct) {
        bf16x8 b = *(const bf16x8*)&wb[(cp * 2 + ct) * 16 + ql][ks * 32 + g * 8];
        acc[ct] = __builtin_amdgcn_mfma_f32_16x16x32_bf16(a, b, acc[ct], 0, 0, 0);
      }
    }
  }
#pragma unroll
  for (int ct = 0; ct < 2; ++ct) {
    int col = c0 + (cp * 2 + ct) * 16 + ql;
    float bv = bias[col];
#pragma unroll
    for (int reg = 0; reg < 4; ++reg) {
      long row = r0 + rg * 16 + g * 4 + reg;
      out[row * 256 + col] = f2b(acc[ct][reg] + bv);
    }
  }
}

// ---------- K16: fc GEMM (32-row tile) with x_local row-conv fused ----------
__global__ __launch_bounds__(256) void k_gemm_fc(const unsigned short* __restrict__ XM2,
                                                 const unsigned short* __restrict__ XGL,
                                                 const float* __restrict__ lcw,
                                                 const float* __restrict__ lcb,
                                                 const float* __restrict__ w,
                                                 const float* __restrict__ bias,
                                                 float* __restrict__ out) {
  __shared__ unsigned short xa[32][72];
  __shared__ unsigned short wb[64][72];
  int r0 = blockIdx.x * 32;
  int c0 = blockIdx.y * 64;
  int t = threadIdx.x;
  int w8 = t >> 6, lane = t & 63, g = lane >> 4, ql = lane & 15;
  int rg = w8 & 1, cp = w8 >> 1;
  const f32x4 zf = {0.f, 0.f, 0.f, 0.f};
  f32x4 acc[2] = {zf, zf};
  int ar = t >> 3, ak = (t & 7) * 8;
  int wr = t >> 2, wk = (t & 3) * 16;
  for (int k0 = 0; k0 < 512; k0 += 64) {
    __syncthreads();
    int kk = k0 + ak;
    long row = r0 + ar;
    if (kk < 256) {
      int n = (int)(row & 1023);
      const unsigned short* pc = XM2 + row * 256 + kk;
      bool hm = n > 0, hp = n < 1023;
#pragma unroll
      for (int j = 0; j < 2; ++j) {
        ushort4v v4 = *(const ushort4v*)(pc + 4 * j);
        ushort4v zm = {0, 0, 0, 0};
        ushort4v vm4 = hm ? *(const ushort4v*)(pc - 256 + 4 * j) : zm;
        ushort4v vp4 = hp ? *(const ushort4v*)(pc + 256 + 4 * j) : zm;
        int c = kk + 4 * j;
#pragma unroll
        for (int e = 0; e < 4; ++e) {
          float vv = b2f(v4[e]);
          float vmv = hm ? b2f(vm4[e]) : 0.f;
          float vpv = hp ? b2f(vp4[e]) : 0.f;
          xa[ar][ak + 4 * j + e] = f2b(lcb[c + e] + lcw[(c + e) * 3] * vmv +
                                       lcw[(c + e) * 3 + 1] * vv +
                                       lcw[(c + e) * 3 + 2] * vpv);
        }
      }
    } else {
      const unsigned short* xsrc = XGL + row * 256 + (kk - 256);
      *(ushort8v*)&xa[ar][ak] = *(const ushort8v*)xsrc;
    }
    const float* wsrc = w + (long)(c0 + wr) * 512 + k0 + wk;
#pragma unroll
    for (int j = 0; j < 4; ++j) {
      float4 v = *(const float4*)(wsrc + 4 * j);
      ushort4v u = {f2b(v.x), f2b(v.y), f2b(v.z), f2b(v.w)};
      *(ushort4v*)&wb[wr][wk + 4 * j] = u;
    }
    __syncthreads();
#pragma unroll
    for (int ks = 0; ks < 2; ++ks) {
      bf16x8 a = *(const bf16x8*)&xa[rg * 16 + ql][ks * 32 + g * 8];
#pragma unroll
      for (int ct = 0; ct < 2; ++ct) {
        bf16x8 b = *(const bf16x8*)&wb[(cp * 2 + ct) * 16 + ql][ks * 32 + g * 8];
        acc[ct] = __builtin_amdgcn_mfma_f32_16x16x32_bf16(a, b, acc[ct], 0, 0, 0);
      }
    }
  }
#pragma unroll
  for (int ct = 0; ct < 2; ++ct) {
    int col = c0 + (cp * 2 + ct) * 16 + ql;
    float bv = bias[col];
#pragma unroll
    for (int reg = 0; reg < 4; ++reg) {
      long row = r0 + rg * 16 + g * 4 + reg;
      out[row * 256 + col] = acc[ct][reg] + bv;
    }
  }
}

// ---------- K14: MFMA bf16 flash attention (bf16 QKV input, bf16 O output) ----------
__global__ __launch_bounds__(256) void k_attn_mfma(const unsigned short* __restrict__ qkvb,
                                                   unsigned short* __restrict__ Ob) {
  __shared__ unsigned short K_lds[64 * 40];
  __shared__ unsigned short Vt_lds[32 * 72];
  __shared__ unsigned short P_lds[4][16 * 72];
  int bx = blockIdx.x;
  int bh = bx >> 4, qt = bx & 15;
  int b = bh >> 3, h = bh & 7;
  int t = threadIdx.x;
  int w = t >> 6, lane = t & 63;
  int g = lane >> 4, ql = lane & 15;
  const float qscale = 0.17677669529663687f * 1.44269504088896341f;  // 1/sqrt(32)*log2(e)

  bf16x8 q_frag = *(const bf16x8*)(qkvb + ((long)(b * N_ + qt * 64 + w * 16 + ql)) * 768 + h * HD_ + g * 8);
  float m = -1e30f, l = 0.f;
  f32x4 o_acc[2];
  const f32x4 zf = {0.f, 0.f, 0.f, 0.f};
  o_acc[0] = zf; o_acc[1] = zf;

  for (int kt = 0; kt < 16; ++kt) {
    __syncthreads();
    {
      int kr = t >> 2, d0 = (t & 3) * 8;
      const unsigned short* gp = qkvb + ((long)(b * N_ + kt * 64 + kr)) * 768 + 256 + h * HD_ + d0;
      ushort8v kv = *(const ushort8v*)gp;
      *(ushort8v*)&K_lds[kr * 40 + d0] = kv;
      ushort8v vv = *(const ushort8v*)(gp + 256);
#pragma unroll
      for (int i = 0; i < 8; ++i) Vt_lds[(d0 + i) * 72 + kr] = vv[i];
    }
    __syncthreads();
    f32x4 s_frag[4];
#pragma unroll
    for (int s = 0; s < 4; ++s) {
      bf16x8 k_frag = *(const bf16x8*)&K_lds[(s * 16 + ql) * 40 + g * 8];
      s_frag[s] = __builtin_amdgcn_mfma_f32_16x16x32_bf16(k_frag, q_frag, zf, 0, 0, 0);
    }
    float sv[16];
#pragma unroll
    for (int s = 0; s < 4; ++s)
#pragma unroll
      for (int r = 0; r < 4; ++r) sv[s * 4 + r] = s_frag[s][r] * qscale;
    float tmax = sv[0];
#pragma unroll
    for (int i = 1; i < 16; ++i) tmax = fmaxf(tmax, sv[i]);
    tmax = fmaxf(tmax, __shfl_xor(tmax, 16));
    tmax = fmaxf(tmax, __shfl_xor(tmax, 32));
    float mn = fmaxf(m, tmax);
    float corr = exp2f(m - mn);
    float psum = 0.f;
    unsigned short pb[16];
#pragma unroll
    for (int i = 0; i < 16; ++i) {
      float p = exp2f(sv[i] - mn);
      psum += p;
      pb[i] = f2b(p);
    }
    psum += __shfl_xor(psum, 16);
    psum += __shfl_xor(psum, 32);
    l = l * corr + psum;
    m = mn;
#pragma unroll
    for (int mt = 0; mt < 2; ++mt)
#pragma unroll
      for (int r = 0; r < 4; ++r) o_acc[mt][r] *= corr;
#pragma unroll
    for (int s = 0; s < 4; ++s) {
      ushort4v p4 = {pb[s * 4], pb[s * 4 + 1], pb[s * 4 + 2], pb[s * 4 + 3]};
      *(ushort4v*)&P_lds[w][ql * 72 + s * 16 + g * 4] = p4;
    }
#pragma unroll
    for (int c = 0; c < 2; ++c) {
      bf16x8 p_frag = *(const bf16x8*)&P_lds[w][ql * 72 + c * 32 + g * 8];
#pragma unroll
      for (int mt = 0; mt < 2; ++mt) {
        bf16x8 v_frag = *(const bf16x8*)&Vt_lds[(mt * 16 + ql) * 72 + c * 32 + g * 8];
        o_acc[mt] = __builtin_amdgcn_mfma_f32_16x16x32_bf16(v_frag, p_frag, o_acc[mt], 0, 0, 0);
      }
    }
  }
  float inv = 1.f / l;
  unsigned short* op = Ob + ((long)(b * N_ + qt * 64 + w * 16 + ql)) * C_ + h * HD_;
#pragma unroll
  for (int mt = 0; mt < 2; ++mt) {
    ushort4v o4 = {f2b(o_acc[mt][0] * inv), f2b(o_acc[mt][1] * inv),
                   f2b(o_acc[mt][2] * inv), f2b(o_acc[mt][3] * inv)};
    *(ushort4v*)(op + mt * 16 + g * 4) = o4;
  }
}

// ---------- K17: LN(lgn) + exact GELU -> (B,C,N), tiled coalesced ----------
__global__ __launch_bounds__(256) void k_lngelu(const float* __restrict__ XO,
                                                const float* __restrict__ lw,
                                                const float* __restrict__ lb,
                                                float* __restrict__ XI) {
  __shared__ float tile[256][17];
  __shared__ float redp[16][16][2];
  __shared__ float stats[16][2];
  int bx = blockIdx.x;
  int b = bx >> 6, n0 = (bx & 63) * 16;
  int c = threadIdx.x;
#pragma unroll
  for (int j = 0; j < 16; ++j)
    tile[c][j] = XO[((long)(b * N_ + n0 + j)) * C_ + c];
  __syncthreads();
  {
    int n = c & 15, g = c >> 4;
    float a = 0.f, q = 0.f;
#pragma unroll
    for (int i = 0; i < 16; ++i) {
      float v = tile[g * 16 + i][n];
      a += v; q += v * v;
    }
    redp[g][n][0] = a; redp[g][n][1] = q;
  }
  __syncthreads();
  if (c < 16) {
    float a = 0.f, q = 0.f;
#pragma unroll
    for (int g2 = 0; g2 < 16; ++g2) { a += redp[g2][c][0]; q += redp[g2][c][1]; }
    float mu = a * (1.f / C_);
    float rs = rsqrtf(q * (1.f / C_) - mu * mu + 1e-5f);
    stats[c][0] = mu; stats[c][1] = rs;
  }
  __syncthreads();
  float wv = lw[c], bv = lb[c];
  float o[16];
#pragma unroll
  for (int j = 0; j < 16; ++j) {
    float x = (tile[c][j] - stats[j][0]) * stats[j][1] * wv + bv;
    o[j] = 0.5f * x * (1.f + erff(x * 0.70710678118654752f));
  }
  float* dst = &XI[((long)(b * C_ + c)) * N_ + n0];
#pragma unroll
  for (int j4 = 0; j4 < 4; ++j4)
    *(float4*)(dst + j4 * 4) = make_float4(o[4 * j4], o[4 * j4 + 1], o[4 * j4 + 2], o[4 * j4 + 3]);
}

// ---------- K18+K19 fused: ln over (H,W) + depthwise 3x3 per (b,c) plane ----------
__global__ __launch_bounds__(256) void k_lnhw_dwc(const float* __restrict__ XIin,
                                                  const float* __restrict__ w,
                                                  const float* __restrict__ bias,
                                                  float* __restrict__ XD) {
  __shared__ float pl[32][33];
  __shared__ float red[8];
  long base = (long)blockIdx.x * 1024;
  int c = blockIdx.x & 255;
  int t = threadIdx.x;
  float4 v = *(const float4*)&XIin[base + t * 4];
  float a = v.x + v.y + v.z + v.w;
  float q = v.x * v.x + v.y * v.y + v.z * v.z + v.w * v.w;
  float2 s = blockReduce2(a, q, red);
  float mu = s.x * (1.f / 1024.f);
  float rs = rsqrtf(s.y * (1.f / 1024.f) - mu * mu + 1e-5f);
  int hh = t >> 3, w0 = (t & 7) * 4;
  pl[hh][w0 + 0] = (v.x - mu) * rs;
  pl[hh][w0 + 1] = (v.y - mu) * rs;
  pl[hh][w0 + 2] = (v.z - mu) * rs;
  pl[hh][w0 + 3] = (v.w - mu) * rs;
  __syncthreads();
  float wk[9];
#pragma unroll
  for (int i = 0; i < 9; ++i) wk[i] = w[c * 9 + i];
  float bv = bias[c];
  float o[4];
#pragma unroll
  for (int j = 0; j < 4; ++j) {
    int ww = w0 + j;
    float acc = bv;
#pragma unroll
    for (int kh = 0; kh < 3; ++kh) {
      int h2 = hh + kh - 1;
      if (h2 < 0 || h2 >= 32) continue;
#pragma unroll
      for (int kw = 0; kw < 3; ++kw) {
        int w2 = ww + kw - 1;
        if (w2 < 0 || w2 >= 32) continue;
        acc += wk[kh * 3 + kw] * pl[h2][w2];
      }
    }
    o[j] = acc;
  }
  *(float4*)&XD[base + t * 4] = make_float4(o[0], o[1], o[2], o[3]);
}

// ---------- K20: fused final LN + projection (cm 2-pass GEMM, direct (B,C,N) out) ----------
__global__ __launch_bounds__(256) void k_lnproj(const float* __restrict__ XD,
                                                const float* __restrict__ nw,
                                                const float* __restrict__ nbias,
                                                const float* __restrict__ w,
                                                const float* __restrict__ bias,
                                                float* __restrict__ out) {
  __shared__ unsigned short xa[64][72];
  __shared__ unsigned short wb[64][72];
  __shared__ float ps[4][64], pq[4][64];
  __shared__ float mu_s[64], rs_s[64];
  int rb = blockIdx.x;
  int b = rb >> 4, n0 = (rb & 15) * 64;
  int c0 = blockIdx.y * 64;
  int t = threadIdx.x;
  {
    int nl = t & 63, cq = t >> 6;
    const float* src = XD + ((long)(b * 256 + cq * 64)) * 1024 + n0 + nl;
    float s = 0.f, q = 0.f;
    for (int i = 0; i < 64; ++i) {
      float v = src[(long)i * 1024];
      s += v; q += v * v;
    }
    ps[cq][nl] = s; pq[cq][nl] = q;
  }
  __syncthreads();
  if (t < 64) {
    float s = ps[0][t] + ps[1][t] + ps[2][t] + ps[3][t];
    float q = pq[0][t] + pq[1][t] + pq[2][t] + pq[3][t];
    float mu = s * (1.f / 256.f);
    float rs = rsqrtf(q * (1.f / 256.f) - mu * mu + 1e-5f);
    mu_s[t] = mu; rs_s[t] = rs;
  }
  int wv = t >> 6, lane = t & 63, g = lane >> 4, ql = lane & 15;
  const f32x4 zf = {0.f, 0.f, 0.f, 0.f};
  f32x4 acc[4] = {zf, zf, zf, zf};
  int rr = t >> 2, kq = (t & 3) * 16;
  for (int k0 = 0; k0 < 256; k0 += 64) {
    __syncthreads();
    {
      int ch = k0 + rr;
      const float* src = XD + ((long)(b * 256 + ch)) * 1024 + n0 + kq;
      float wv_ = nw[ch], bv_ = nbias[ch];
#pragma unroll
      for (int j = 0; j < 4; ++j) {
        float4 v = *(const float4*)(src + 4 * j);
        int n = kq + 4 * j;
        xa[n + 0][rr] = f2b((v.x - mu_s[n + 0]) * rs_s[n + 0] * wv_ + bv_);
        xa[n + 1][rr] = f2b((v.y - mu_s[n + 1]) * rs_s[n + 1] * wv_ + bv_);
        xa[n + 2][rr] = f2b((v.z - mu_s[n + 2]) * rs_s[n + 2] * wv_ + bv_);
        xa[n + 3][rr] = f2b((v.w - mu_s[n + 3]) * rs_s[n + 3] * wv_ + bv_);
      }
      const float* wsrc = w + (long)(c0 + rr) * 256 + k0 + kq;
#pragma unroll
      for (int j = 0; j < 4; ++j) {
        float4 v = *(const float4*)(wsrc + 4 * j);
        ushort4v u = {f2b(v.x), f2b(v.y), f2b(v.z), f2b(v.w)};
        *(ushort4v*)&wb[rr][kq + 4 * j] = u;
      }
    }
    __syncthreads();
#pragma unroll
    for (int ks = 0; ks < 2; ++ks) {
      bf16x8 a = *(const bf16x8*)&xa[wv * 16 + ql][ks * 32 + g * 8];
#pragma unroll
      for (int ct = 0; ct < 4; ++ct) {
        bf16x8 bfr = *(const bf16x8*)&wb[ct * 16 + ql][ks * 32 + g * 8];
        acc[ct] = __builtin_amdgcn_mfma_f32_16x16x32_bf16(a, bfr, acc[ct], 0, 0, 0);
      }
    }
  }
#pragma unroll
  for (int ct = 0; ct < 4; ++ct) {
    int col = c0 + ct * 16 + ql;
    float bv = bias[col];
    long basei = ((long)(b * 256 + col)) * 1024 + n0 + wv * 16 + g * 4;
    *(float4*)(out + basei) = make_float4(acc[ct][0] + bv, acc[ct][1] + bv,
                                          acc[ct][2] + bv, acc[ct][3] + bv);
  }
}

extern "C" void kernel_launch(void* const* d_in, const int* in_sizes, int n_in,
                              void* d_out, int out_size, void* d_ws, size_t ws_size,
                              hipStream_t stream) {
  const float* x        = (const float*)d_in[0];
  const float* norm_w   = (const float*)d_in[1];
  const float* norm_b   = (const float*)d_in[2];
  const float* skip     = (const float*)d_in[3];
  const float* m_inw    = (const float*)d_in[4];
  const float* m_convw  = (const float*)d_in[5];
  const float* m_convb  = (const float*)d_in[6];
  const float* m_xpw    = (const float*)d_in[7];
  const float* m_dtw    = (const float*)d_in[8];
  const float* m_dtb    = (const float*)d_in[9];
  const float* m_alog   = (const float*)d_in[10];
  const float* m_d      = (const float*)d_in[11];
  const float* m_outw   = (const float*)d_in[12];
  const float* qdw_w    = (const float*)d_in[13];
  const float* qdw_b    = (const float*)d_in[14];
  const float* qpw_w    = (const float*)d_in[15];
  const float* qpw_b    = (const float*)d_in[16];
  const float* rdw_w    = (const float*)d_in[17];
  const float* rdw_b    = (const float*)d_in[18];
  const float* rpw_w    = (const float*)d_in[19];
  const float* rpw_b    = (const float*)d_in[20];
  const float* fdw_w    = (const float*)d_in[21];
  const float* fdw_b    = (const float*)d_in[22];
  const float* fpw_w    = (const float*)d_in[23];
  const float* fpw_b    = (const float*)d_in[24];
  const float* lc_w     = (const float*)d_in[25];
  const float* lc_b     = (const float*)d_in[26];
  const float* attn_inw = (const float*)d_in[27];
  const float* attn_inb = (const float*)d_in[28];
  const float* attn_outw= (const float*)d_in[29];
  const float* attn_outb= (const float*)d_in[30];
  const float* lgn_w    = (const float*)d_in[31];
  const float* lgn_b    = (const float*)d_in[32];
  const float* fc_w     = (const float*)d_in[33];
  const float* fc_b     = (const float*)d_in[34];
  const float* dwc_w    = (const float*)d_in[35];
  const float* dwc_b    = (const float*)d_in[36];
  const float* proj_w   = (const float*)d_in[37];
  const float* proj_b   = (const float*)d_in[38];
  float* out = (float*)d_out;

  float* ws = (float*)d_ws;
  const size_t F = 1048576;  // B*N*C
  float* XN  = ws + 1 * F;
  unsigned short* UB = (unsigned short*)(ws + 2 * F);
  float* Z   = ws + 4 * F;
  float* DT  = ws + 6 * F;
  float* BM  = ws + 8 * F;
  float* CM  = ws + 8 * F + F / 4;
  float* XMC = ws + 8 * F + F / 2;
  float* SC_APROD = ws + 8 * F + F / 2;
  float* SC_HEND  = ws + 9 * F;
  float* G   = ws + 0 * F;
  float* XG  = ws + 2 * F;
  float* RB  = ws + 4 * F;
  unsigned short* XM2B = (unsigned short*)(ws + 5 * F);
  unsigned short* QKVB = (unsigned short*)(ws + 1 * F);
  unsigned short* OB   = (unsigned short*)(ws + 4 * F);
  unsigned short* XGLB = (unsigned short*)(ws + 6 * F);
  float* XO  = ws + 7 * F;
  float* XI  = ws + 8 * F;
  float* XD  = ws + 0 * F;
  (void)ws_size; (void)in_sizes; (void)n_in; (void)out_size;

  k_ln_t2<<<256, 256, 0, stream>>>(x, norm_w, norm_b, XN);
  k_inproj_conv<<<dim3(64, 16), 256, 0, stream>>>(XN, m_inw, m_convw, m_convb, UB, Z);
  k_xdbc_scanA<<<256, 256, 0, stream>>>(UB, m_xpw, m_dtw, m_dtb, m_alog,
                                        DT, BM, CM, SC_APROD, SC_HEND);
  k_scanC<<<512, 256, 0, stream>>>(DT, UB, BM, CM, m_alog, m_d, SC_APROD, SC_HEND);
  k_outproj_mfma<<<dim3(128, 4), 256, 0, stream>>>(DT, Z, m_outw, XN, skip, XMC);
  k_gate<<<256, 256, 0, stream>>>(XMC, qdw_w, qdw_b, qpw_w, qpw_b, G);
  k_xg<<<256, 256, 0, stream>>>(XMC, G, XG);
  k_gemm_cm_dw<256><<<dim3(128, 4), 256, 0, stream>>>(XG, nullptr, rdw_w, rdw_b,
                                                      rpw_w, rpw_b, XG, nullptr, RB, nullptr);
  k_gemm_cm_dw<512><<<dim3(128, 4), 256, 0, stream>>>(x, RB, fdw_w, fdw_b,
                                                      fpw_w, fpw_b, nullptr, x, nullptr, XM2B);
  k_gemm_qkv<<<dim3(64, 12), 256, 0, stream>>>(XM2B, attn_inw, attn_inb, QKVB);
  k_attn_mfma<<<512, 256, 0, stream>>>(QKVB, OB);
  k_gemm_attnout<<<dim3(128, 4), 256, 0, stream>>>(OB, attn_outw, attn_outb, XGLB);
  k_gemm_fc<<<dim3(128, 4), 256, 0, stream>>>(XM2B, XGLB, lc_w, lc_b, fc_w, fc_b, XO);
  k_lngelu<<<256, 256, 0, stream>>>(XO, lgn_w, lgn_b, XI);
  k_lnhw_dwc<<<1024, 256, 0, stream>>>(XI, dwc_w, dwc_b, XD);
  k_lnproj<<<dim3(64, 4), 256, 0, stream>>>(XD, norm_w, norm_b, proj_w, proj_b, out);
}

// Round 19
// 189.809 us; speedup vs baseline: 1.0804x; 1.0173x over previous
//
#include <hip/hip_runtime.h>
#include <math.h>

// MambaLiteUNet — round 18: occupancy pass 2 — k_lnproj 32-n row-split (dim3(128,4)),
// k_xg 32-n tiles (512 blocks), k_gate 512x128. All 1-block/CU stragglers now >=2/CU.

namespace {
constexpr int NB_ = 4, DM_ = 64, DIN_ = 128, DS_ = 16, DTR_ = 4;
constexpr int C_ = 256, N_ = 1024, B_ = 4, HD_ = 32;
constexpr int NCH = 16, LCH = 64;          // scan: 16 time-chunks of 64
constexpr int NSTATE = 16 * 128 * 16;      // nbb * DIN * DS = 32768
}

typedef __attribute__((ext_vector_type(8))) short bf16x8;
typedef __attribute__((ext_vector_type(4))) float f32x4;
typedef __attribute__((ext_vector_type(8))) unsigned short ushort8v;
typedef __attribute__((ext_vector_type(4))) unsigned short ushort4v;

// ---------- helpers ----------
__device__ __forceinline__ unsigned short f2b(float f) {  // fp32 -> bf16 RNE
  unsigned int u = __float_as_uint(f);
  unsigned int r = u + 0x7FFFu + ((u >> 16) & 1u);
  return (unsigned short)(r >> 16);
}
__device__ __forceinline__ float b2f(unsigned short u) {
  return __uint_as_float(((unsigned int)u) << 16);
}

__device__ __forceinline__ float2 blockReduce2(float a, float b, float* red) {
#pragma unroll
  for (int m = 1; m < 64; m <<= 1) {
    a += __shfl_xor(a, m, 64);
    b += __shfl_xor(b, m, 64);
  }
  int w = threadIdx.x >> 6;
  if ((threadIdx.x & 63) == 0) { red[2 * w] = a; red[2 * w + 1] = b; }
  __syncthreads();
  float ra = red[0] + red[2] + red[4] + red[6];
  float rb = red[1] + red[3] + red[5] + red[7];
  return make_float2(ra, rb);
}

__device__ __forceinline__ float siluf(float x) { return x / (1.f + expf(-x)); }
__device__ __forceinline__ float sigmf(float x) { return 1.f / (1.f + expf(-x)); }
__device__ __forceinline__ float softplusf(float x) {
  return fmaxf(x, 0.f) + log1pf(expf(-fabsf(x)));
}

// ---------- K1: LN over C of (B,C,N) -> (B,N,C), coalesced LDS-tile ----------
__global__ __launch_bounds__(256) void k_ln_t2(const float* __restrict__ in,
                                               const float* __restrict__ w,
                                               const float* __restrict__ bias,
                                               float* __restrict__ out_ln) {
  __shared__ float tile[256][17];
  __shared__ float redp[16][16][2];
  __shared__ float stats[16][2];
  int bx = blockIdx.x;
  int b = bx >> 6, n0 = (bx & 63) * 16;
  int c = threadIdx.x;
  {
    const float* p = in + ((long)(b * C_ + c)) * N_ + n0;
#pragma unroll
    for (int j = 0; j < 16; ++j) tile[c][j] = p[j];
  }
  __syncthreads();
  {
    int n = c & 15, g = c >> 4;
    float a = 0.f, q = 0.f;
#pragma unroll
    for (int i = 0; i < 16; ++i) {
      float v = tile[g * 16 + i][n];
      a += v; q += v * v;
    }
    redp[g][n][0] = a; redp[g][n][1] = q;
  }
  __syncthreads();
  if (c < 16) {
    float a = 0.f, q = 0.f;
#pragma unroll
    for (int g2 = 0; g2 < 16; ++g2) { a += redp[g2][c][0]; q += redp[g2][c][1]; }
    float mu = a * (1.f / C_);
    float rs = rsqrtf(q * (1.f / C_) - mu * mu + 1e-5f);
    stats[c][0] = mu; stats[c][1] = rs;
  }
  __syncthreads();
  float wv = w[c], bv = bias[c];
#pragma unroll
  for (int j = 0; j < 16; ++j) {
    float v = tile[c][j];
    long o = ((long)(b * N_ + n0 + j)) * C_ + c;
    out_ln[o] = (v - stats[j][0]) * stats[j][1] * wv + bv;
  }
}

// ---------- K2: mamba in-proj (MFMA) with fused causal conv + silu; U out bf16 ----------
__global__ __launch_bounds__(256) void k_inproj_conv(const float* __restrict__ xn,
                                                     const float* __restrict__ inw,
                                                     const float* __restrict__ cw,
                                                     const float* __restrict__ cb,
                                                     unsigned short* __restrict__ U,
                                                     float* __restrict__ Z) {
  __shared__ unsigned short xa[64][72];
  __shared__ unsigned short wb[64][72];
  __shared__ float ut[67][65];
  int r0 = blockIdx.x * 64;
  int nb = blockIdx.y >> 2, q = blockIdx.y & 3, c0 = q * 64;
  int t = threadIdx.x;
  int wv = t >> 6, lane = t & 63, g = lane >> 4, ql = lane & 15;
  const f32x4 zf = {0.f, 0.f, 0.f, 0.f};
  f32x4 acc[4] = {zf, zf, zf, zf};
  int rr = t >> 2, kq = (t & 3) * 16;
  {
    const float* xsrc = xn + (long)(r0 + rr) * C_ + nb * 64 + kq;
#pragma unroll
    for (int j = 0; j < 4; ++j) {
      float4 v = *(const float4*)(xsrc + 4 * j);
      ushort4v u = {f2b(v.x), f2b(v.y), f2b(v.z), f2b(v.w)};
      *(ushort4v*)&xa[rr][kq + 4 * j] = u;
    }
    const float* wsrc = inw + ((long)nb * 256 + c0 + rr) * 64 + kq;
#pragma unroll
    for (int j = 0; j < 4; ++j) {
      float4 v = *(const float4*)(wsrc + 4 * j);
      ushort4v u = {f2b(v.x), f2b(v.y), f2b(v.z), f2b(v.w)};
      *(ushort4v*)&wb[rr][kq + 4 * j] = u;
    }
  }
  __syncthreads();
#pragma unroll
  for (int ks = 0; ks < 2; ++ks) {
    bf16x8 a = *(const bf16x8*)&xa[wv * 16 + ql][ks * 32 + g * 8];
#pragma unroll
    for (int ct = 0; ct < 4; ++ct) {
      bf16x8 b = *(const bf16x8*)&wb[ct * 16 + ql][ks * 32 + g * 8];
      acc[ct] = __builtin_amdgcn_mfma_f32_16x16x32_bf16(a, b, acc[ct], 0, 0, 0);
    }
  }
  if (q < 2) {
#pragma unroll
    for (int ct = 0; ct < 4; ++ct)
#pragma unroll
      for (int reg = 0; reg < 4; ++reg)
        ut[3 + wv * 16 + g * 4 + reg][ct * 16 + ql] = acc[ct][reg];
    if (t < 192) {
      int hr = t >> 6, lc = t & 63;
      float hv = 0.f;
      if ((r0 & 1023) != 0) {
        const float* xrow = xn + (long)(r0 - 3 + hr) * C_ + nb * 64;
        const float* wrow = inw + ((long)nb * 256 + c0 + lc) * 64;
#pragma unroll 8
        for (int k = 0; k < 64; ++k) hv += xrow[k] * wrow[k];
      }
      ut[hr][lc] = hv;
    }
    __syncthreads();
#pragma unroll
    for (int ct = 0; ct < 4; ++ct) {
      int lc = ct * 16 + ql;
      int d = c0 + lc;
      const float* cwp = cw + (nb * DIN_ + d) * 4;
      float w0 = cwp[0], w1 = cwp[1], w2 = cwp[2], w3 = cwp[3];
      float bv = cb[nb * DIN_ + d];
#pragma unroll
      for (int reg = 0; reg < 4; ++reg) {
        int lr = wv * 16 + g * 4 + reg;
        float a = bv + w3 * ut[3 + lr][lc] + w2 * ut[2 + lr][lc] +
                  w1 * ut[1 + lr][lc] + w0 * ut[lr][lc];
        long row = (long)nb * 4096 + r0 + lr;
        U[row * DIN_ + d] = f2b(siluf(a));
      }
    }
  } else {
#pragma unroll
    for (int ct = 0; ct < 4; ++ct) {
      int col = c0 - 128 + ct * 16 + ql;
#pragma unroll
      for (int reg = 0; reg < 4; ++reg) {
        long row = (long)nb * 4096 + r0 + wv * 16 + g * 4 + reg;
        Z[row * DIN_ + col] = acc[ct][reg];
      }
    }
  }
}

// ---------- K4: xdbc (MFMA, bf16 U in) + dt/Bm/Cm epilogue + fused scan phase A ----------
__global__ __launch_bounds__(256) void k_xdbc_scanA(const unsigned short* __restrict__ U,
                                                    const float* __restrict__ xpw,
                                                    const float* __restrict__ dtw,
                                                    const float* __restrict__ dtb,
                                                    const float* __restrict__ alog,
                                                    float* __restrict__ DT,
                                                    float* __restrict__ BMb,
                                                    float* __restrict__ CMb,
                                                    float* __restrict__ Aprod,
                                                    float* __restrict__ Hend) {
  __shared__ unsigned short xa[64][72];
  __shared__ unsigned short wb[48][72];
  __shared__ float xd_s[64][40];
  __shared__ float dtw_s[128][4];
  __shared__ float dtb_s[128];
  __shared__ float dt_s[64][132];
  __shared__ float u_s[64][132];
  __shared__ float bm_s[64][20];
  int t = threadIdx.x;
  long row0 = (long)blockIdx.x * 64;
  int nb = blockIdx.x >> 6;
  int nbb = blockIdx.x >> 4, chunk = blockIdx.x & 15;
  for (int i = t; i < 512; i += 256) dtw_s[i >> 2][i & 3] = dtw[nb * 512 + i];
  if (t < 128) dtb_s[t] = dtb[nb * DIN_ + t];
  int wv = t >> 6, lane = t & 63, g = lane >> 4, ql = lane & 15;
  const f32x4 zf = {0.f, 0.f, 0.f, 0.f};
  f32x4 acc[3] = {zf, zf, zf};
  int rr = t >> 2, kq = (t & 3) * 16;
  for (int k0 = 0; k0 < 128; k0 += 64) {
    __syncthreads();
    const unsigned short* xsrc = U + (row0 + rr) * DIN_ + k0 + kq;
#pragma unroll
    for (int j = 0; j < 2; ++j) {
      ushort8v u8 = *(const ushort8v*)(xsrc + 8 * j);
      *(ushort8v*)&xa[rr][kq + 8 * j] = u8;
#pragma unroll
      for (int e = 0; e < 8; ++e) u_s[rr][k0 + kq + 8 * j + e] = b2f(u8[e]);
    }
    if (rr < 48) {
      if (rr < 36) {
        const float* wsrc = xpw + (long)nb * 36 * 128 + rr * 128 + k0 + kq;
#pragma unroll
        for (int j = 0; j < 4; ++j) {
          float4 v = *(const float4*)(wsrc + 4 * j);
          ushort4v u = {f2b(v.x), f2b(v.y), f2b(v.z), f2b(v.w)};
          *(ushort4v*)&wb[rr][kq + 4 * j] = u;
        }
      } else {
        ushort4v z = {0, 0, 0, 0};
#pragma unroll
        for (int j = 0; j < 4; ++j) *(ushort4v*)&wb[rr][kq + 4 * j] = z;
      }
    }
    __syncthreads();
#pragma unroll
    for (int ks = 0; ks < 2; ++ks) {
      bf16x8 a = *(const bf16x8*)&xa[wv * 16 + ql][ks * 32 + g * 8];
#pragma unroll
      for (int ct = 0; ct < 3; ++ct) {
        bf16x8 b = *(const bf16x8*)&wb[ct * 16 + ql][ks * 32 + g * 8];
        acc[ct] = __builtin_amdgcn_mfma_f32_16x16x32_bf16(a, b, acc[ct], 0, 0, 0);
      }
    }
  }
#pragma unroll
  for (int ct = 0; ct < 3; ++ct) {
    int col = ct * 16 + ql;
    if (col < 36) {
#pragma unroll
      for (int reg = 0; reg < 4; ++reg)
        xd_s[wv * 16 + g * 4 + reg][col] = acc[ct][reg];
    }
  }
  __syncthreads();
  {
    int r = t >> 2, sq = (t & 3) * 4;
    float4 bm4 = make_float4(xd_s[r][4 + sq], xd_s[r][5 + sq],
                             xd_s[r][6 + sq], xd_s[r][7 + sq]);
    *(float4*)&BMb[(row0 + r) * DS_ + sq] = bm4;
    *(float4*)&bm_s[r][sq] = bm4;
    float4 cm4 = make_float4(xd_s[r][20 + sq], xd_s[r][21 + sq],
                             xd_s[r][22 + sq], xd_s[r][23 + sq]);
    *(float4*)&CMb[(row0 + r) * DS_ + sq] = cm4;
  }
  {
    int r = t >> 2, dg = t & 3;
    float x0 = xd_s[r][0], x1 = xd_s[r][1], x2 = xd_s[r][2], x3 = xd_s[r][3];
    float* dst = DT + (row0 + r) * DIN_ + dg * 32;
#pragma unroll
    for (int j = 0; j < 8; ++j) {
      float o[4];
#pragma unroll
      for (int e = 0; e < 4; ++e) {
        int d = dg * 32 + j * 4 + e;
        float a = dtb_s[d] + x0 * dtw_s[d][0] + x1 * dtw_s[d][1] +
                  x2 * dtw_s[d][2] + x3 * dtw_s[d][3];
        o[e] = softplusf(a);
      }
      float4 o4 = make_float4(o[0], o[1], o[2], o[3]);
      *(float4*)(dst + j * 4) = o4;
      *(float4*)&dt_s[r][dg * 32 + j * 4] = o4;
    }
  }
  __syncthreads();
  {
    int dl = t >> 2, sg = t & 3;
#pragma unroll
    for (int dh = 0; dh < 2; ++dh) {
      int d = dh * 64 + dl;
      float A[4];
#pragma unroll
      for (int i = 0; i < 4; ++i)
        A[i] = -expf(alog[(nb * DIN_ + d) * DS_ + sg * 4 + i]);
      float h[4] = {0.f, 0.f, 0.f, 0.f};
      float ap[4] = {1.f, 1.f, 1.f, 1.f};
      for (int tt = 0; tt < LCH; ++tt) {
        float dtv = dt_s[tt][d];
        float uv  = u_s[tt][d];
        float cc = dtv * uv;
        float4 bm4 = *(const float4*)&bm_s[tt][sg * 4];
        float bmv[4] = {bm4.x, bm4.y, bm4.z, bm4.w};
#pragma unroll
        for (int i = 0; i < 4; ++i) {
          float dA = __expf(dtv * A[i]);
          h[i] = dA * h[i] + cc * bmv[i];
          ap[i] *= dA;
        }
      }
      long st = (long)chunk * NSTATE + ((nbb << 7) + d) * 16 + sg * 4;
      *(float4*)&Aprod[st] = make_float4(ap[0], ap[1], ap[2], ap[3]);
      *(float4*)&Hend[st]  = make_float4(h[0], h[1], h[2], h[3]);
    }
  }
}

// ---------- K5c: scan phase C — inline carry composition, emit y over DT ----------
__global__ __launch_bounds__(256) void k_scanC(float* __restrict__ DT,
                                               const unsigned short* __restrict__ U,
                                               const float* __restrict__ BMb,
                                               const float* __restrict__ CMb,
                                               const float* __restrict__ alog,
                                               const float* __restrict__ Dp,
                                               const float* __restrict__ Aprod,
                                               const float* __restrict__ Hend) {
  __shared__ float dt_s[64][64];
  __shared__ float u_s[64][64];
  __shared__ float bm_s[64][16];
  __shared__ float cm_s[64][16];
  int bx = blockIdx.x;
  int chunk = bx >> 5, rem = bx & 31, nbb = rem >> 1, dh = rem & 1;
  int nb = nbb >> 2;
  int t = threadIdx.x;
  int dl = t >> 2, sg = t & 3;
  int d = dh * 64 + dl;
  long base = (long)nbb * N_ + chunk * LCH;
#pragma unroll
  for (int j = 0; j < 4; ++j) {
    int f = t + 256 * j;
    int tt = f >> 4, dq = (f & 15) * 4;
    long src = (base + tt) * DIN_ + dh * 64 + dq;
    *(float4*)&dt_s[tt][dq] = *(const float4*)&DT[src];
    ushort4v u4 = *(const ushort4v*)&U[src];
    u_s[tt][dq + 0] = b2f(u4[0]);
    u_s[tt][dq + 1] = b2f(u4[1]);
    u_s[tt][dq + 2] = b2f(u4[2]);
    u_s[tt][dq + 3] = b2f(u4[3]);
  }
  {
    int tt = t >> 2, sq = (t & 3) * 4;
    *(float4*)&bm_s[tt][sq] = *(const float4*)&BMb[(base + tt) * DS_ + sq];
    *(float4*)&cm_s[tt][sq] = *(const float4*)&CMb[(base + tt) * DS_ + sq];
  }
  float A[4];
#pragma unroll
  for (int i = 0; i < 4; ++i)
    A[i] = -expf(alog[(nb * DIN_ + d) * DS_ + sg * 4 + i]);
  float Dv = Dp[nb * DIN_ + d];
  float h[4] = {0.f, 0.f, 0.f, 0.f};
  {
    long state4 = ((nbb << 7) + d) * 16 + sg * 4;
    for (int c = 0; c < chunk; ++c) {
      float4 a4 = *(const float4*)&Aprod[(long)c * NSTATE + state4];
      float4 e4 = *(const float4*)&Hend[(long)c * NSTATE + state4];
      h[0] = e4.x + a4.x * h[0];
      h[1] = e4.y + a4.y * h[1];
      h[2] = e4.z + a4.z * h[2];
      h[3] = e4.w + a4.w * h[3];
    }
  }
  __syncthreads();
  for (int tt = 0; tt < LCH; ++tt) {
    float dtv = dt_s[tt][dl];
    float uv  = u_s[tt][dl];
    float cc = dtv * uv;
    float4 bm4 = *(const float4*)&bm_s[tt][sg * 4];
    float4 cm4 = *(const float4*)&cm_s[tt][sg * 4];
    float bmv[4] = {bm4.x, bm4.y, bm4.z, bm4.w};
    float cmv[4] = {cm4.x, cm4.y, cm4.z, cm4.w};
    float p = 0.f;
#pragma unroll
    for (int i = 0; i < 4; ++i) {
      float dA = __expf(dtv * A[i]);
      h[i] = dA * h[i] + cc * bmv[i];
      p += h[i] * cmv[i];
    }
    p += __shfl_xor(p, 1, 64);
    p += __shfl_xor(p, 2, 64);
    if (sg == 0) DT[(base + tt) * DIN_ + d] = p + Dv * uv;
  }
}

// ---------- K6: out-proj (MFMA, 32-row tile): xm = (y*silu(z)) @ outw^T + skip*xn ----------
__global__ __launch_bounds__(256) void k_outproj_mfma(const float* __restrict__ Y,
                                                      const float* __restrict__ Zb,
                                                      const float* __restrict__ outw,
                                                      const float* __restrict__ xn,
                                                      const float* __restrict__ skip,
                                                      float* __restrict__ XMC) {
  __shared__ unsigned short xa[32][72];
  __shared__ unsigned short wb[64][72];
  int r0 = blockIdx.x * 32;
  int nb = blockIdx.y;
  int t = threadIdx.x;
  int w = t >> 6, lane = t & 63, g = lane >> 4, ql = lane & 15;
  int rg = w & 1, cp = w >> 1;
  const f32x4 zf = {0.f, 0.f, 0.f, 0.f};
  f32x4 acc[2] = {zf, zf};
  int ar = t >> 3, ak = (t & 7) * 8;
  int wr = t >> 2, wk = (t & 3) * 16;
  for (int k0 = 0; k0 < 128; k0 += 64) {
    __syncthreads();
    long row = (long)nb * 4096 + r0 + ar;
    const float* ysrc = Y + row * DIN_ + k0 + ak;
    const float* zsrc = Zb + row * DIN_ + k0 + ak;
#pragma unroll
    for (int j = 0; j < 2; ++j) {
      float4 yv = *(const float4*)(ysrc + 4 * j);
      float4 zv = *(const float4*)(zsrc + 4 * j);
      ushort4v u = {f2b(yv.x * siluf(zv.x)), f2b(yv.y * siluf(zv.y)),
                    f2b(yv.z * siluf(zv.z)), f2b(yv.w * siluf(zv.w))};
      *(ushort4v*)&xa[ar][ak + 4 * j] = u;
    }
    const float* wsrc = outw + ((long)nb * 64 + wr) * 128 + k0 + wk;
#pragma unroll
    for (int j = 0; j < 4; ++j) {
      float4 v = *(const float4*)(wsrc + 4 * j);
      ushort4v u = {f2b(v.x), f2b(v.y), f2b(v.z), f2b(v.w)};
      *(ushort4v*)&wb[wr][wk + 4 * j] = u;
    }
    __syncthreads();
#pragma unroll
    for (int ks = 0; ks < 2; ++ks) {
      bf16x8 a = *(const bf16x8*)&xa[rg * 16 + ql][ks * 32 + g * 8];
#pragma unroll
      for (int ct = 0; ct < 2; ++ct) {
        bf16x8 b = *(const bf16x8*)&wb[(cp * 2 + ct) * 16 + ql][ks * 32 + g * 8];
        acc[ct] = __builtin_amdgcn_mfma_f32_16x16x32_bf16(a, b, acc[ct], 0, 0, 0);
      }
    }
  }
  float sk = skip[0];
#pragma unroll
  for (int ct = 0; ct < 2; ++ct) {
    int col = (cp * 2 + ct) * 16 + ql;
#pragma unroll
    for (int reg = 0; reg < 4; ++reg) {
      int bn = r0 + rg * 16 + g * 4 + reg;
      long oc = (long)bn * C_ + nb * 64 + col;
      XMC[oc] = acc[ct][reg] + sk * xn[oc];
    }
  }
}

// ---------- K7: gate (512 blocks x 128 threads, 2 blocks/CU) ----------
__global__ __launch_bounds__(128) void k_gate(const float* __restrict__ XMC,
                                              const float* __restrict__ qdw_w,
                                              const float* __restrict__ qdw_b,
                                              const float* __restrict__ qpw_w,
                                              const float* __restrict__ qpw_b,
                                              float* __restrict__ G) {
  int t = threadIdx.x;
  int gid = (blockIdx.x * 128 + t) >> 4;     // b*N + n
  int cq = t & 3, p = (t >> 2) & 3;
  int b = gid >> 10, n = gid & 1023;
  float a = 0.f;
#pragma unroll
  for (int k = 0; k < 3; ++k) {
    int nn = n + k - 1;
    if (nn < 0 || nn >= N_) continue;
    const float* xr = XMC + ((long)b * N_ + nn) * C_ + p * 64 + cq * 16;
    const float* wr = qdw_w + (p * 64 + cq * 16) * 3 + k;
    float xv[16];
    *(float4*)&xv[0]  = *(const float4*)(xr);
    *(float4*)&xv[4]  = *(const float4*)(xr + 4);
    *(float4*)&xv[8]  = *(const float4*)(xr + 8);
    *(float4*)&xv[12] = *(const float4*)(xr + 12);
#pragma unroll
    for (int i = 0; i < 16; ++i) a += xv[i] * wr[i * 3];
  }
  a += __shfl_xor(a, 1, 64);
  a += __shfl_xor(a, 2, 64);
  float q1 = a + qdw_b[p];
  int lane = t & 63;
  float q1g[4];
#pragma unroll
  for (int pp = 0; pp < 4; ++pp) q1g[pp] = __shfl(q1, (lane & ~12) | (pp << 2), 64);
  int o = p;
  float r = qpw_b[o];
#pragma unroll
  for (int pp = 0; pp < 4; ++pp) r += qpw_w[o * 4 + pp] * q1g[pp];
  if (cq == 0) G[((long)b * 4 + o) * N_ + n] = sigmf(r);
}

// ---------- K8: xg (B,C,N) = g * xm — 32-n LDS tile transpose, 512 blocks ----------
__global__ __launch_bounds__(256) void k_xg(const float* __restrict__ XMC,
                                            const float* __restrict__ G,
                                            float* __restrict__ XG) {
  __shared__ float tile[64][33];
  int bx = blockIdx.x;
  int b = bx >> 7, ct = (bx >> 5) & 3, nt = bx & 31;
  int c0 = ct * 64, n0 = nt * 32;
  int t = threadIdx.x;
  {
    int cc = t & 63, nq = t >> 6;
#pragma unroll
    for (int j = 0; j < 8; ++j) {
      int nn = nq * 8 + j;
      tile[cc][nn] = XMC[((long)(b * N_ + n0 + nn)) * C_ + c0 + cc];
    }
  }
  __syncthreads();
  {
    int nl = t & 31, cq = t >> 5;
    float g = G[((long)(b * 4 + ct)) * N_ + n0 + nl];
#pragma unroll
    for (int j = 0; j < 8; ++j) {
      int cl = cq * 8 + j;
      XG[((long)(b * C_ + c0 + cl)) * N_ + n0 + nl] = g * tile[cl][nl];
    }
  }
}

// ---------- MFMA GEMM (32-n tile), channel-major, 3-tap dw conv fused ----------
// grid dim3(128, 4): b(4) x ntile(32), c0 = y*64.
template <int KD>
__global__ __launch_bounds__(256) void k_gemm_cm_dw(const float* __restrict__ inA,
                                                    const float* __restrict__ inB,
                                                    const float* __restrict__ dww,
                                                    const float* __restrict__ dwb,
                                                    const float* __restrict__ w,
                                                    const float* __restrict__ bias,
                                                    const float* __restrict__ residCM,
                                                    const float* __restrict__ residXCM,
                                                    float* __restrict__ outCM,
                                                    unsigned short* __restrict__ outRMb) {
  __shared__ unsigned short xa[32][72];  // [n][k]
  __shared__ unsigned short wb[64][72];  // [cout][k]
  int rb = blockIdx.x;
  int b = rb >> 5, n0 = (rb & 31) * 32;
  int c0 = blockIdx.y * 64;
  int t = threadIdx.x;
  int w8 = t >> 6, lane = t & 63, g = lane >> 4, ql = lane & 15;
  int rg = w8 & 1, cp = w8 >> 1;
  const f32x4 zf = {0.f, 0.f, 0.f, 0.f};
  f32x4 acc[2] = {zf, zf};
  int cr = t >> 2, nq = (t & 3) * 8;
  int wr = t >> 2, wk = (t & 3) * 16;
  for (int k0 = 0; k0 < KD; k0 += 64) {
    __syncthreads();
    {
      int k = k0 + cr;
      const float* src = (inB != nullptr && k >= 256)
                             ? inB + ((long)(b * 256 + k - 256)) * 1024
                             : inA + ((long)(b * 256 + k)) * 1024;
      float w0 = dww[k * 3], w1 = dww[k * 3 + 1], w2 = dww[k * 3 + 2], bv = dwb[k];
#pragma unroll
      for (int j = 0; j < 2; ++j) {
        int nb4 = n0 + nq + 4 * j;
        float4 v = *(const float4*)&src[nb4];
        float vm1 = (nb4 > 0) ? src[nb4 - 1] : 0.f;
        float vp4 = (nb4 + 4 < 1024) ? src[nb4 + 4] : 0.f;
        xa[nq + 4 * j + 0][cr] = f2b(bv + w0 * vm1 + w1 * v.x + w2 * v.y);
        xa[nq + 4 * j + 1][cr] = f2b(bv + w0 * v.x + w1 * v.y + w2 * v.z);
        xa[nq + 4 * j + 2][cr] = f2b(bv + w0 * v.y + w1 * v.z + w2 * v.w);
        xa[nq + 4 * j + 3][cr] = f2b(bv + w0 * v.z + w1 * v.w + w2 * vp4);
      }
    }
    const float* wsrc = w + (long)(c0 + wr) * KD + k0 + wk;
#pragma unroll
    for (int j = 0; j < 4; ++j) {
      float4 v = *(const float4*)(wsrc + 4 * j);
      ushort4v u = {f2b(v.x), f2b(v.y), f2b(v.z), f2b(v.w)};
      *(ushort4v*)&wb[wr][wk + 4 * j] = u;
    }
    __syncthreads();
#pragma unroll
    for (int ks = 0; ks < 2; ++ks) {
      bf16x8 a = *(const bf16x8*)&xa[rg * 16 + ql][ks * 32 + g * 8];
#pragma unroll
      for (int ct = 0; ct < 2; ++ct) {
        bf16x8 bfr = *(const bf16x8*)&wb[(cp * 2 + ct) * 16 + ql][ks * 32 + g * 8];
        acc[ct] = __builtin_amdgcn_mfma_f32_16x16x32_bf16(a, bfr, acc[ct], 0, 0, 0);
      }
    }
  }
#pragma unroll
  for (int ct = 0; ct < 2; ++ct) {
    int col = c0 + (cp * 2 + ct) * 16 + ql;
    float bv = bias[col];
    if (outCM) {
      long base = ((long)(b * 256 + col)) * 1024 + n0 + rg * 16 + g * 4;
      float4 r4 = *(const float4*)(residCM + base);
      float4 o = make_float4(acc[ct][0] + bv + r4.x, acc[ct][1] + bv + r4.y,
                             acc[ct][2] + bv + r4.z, acc[ct][3] + bv + r4.w);
      *(float4*)(outCM + base) = o;
    } else {
      int nbase = n0 + rg * 16 + g * 4;
      float4 r4 = *(const float4*)&residXCM[((long)(b * 256 + col)) * 1024 + nbase];
      float rv[4] = {r4.x, r4.y, r4.z, r4.w};
#pragma unroll
      for (int reg = 0; reg < 4; ++reg) {
        long row = (long)b * 1024 + nbase + reg;
        outRMb[row * 256 + col] = f2b(acc[ct][reg] + bv + rv[reg]);
      }
    }
  }
}

// ---------- K13: QKV GEMM — bf16 XM2 in, bf16 out ----------
__global__ __launch_bounds__(256) void k_gemm_qkv(const unsigned short* __restrict__ in,
                                                  const float* __restrict__ w,
                                                  const float* __restrict__ bias,
                                                  unsigned short* __restrict__ out) {
  __shared__ unsigned short xa[64][72];
  __shared__ unsigned short wb[64][72];
  int r0 = blockIdx.x * 64;
  int c0 = blockIdx.y * 64;
  int t = threadIdx.x;
  int wv = t >> 6, lane = t & 63, g = lane >> 4, ql = lane & 15;
  const f32x4 zf = {0.f, 0.f, 0.f, 0.f};
  f32x4 acc[4] = {zf, zf, zf, zf};
  int rr = t >> 2, kq = (t & 3) * 16;
  for (int k0 = 0; k0 < 256; k0 += 64) {
    __syncthreads();
    const unsigned short* xsrc = in + (long)(r0 + rr) * 256 + k0 + kq;
#pragma unroll
    for (int j = 0; j < 2; ++j)
      *(ushort8v*)&xa[rr][kq + 8 * j] = *(const ushort8v*)(xsrc + 8 * j);
    const float* wsrc = w + (long)(c0 + rr) * 256 + k0 + kq;
#pragma unroll
    for (int j = 0; j < 4; ++j) {
      float4 v = *(const float4*)(wsrc + 4 * j);
      ushort4v u = {f2b(v.x), f2b(v.y), f2b(v.z), f2b(v.w)};
      *(ushort4v*)&wb[rr][kq + 4 * j] = u;
    }
    __syncthreads();
#pragma unroll
    for (int ks = 0; ks < 2; ++ks) {
      bf16x8 a = *(const bf16x8*)&xa[wv * 16 + ql][ks * 32 + g * 8];
#pragma unroll
      for (int ct = 0; ct < 4; ++ct) {
        bf16x8 b = *(const bf16x8*)&wb[ct * 16 + ql][ks * 32 + g * 8];
        acc[ct] = __builtin_amdgcn_mfma_f32_16x16x32_bf16(a, b, acc[ct], 0, 0, 0);
      }
    }
  }
#pragma unroll
  for (int ct = 0; ct < 4; ++ct) {
    int col = c0 + ct * 16 + ql;
    float bv = bias[col];
#pragma unroll
    for (int reg = 0; reg < 4; ++reg) {
      long row = r0 + wv * 16 + g * 4 + reg;
      out[row * 768 + col] = f2b(acc[ct][reg] + bv);
    }
  }
}

// ---------- K15: attn-out GEMM (32-row tile) — bf16 in/out ----------
__global__ __launch_bounds__(256) void k_gemm_attnout(const unsigned short* __restrict__ inA,
                                                      const float* __restrict__ w,
                                                      const float* __restrict__ bias,
                                                      unsigned short* __restrict__ out) {
  __shared__ unsigned short xa[32][72];
  __shared__ unsigned short wb[64][72];
  int r0 = blockIdx.x * 32;
  int c0 = blockIdx.y * 64;
  int t = threadIdx.x;
  int w8 = t >> 6, lane = t & 63, g = lane >> 4, ql = lane & 15;
  int rg = w8 & 1, cp = w8 >> 1;
  const f32x4 zf = {0.f, 0.f, 0.f, 0.f};
  f32x4 acc[2] = {zf, zf};
  int ar = t >> 3, ak = (t & 7) * 8;
  int wr = t >> 2, wk = (t & 3) * 16;
  for (int k0 = 0; k0 < 256; k0 += 64) {
    __syncthreads();
    const unsigned short* xsrc = inA + (long)(r0 + ar) * 256 + k0 + ak;
    *(ushort8v*)&xa[ar][ak] = *(const ushort8v*)xsrc;
    const float* wsrc = w + (long)(c0 + wr) * 256 + k0 + wk;
#pragma unroll
    for (int j = 0; j < 4; ++j) {
      float4 v = *(const float4*)(wsrc + 4 * j);
      ushort4v u = {f2b(v.x), f2b(v.y), f2b(v.z), f2b(v.w)};
      *(ushort4v*)&wb[wr][wk + 4 * j] = u;
    }
    __syncthreads();
#pragma unroll
    for (int ks = 0; ks < 2; ++ks) {
      bf16x8 a = *(const bf16x8*)&xa[rg * 16 + ql][ks * 32 + g * 8];
#pragma unroll
      for (int ct = 0; ct < 2; ++ct) {
        bf16x8 b = *(const bf16x8*)&wb[(cp * 2 + ct) * 16 + ql][ks * 32 + g * 8];
        acc[ct] = __builtin_amdgcn_mfma_f32_16x16x32_bf16(a, b, acc[ct], 0, 0, 0);
      }
    }
  }
#pragma unroll
  for (int ct = 0; ct < 2; ++ct) {
    int col = c0 + (cp * 2 + ct) * 16 + ql;
    float bv = bias[col];
#pragma unroll
    for (int reg = 0; reg < 4; ++reg) {
      long row = r0 + rg * 16 + g * 4 + reg;
      out[row * 256 + col] = f2b(acc[ct][reg] + bv);
    }
  }
}

// ---------- K16: fc GEMM (32-row tile) with x_local row-conv fused ----------
__global__ __launch_bounds__(256) void k_gemm_fc(const unsigned short* __restrict__ XM2,
                                                 const unsigned short* __restrict__ XGL,
                                                 const float* __restrict__ lcw,
                                                 const float* __restrict__ lcb,
                                                 const float* __restrict__ w,
                                                 const float* __restrict__ bias,
                                                 float* __restrict__ out) {
  __shared__ unsigned short xa[32][72];
  __shared__ unsigned short wb[64][72];
  int r0 = blockIdx.x * 32;
  int c0 = blockIdx.y * 64;
  int t = threadIdx.x;
  int w8 = t >> 6, lane = t & 63, g = lane >> 4, ql = lane & 15;
  int rg = w8 & 1, cp = w8 >> 1;
  const f32x4 zf = {0.f, 0.f, 0.f, 0.f};
  f32x4 acc[2] = {zf, zf};
  int ar = t >> 3, ak = (t & 7) * 8;
  int wr = t >> 2, wk = (t & 3) * 16;
  for (int k0 = 0; k0 < 512; k0 += 64) {
    __syncthreads();
    int kk = k0 + ak;
    long row = r0 + ar;
    if (kk < 256) {
      int n = (int)(row & 1023);
      const unsigned short* pc = XM2 + row * 256 + kk;
      bool hm = n > 0, hp = n < 1023;
#pragma unroll
      for (int j = 0; j < 2; ++j) {
        ushort4v v4 = *(const ushort4v*)(pc + 4 * j);
        ushort4v zm = {0, 0, 0, 0};
        ushort4v vm4 = hm ? *(const ushort4v*)(pc - 256 + 4 * j) : zm;
        ushort4v vp4 = hp ? *(const ushort4v*)(pc + 256 + 4 * j) : zm;
        int c = kk + 4 * j;
#pragma unroll
        for (int e = 0; e < 4; ++e) {
          float vv = b2f(v4[e]);
          float vmv = hm ? b2f(vm4[e]) : 0.f;
          float vpv = hp ? b2f(vp4[e]) : 0.f;
          xa[ar][ak + 4 * j + e] = f2b(lcb[c + e] + lcw[(c + e) * 3] * vmv +
                                       lcw[(c + e) * 3 + 1] * vv +
                                       lcw[(c + e) * 3 + 2] * vpv);
        }
      }
    } else {
      const unsigned short* xsrc = XGL + row * 256 + (kk - 256);
      *(ushort8v*)&xa[ar][ak] = *(const ushort8v*)xsrc;
    }
    const float* wsrc = w + (long)(c0 + wr) * 512 + k0 + wk;
#pragma unroll
    for (int j = 0; j < 4; ++j) {
      float4 v = *(const float4*)(wsrc + 4 * j);
      ushort4v u = {f2b(v.x), f2b(v.y), f2b(v.z), f2b(v.w)};
      *(ushort4v*)&wb[wr][wk + 4 * j] = u;
    }
    __syncthreads();
#pragma unroll
    for (int ks = 0; ks < 2; ++ks) {
      bf16x8 a = *(const bf16x8*)&xa[rg * 16 + ql][ks * 32 + g * 8];
#pragma unroll
      for (int ct = 0; ct < 2; ++ct) {
        bf16x8 b = *(const bf16x8*)&wb[(cp * 2 + ct) * 16 + ql][ks * 32 + g * 8];
        acc[ct] = __builtin_amdgcn_mfma_f32_16x16x32_bf16(a, b, acc[ct], 0, 0, 0);
      }
    }
  }
#pragma unroll
  for (int ct = 0; ct < 2; ++ct) {
    int col = c0 + (cp * 2 + ct) * 16 + ql;
    float bv = bias[col];
#pragma unroll
    for (int reg = 0; reg < 4; ++reg) {
      long row = r0 + rg * 16 + g * 4 + reg;
      out[row * 256 + col] = acc[ct][reg] + bv;
    }
  }
}

// ---------- K14: MFMA bf16 flash attention (bf16 QKV input, bf16 O output) ----------
__global__ __launch_bounds__(256) void k_attn_mfma(const unsigned short* __restrict__ qkvb,
                                                   unsigned short* __restrict__ Ob) {
  __shared__ unsigned short K_lds[64 * 40];
  __shared__ unsigned short Vt_lds[32 * 72];
  __shared__ unsigned short P_lds[4][16 * 72];
  int bx = blockIdx.x;
  int bh = bx >> 4, qt = bx & 15;
  int b = bh >> 3, h = bh & 7;
  int t = threadIdx.x;
  int w = t >> 6, lane = t & 63;
  int g = lane >> 4, ql = lane & 15;
  const float qscale = 0.17677669529663687f * 1.44269504088896341f;  // 1/sqrt(32)*log2(e)

  bf16x8 q_frag = *(const bf16x8*)(qkvb + ((long)(b * N_ + qt * 64 + w * 16 + ql)) * 768 + h * HD_ + g * 8);
  float m = -1e30f, l = 0.f;
  f32x4 o_acc[2];
  const f32x4 zf = {0.f, 0.f, 0.f, 0.f};
  o_acc[0] = zf; o_acc[1] = zf;

  for (int kt = 0; kt < 16; ++kt) {
    __syncthreads();
    {
      int kr = t >> 2, d0 = (t & 3) * 8;
      const unsigned short* gp = qkvb + ((long)(b * N_ + kt * 64 + kr)) * 768 + 256 + h * HD_ + d0;
      ushort8v kv = *(const ushort8v*)gp;
      *(ushort8v*)&K_lds[kr * 40 + d0] = kv;
      ushort8v vv = *(const ushort8v*)(gp + 256);
#pragma unroll
      for (int i = 0; i < 8; ++i) Vt_lds[(d0 + i) * 72 + kr] = vv[i];
    }
    __syncthreads();
    f32x4 s_frag[4];
#pragma unroll
    for (int s = 0; s < 4; ++s) {
      bf16x8 k_frag = *(const bf16x8*)&K_lds[(s * 16 + ql) * 40 + g * 8];
      s_frag[s] = __builtin_amdgcn_mfma_f32_16x16x32_bf16(k_frag, q_frag, zf, 0, 0, 0);
    }
    float sv[16];
#pragma unroll
    for (int s = 0; s < 4; ++s)
#pragma unroll
      for (int r = 0; r < 4; ++r) sv[s * 4 + r] = s_frag[s][r] * qscale;
    float tmax = sv[0];
#pragma unroll
    for (int i = 1; i < 16; ++i) tmax = fmaxf(tmax, sv[i]);
    tmax = fmaxf(tmax, __shfl_xor(tmax, 16));
    tmax = fmaxf(tmax, __shfl_xor(tmax, 32));
    float mn = fmaxf(m, tmax);
    float corr = exp2f(m - mn);
    float psum = 0.f;
    unsigned short pb[16];
#pragma unroll
    for (int i = 0; i < 16; ++i) {
      float p = exp2f(sv[i] - mn);
      psum += p;
      pb[i] = f2b(p);
    }
    psum += __shfl_xor(psum, 16);
    psum += __shfl_xor(psum, 32);
    l = l * corr + psum;
    m = mn;
#pragma unroll
    for (int mt = 0; mt < 2; ++mt)
#pragma unroll
      for (int r = 0; r < 4; ++r) o_acc[mt][r] *= corr;
#pragma unroll
    for (int s = 0; s < 4; ++s) {
      ushort4v p4 = {pb[s * 4], pb[s * 4 + 1], pb[s * 4 + 2], pb[s * 4 + 3]};
      *(ushort4v*)&P_lds[w][ql * 72 + s * 16 + g * 4] = p4;
    }
#pragma unroll
    for (int c = 0; c < 2; ++c) {
      bf16x8 p_frag = *(const bf16x8*)&P_lds[w][ql * 72 + c * 32 + g * 8];
#pragma unroll
      for (int mt = 0; mt < 2; ++mt) {
        bf16x8 v_frag = *(const bf16x8*)&Vt_lds[(mt * 16 + ql) * 72 + c * 32 + g * 8];
        o_acc[mt] = __builtin_amdgcn_mfma_f32_16x16x32_bf16(v_frag, p_frag, o_acc[mt], 0, 0, 0);
      }
    }
  }
  float inv = 1.f / l;
  unsigned short* op = Ob + ((long)(b * N_ + qt * 64 + w * 16 + ql)) * C_ + h * HD_;
#pragma unroll
  for (int mt = 0; mt < 2; ++mt) {
    ushort4v o4 = {f2b(o_acc[mt][0] * inv), f2b(o_acc[mt][1] * inv),
                   f2b(o_acc[mt][2] * inv), f2b(o_acc[mt][3] * inv)};
    *(ushort4v*)(op + mt * 16 + g * 4) = o4;
  }
}

// ---------- K17: LN(lgn) + exact GELU -> (B,C,N), tiled coalesced ----------
__global__ __launch_bounds__(256) void k_lngelu(const float* __restrict__ XO,
                                                const float* __restrict__ lw,
                                                const float* __restrict__ lb,
                                                float* __restrict__ XI) {
  __shared__ float tile[256][17];
  __shared__ float redp[16][16][2];
  __shared__ float stats[16][2];
  int bx = blockIdx.x;
  int b = bx >> 6, n0 = (bx & 63) * 16;
  int c = threadIdx.x;
#pragma unroll
  for (int j = 0; j < 16; ++j)
    tile[c][j] = XO[((long)(b * N_ + n0 + j)) * C_ + c];
  __syncthreads();
  {
    int n = c & 15, g = c >> 4;
    float a = 0.f, q = 0.f;
#pragma unroll
    for (int i = 0; i < 16; ++i) {
      float v = tile[g * 16 + i][n];
      a += v; q += v * v;
    }
    redp[g][n][0] = a; redp[g][n][1] = q;
  }
  __syncthreads();
  if (c < 16) {
    float a = 0.f, q = 0.f;
#pragma unroll
    for (int g2 = 0; g2 < 16; ++g2) { a += redp[g2][c][0]; q += redp[g2][c][1]; }
    float mu = a * (1.f / C_);
    float rs = rsqrtf(q * (1.f / C_) - mu * mu + 1e-5f);
    stats[c][0] = mu; stats[c][1] = rs;
  }
  __syncthreads();
  float wv = lw[c], bv = lb[c];
  float o[16];
#pragma unroll
  for (int j = 0; j < 16; ++j) {
    float x = (tile[c][j] - stats[j][0]) * stats[j][1] * wv + bv;
    o[j] = 0.5f * x * (1.f + erff(x * 0.70710678118654752f));
  }
  float* dst = &XI[((long)(b * C_ + c)) * N_ + n0];
#pragma unroll
  for (int j4 = 0; j4 < 4; ++j4)
    *(float4*)(dst + j4 * 4) = make_float4(o[4 * j4], o[4 * j4 + 1], o[4 * j4 + 2], o[4 * j4 + 3]);
}

// ---------- K18+K19 fused: ln over (H,W) + depthwise 3x3 per (b,c) plane ----------
__global__ __launch_bounds__(256) void k_lnhw_dwc(const float* __restrict__ XIin,
                                                  const float* __restrict__ w,
                                                  const float* __restrict__ bias,
                                                  float* __restrict__ XD) {
  __shared__ float pl[32][33];
  __shared__ float red[8];
  long base = (long)blockIdx.x * 1024;
  int c = blockIdx.x & 255;
  int t = threadIdx.x;
  float4 v = *(const float4*)&XIin[base + t * 4];
  float a = v.x + v.y + v.z + v.w;
  float q = v.x * v.x + v.y * v.y + v.z * v.z + v.w * v.w;
  float2 s = blockReduce2(a, q, red);
  float mu = s.x * (1.f / 1024.f);
  float rs = rsqrtf(s.y * (1.f / 1024.f) - mu * mu + 1e-5f);
  int hh = t >> 3, w0 = (t & 7) * 4;
  pl[hh][w0 + 0] = (v.x - mu) * rs;
  pl[hh][w0 + 1] = (v.y - mu) * rs;
  pl[hh][w0 + 2] = (v.z - mu) * rs;
  pl[hh][w0 + 3] = (v.w - mu) * rs;
  __syncthreads();
  float wk[9];
#pragma unroll
  for (int i = 0; i < 9; ++i) wk[i] = w[c * 9 + i];
  float bv = bias[c];
  float o[4];
#pragma unroll
  for (int j = 0; j < 4; ++j) {
    int ww = w0 + j;
    float acc = bv;
#pragma unroll
    for (int kh = 0; kh < 3; ++kh) {
      int h2 = hh + kh - 1;
      if (h2 < 0 || h2 >= 32) continue;
#pragma unroll
      for (int kw = 0; kw < 3; ++kw) {
        int w2 = ww + kw - 1;
        if (w2 < 0 || w2 >= 32) continue;
        acc += wk[kh * 3 + kw] * pl[h2][w2];
      }
    }
    o[j] = acc;
  }
  *(float4*)&XD[base + t * 4] = make_float4(o[0], o[1], o[2], o[3]);
}

// ---------- K20: fused final LN + projection (32-n row tiles, dim3(128,4)) ----------
__global__ __launch_bounds__(256) void k_lnproj(const float* __restrict__ XD,
                                                const float* __restrict__ nw,
                                                const float* __restrict__ nbias,
                                                const float* __restrict__ w,
                                                const float* __restrict__ bias,
                                                float* __restrict__ out) {
  __shared__ unsigned short xa[32][72];
  __shared__ unsigned short wb[64][72];
  __shared__ float ps[8][32], pq[8][32];
  __shared__ float mu_s[32], rs_s[32];
  int rb = blockIdx.x;
  int b = rb >> 5, n0 = (rb & 31) * 32;
  int c0 = blockIdx.y * 64;
  int t = threadIdx.x;
  {
    int nl = t & 31, cq = t >> 5;   // 8 groups x 32 channels
    const float* src = XD + ((long)(b * 256 + cq * 32)) * 1024 + n0 + nl;
    float s = 0.f, q = 0.f;
    for (int i = 0; i < 32; ++i) {
      float v = src[(long)i * 1024];
      s += v; q += v * v;
    }
    ps[cq][nl] = s; pq[cq][nl] = q;
  }
  __syncthreads();
  if (t < 32) {
    float s = 0.f, q = 0.f;
#pragma unroll
    for (int g2 = 0; g2 < 8; ++g2) { s += ps[g2][t]; q += pq[g2][t]; }
    float mu = s * (1.f / 256.f);
    float rs = rsqrtf(q * (1.f / 256.f) - mu * mu + 1e-5f);
    mu_s[t] = mu; rs_s[t] = rs;
  }
  int w8 = t >> 6, lane = t & 63, g = lane >> 4, ql = lane & 15;
  int rg = w8 & 1, cp = w8 >> 1;
  const f32x4 zf = {0.f, 0.f, 0.f, 0.f};
  f32x4 acc[2] = {zf, zf};
  int rr = t >> 2, nq = (t & 3) * 8;
  int wr = t >> 2, wk = (t & 3) * 16;
  for (int k0 = 0; k0 < 256; k0 += 64) {
    __syncthreads();
    {
      int ch = k0 + rr;
      const float* src = XD + ((long)(b * 256 + ch)) * 1024 + n0 + nq;
      float wv_ = nw[ch], bv_ = nbias[ch];
#pragma unroll
      for (int j = 0; j < 2; ++j) {
        float4 v = *(const float4*)(src + 4 * j);
        int n = nq + 4 * j;
        xa[n + 0][rr] = f2b((v.x - mu_s[n + 0]) * rs_s[n + 0] * wv_ + bv_);
        xa[n + 1][rr] = f2b((v.y - mu_s[n + 1]) * rs_s[n + 1] * wv_ + bv_);
        xa[n + 2][rr] = f2b((v.z - mu_s[n + 2]) * rs_s[n + 2] * wv_ + bv_);
        xa[n + 3][rr] = f2b((v.w - mu_s[n + 3]) * rs_s[n + 3] * wv_ + bv_);
      }
      const float* wsrc = w + (long)(c0 + wr) * 256 + k0 + wk;
#pragma unroll
      for (int j = 0; j < 4; ++j) {
        float4 v = *(const float4*)(wsrc + 4 * j);
        ushort4v u = {f2b(v.x), f2b(v.y), f2b(v.z), f2b(v.w)};
        *(ushort4v*)&wb[wr][wk + 4 * j] = u;
      }
    }
    __syncthreads();
#pragma unroll
    for (int ks = 0; ks < 2; ++ks) {
      bf16x8 a = *(const bf16x8*)&xa[rg * 16 + ql][ks * 32 + g * 8];
#pragma unroll
      for (int ct = 0; ct < 2; ++ct) {
        bf16x8 bfr = *(const bf16x8*)&wb[(cp * 2 + ct) * 16 + ql][ks * 32 + g * 8];
        acc[ct] = __builtin_amdgcn_mfma_f32_16x16x32_bf16(a, bfr, acc[ct], 0, 0, 0);
      }
    }
  }
#pragma unroll
  for (int ct = 0; ct < 2; ++ct) {
    int col = c0 + (cp * 2 + ct) * 16 + ql;
    float bv = bias[col];
    long basei = ((long)(b * 256 + col)) * 1024 + n0 + rg * 16 + g * 4;
    *(float4*)(out + basei) = make_float4(acc[ct][0] + bv, acc[ct][1] + bv,
                                          acc[ct][2] + bv, acc[ct][3] + bv);
  }
}

extern "C" void kernel_launch(void* const* d_in, const int* in_sizes, int n_in,
                              void* d_out, int out_size, void* d_ws, size_t ws_size,
                              hipStream_t stream) {
  const float* x        = (const float*)d_in[0];
  const float* norm_w   = (const float*)d_in[1];
  const float* norm_b   = (const float*)d_in[2];
  const float* skip     = (const float*)d_in[3];
  const float* m_inw    = (const float*)d_in[4];
  const float* m_convw  = (const float*)d_in[5];
  const float* m_convb  = (const float*)d_in[6];
  const float* m_xpw    = (const float*)d_in[7];
  const float* m_dtw    = (const float*)d_in[8];
  const float* m_dtb    = (const float*)d_in[9];
  const float* m_alog   = (const float*)d_in[10];
  const float* m_d      = (const float*)d_in[11];
  const float* m_outw   = (const float*)d_in[12];
  const float* qdw_w    = (const float*)d_in[13];
  const float* qdw_b    = (const float*)d_in[14];
  const float* qpw_w    = (const float*)d_in[15];
  const float* qpw_b    = (const float*)d_in[16];
  const float* rdw_w    = (const float*)d_in[17];
  const float* rdw_b    = (const float*)d_in[18];
  const float* rpw_w    = (const float*)d_in[19];
  const float* rpw_b    = (const float*)d_in[20];
  const float* fdw_w    = (const float*)d_in[21];
  const float* fdw_b    = (const float*)d_in[22];
  const float* fpw_w    = (const float*)d_in[23];
  const float* fpw_b    = (const float*)d_in[24];
  const float* lc_w     = (const float*)d_in[25];
  const float* lc_b     = (const float*)d_in[26];
  const float* attn_inw = (const float*)d_in[27];
  const float* attn_inb = (const float*)d_in[28];
  const float* attn_outw= (const float*)d_in[29];
  const float* attn_outb= (const float*)d_in[30];
  const float* lgn_w    = (const float*)d_in[31];
  const float* lgn_b    = (const float*)d_in[32];
  const float* fc_w     = (const float*)d_in[33];
  const float* fc_b     = (const float*)d_in[34];
  const float* dwc_w    = (const float*)d_in[35];
  const float* dwc_b    = (const float*)d_in[36];
  const float* proj_w   = (const float*)d_in[37];
  const float* proj_b   = (const float*)d_in[38];
  float* out = (float*)d_out;

  float* ws = (float*)d_ws;
  const size_t F = 1048576;  // B*N*C
  float* XN  = ws + 1 * F;
  unsigned short* UB = (unsigned short*)(ws + 2 * F);
  float* Z   = ws + 4 * F;
  float* DT  = ws + 6 * F;
  float* BM  = ws + 8 * F;
  float* CM  = ws + 8 * F + F / 4;
  float* XMC = ws + 8 * F + F / 2;
  float* SC_APROD = ws + 8 * F + F / 2;
  float* SC_HEND  = ws + 9 * F;
  float* G   = ws + 0 * F;
  float* XG  = ws + 2 * F;
  float* RB  = ws + 4 * F;
  unsigned short* XM2B = (unsigned short*)(ws + 5 * F);
  unsigned short* QKVB = (unsigned short*)(ws + 1 * F);
  unsigned short* OB   = (unsigned short*)(ws + 4 * F);
  unsigned short* XGLB = (unsigned short*)(ws + 6 * F);
  float* XO  = ws + 7 * F;
  float* XI  = ws + 8 * F;
  float* XD  = ws + 0 * F;
  (void)ws_size; (void)in_sizes; (void)n_in; (void)out_size;

  k_ln_t2<<<256, 256, 0, stream>>>(x, norm_w, norm_b, XN);
  k_inproj_conv<<<dim3(64, 16), 256, 0, stream>>>(XN, m_inw, m_convw, m_convb, UB, Z);
  k_xdbc_scanA<<<256, 256, 0, stream>>>(UB, m_xpw, m_dtw, m_dtb, m_alog,
                                        DT, BM, CM, SC_APROD, SC_HEND);
  k_scanC<<<512, 256, 0, stream>>>(DT, UB, BM, CM, m_alog, m_d, SC_APROD, SC_HEND);
  k_outproj_mfma<<<dim3(128, 4), 256, 0, stream>>>(DT, Z, m_outw, XN, skip, XMC);
  k_gate<<<512, 128, 0, stream>>>(XMC, qdw_w, qdw_b, qpw_w, qpw_b, G);
  k_xg<<<512, 256, 0, stream>>>(XMC, G, XG);
  k_gemm_cm_dw<256><<<dim3(128, 4), 256, 0, stream>>>(XG, nullptr, rdw_w, rdw_b,
                                                      rpw_w, rpw_b, XG, nullptr, RB, nullptr);
  k_gemm_cm_dw<512><<<dim3(128, 4), 256, 0, stream>>>(x, RB, fdw_w, fdw_b,
                                                      fpw_w, fpw_b, nullptr, x, nullptr, XM2B);
  k_gemm_qkv<<<dim3(64, 12), 256, 0, stream>>>(XM2B, attn_inw, attn_inb, QKVB);
  k_attn_mfma<<<512, 256, 0, stream>>>(QKVB, OB);
  k_gemm_attnout<<<dim3(128, 4), 256, 0, stream>>>(OB, attn_outw, attn_outb, XGLB);
  k_gemm_fc<<<dim3(128, 4), 256, 0, stream>>>(XM2B, XGLB, lc_w, lc_b, fc_w, fc_b, XO);
  k_lngelu<<<256, 256, 0, stream>>>(XO, lgn_w, lgn_b, XI);
  k_lnhw_dwc<<<1024, 256, 0, stream>>>(XI, dwc_w, dwc_b, XD);
  k_lnproj<<<dim3(128, 4), 256, 0, stream>>>(XD, norm_w, norm_b, proj_w, proj_b, out);
}

// Round 20
// 189.255 us; speedup vs baseline: 1.0836x; 1.0029x over previous
//
#include <hip/hip_runtime.h>
#include <math.h>

// MambaLiteUNet — round 19: occupancy pass 3 — xdbc LDS diet (merge xa+u_s into
// one bf16 u_sb; 101->74KB -> 2 blocks/CU); k_ln_t2 / k_lngelu split to 8-n
// tiles (512 blocks, 2/CU).

namespace {
constexpr int NB_ = 4, DM_ = 64, DIN_ = 128, DS_ = 16, DTR_ = 4;
constexpr int C_ = 256, N_ = 1024, B_ = 4, HD_ = 32;
constexpr int NCH = 16, LCH = 64;          // scan: 16 time-chunks of 64
constexpr int NSTATE = 16 * 128 * 16;      // nbb * DIN * DS = 32768
}

typedef __attribute__((ext_vector_type(8))) short bf16x8;
typedef __attribute__((ext_vector_type(4))) float f32x4;
typedef __attribute__((ext_vector_type(8))) unsigned short ushort8v;
typedef __attribute__((ext_vector_type(4))) unsigned short ushort4v;

// ---------- helpers ----------
__device__ __forceinline__ unsigned short f2b(float f) {  // fp32 -> bf16 RNE
  unsigned int u = __float_as_uint(f);
  unsigned int r = u + 0x7FFFu + ((u >> 16) & 1u);
  return (unsigned short)(r >> 16);
}
__device__ __forceinline__ float b2f(unsigned short u) {
  return __uint_as_float(((unsigned int)u) << 16);
}

__device__ __forceinline__ float2 blockReduce2(float a, float b, float* red) {
#pragma unroll
  for (int m = 1; m < 64; m <<= 1) {
    a += __shfl_xor(a, m, 64);
    b += __shfl_xor(b, m, 64);
  }
  int w = threadIdx.x >> 6;
  if ((threadIdx.x & 63) == 0) { red[2 * w] = a; red[2 * w + 1] = b; }
  __syncthreads();
  float ra = red[0] + red[2] + red[4] + red[6];
  float rb = red[1] + red[3] + red[5] + red[7];
  return make_float2(ra, rb);
}

__device__ __forceinline__ float siluf(float x) { return x / (1.f + expf(-x)); }
__device__ __forceinline__ float sigmf(float x) { return 1.f / (1.f + expf(-x)); }
__device__ __forceinline__ float softplusf(float x) {
  return fmaxf(x, 0.f) + log1pf(expf(-fabsf(x)));
}

// ---------- K1: LN over C of (B,C,N) -> (B,N,C), 8-n tiles, 512 blocks ----------
__global__ __launch_bounds__(256) void k_ln_t2(const float* __restrict__ in,
                                               const float* __restrict__ w,
                                               const float* __restrict__ bias,
                                               float* __restrict__ out_ln) {
  __shared__ float tile[256][9];
  __shared__ float redp[32][8][2];
  __shared__ float stats[8][2];
  int bx = blockIdx.x;
  int b = bx >> 7, n0 = (bx & 127) * 8;
  int c = threadIdx.x;
  {
    const float* p = in + ((long)(b * C_ + c)) * N_ + n0;
#pragma unroll
    for (int j = 0; j < 8; ++j) tile[c][j] = p[j];
  }
  __syncthreads();
  {
    int n = c & 7, g = c >> 3;
    float a = 0.f, q = 0.f;
#pragma unroll
    for (int i = 0; i < 8; ++i) {
      float v = tile[g * 8 + i][n];
      a += v; q += v * v;
    }
    redp[g][n][0] = a; redp[g][n][1] = q;
  }
  __syncthreads();
  if (c < 8) {
    float a = 0.f, q = 0.f;
#pragma unroll
    for (int g2 = 0; g2 < 32; ++g2) { a += redp[g2][c][0]; q += redp[g2][c][1]; }
    float mu = a * (1.f / C_);
    float rs = rsqrtf(q * (1.f / C_) - mu * mu + 1e-5f);
    stats[c][0] = mu; stats[c][1] = rs;
  }
  __syncthreads();
  float wv = w[c], bv = bias[c];
#pragma unroll
  for (int j = 0; j < 8; ++j) {
    float v = tile[c][j];
    long o = ((long)(b * N_ + n0 + j)) * C_ + c;
    out_ln[o] = (v - stats[j][0]) * stats[j][1] * wv + bv;
  }
}

// ---------- K2: mamba in-proj (MFMA) with fused causal conv + silu; U out bf16 ----------
__global__ __launch_bounds__(256) void k_inproj_conv(const float* __restrict__ xn,
                                                     const float* __restrict__ inw,
                                                     const float* __restrict__ cw,
                                                     const float* __restrict__ cb,
                                                     unsigned short* __restrict__ U,
                                                     float* __restrict__ Z) {
  __shared__ unsigned short xa[64][72];
  __shared__ unsigned short wb[64][72];
  __shared__ float ut[67][65];
  int r0 = blockIdx.x * 64;
  int nb = blockIdx.y >> 2, q = blockIdx.y & 3, c0 = q * 64;
  int t = threadIdx.x;
  int wv = t >> 6, lane = t & 63, g = lane >> 4, ql = lane & 15;
  const f32x4 zf = {0.f, 0.f, 0.f, 0.f};
  f32x4 acc[4] = {zf, zf, zf, zf};
  int rr = t >> 2, kq = (t & 3) * 16;
  {
    const float* xsrc = xn + (long)(r0 + rr) * C_ + nb * 64 + kq;
#pragma unroll
    for (int j = 0; j < 4; ++j) {
      float4 v = *(const float4*)(xsrc + 4 * j);
      ushort4v u = {f2b(v.x), f2b(v.y), f2b(v.z), f2b(v.w)};
      *(ushort4v*)&xa[rr][kq + 4 * j] = u;
    }
    const float* wsrc = inw + ((long)nb * 256 + c0 + rr) * 64 + kq;
#pragma unroll
    for (int j = 0; j < 4; ++j) {
      float4 v = *(const float4*)(wsrc + 4 * j);
      ushort4v u = {f2b(v.x), f2b(v.y), f2b(v.z), f2b(v.w)};
      *(ushort4v*)&wb[rr][kq + 4 * j] = u;
    }
  }
  __syncthreads();
#pragma unroll
  for (int ks = 0; ks < 2; ++ks) {
    bf16x8 a = *(const bf16x8*)&xa[wv * 16 + ql][ks * 32 + g * 8];
#pragma unroll
    for (int ct = 0; ct < 4; ++ct) {
      bf16x8 b = *(const bf16x8*)&wb[ct * 16 + ql][ks * 32 + g * 8];
      acc[ct] = __builtin_amdgcn_mfma_f32_16x16x32_bf16(a, b, acc[ct], 0, 0, 0);
    }
  }
  if (q < 2) {
#pragma unroll
    for (int ct = 0; ct < 4; ++ct)
#pragma unroll
      for (int reg = 0; reg < 4; ++reg)
        ut[3 + wv * 16 + g * 4 + reg][ct * 16 + ql] = acc[ct][reg];
    if (t < 192) {
      int hr = t >> 6, lc = t & 63;
      float hv = 0.f;
      if ((r0 & 1023) != 0) {
        const float* xrow = xn + (long)(r0 - 3 + hr) * C_ + nb * 64;
        const float* wrow = inw + ((long)nb * 256 + c0 + lc) * 64;
#pragma unroll 8
        for (int k = 0; k < 64; ++k) hv += xrow[k] * wrow[k];
      }
      ut[hr][lc] = hv;
    }
    __syncthreads();
#pragma unroll
    for (int ct = 0; ct < 4; ++ct) {
      int lc = ct * 16 + ql;
      int d = c0 + lc;
      const float* cwp = cw + (nb * DIN_ + d) * 4;
      float w0 = cwp[0], w1 = cwp[1], w2 = cwp[2], w3 = cwp[3];
      float bv = cb[nb * DIN_ + d];
#pragma unroll
      for (int reg = 0; reg < 4; ++reg) {
        int lr = wv * 16 + g * 4 + reg;
        float a = bv + w3 * ut[3 + lr][lc] + w2 * ut[2 + lr][lc] +
                  w1 * ut[1 + lr][lc] + w0 * ut[lr][lc];
        long row = (long)nb * 4096 + r0 + lr;
        U[row * DIN_ + d] = f2b(siluf(a));
      }
    }
  } else {
#pragma unroll
    for (int ct = 0; ct < 4; ++ct) {
      int col = c0 - 128 + ct * 16 + ql;
#pragma unroll
      for (int reg = 0; reg < 4; ++reg) {
        long row = (long)nb * 4096 + r0 + wv * 16 + g * 4 + reg;
        Z[row * DIN_ + col] = acc[ct][reg];
      }
    }
  }
}

// ---------- K4: xdbc (MFMA, bf16 U in) + dt/Bm/Cm epilogue + fused scan phase A ----------
// LDS diet: single bf16 u_sb buffer serves both MFMA A-fragments and phase-A u reads.
__global__ __launch_bounds__(256) void k_xdbc_scanA(const unsigned short* __restrict__ U,
                                                    const float* __restrict__ xpw,
                                                    const float* __restrict__ dtw,
                                                    const float* __restrict__ dtb,
                                                    const float* __restrict__ alog,
                                                    float* __restrict__ DT,
                                                    float* __restrict__ BMb,
                                                    float* __restrict__ CMb,
                                                    float* __restrict__ Aprod,
                                                    float* __restrict__ Hend) {
  __shared__ unsigned short u_sb[64][136];   // bf16 U rows, full K=128 (+8 pad, rows 16B-aligned)
  __shared__ unsigned short wb[48][72];
  __shared__ float xd_s[64][40];
  __shared__ float dtw_s[128][4];
  __shared__ float dtb_s[128];
  __shared__ float dt_s[64][132];
  __shared__ float bm_s[64][20];
  int t = threadIdx.x;
  long row0 = (long)blockIdx.x * 64;
  int nb = blockIdx.x >> 6;
  int nbb = blockIdx.x >> 4, chunk = blockIdx.x & 15;
  for (int i = t; i < 512; i += 256) dtw_s[i >> 2][i & 3] = dtw[nb * 512 + i];
  if (t < 128) dtb_s[t] = dtb[nb * DIN_ + t];
  int wv = t >> 6, lane = t & 63, g = lane >> 4, ql = lane & 15;
  const f32x4 zf = {0.f, 0.f, 0.f, 0.f};
  f32x4 acc[3] = {zf, zf, zf};
  int rr = t >> 2, kq = (t & 3) * 16;
  for (int k0 = 0; k0 < 128; k0 += 64) {
    __syncthreads();
    const unsigned short* xsrc = U + (row0 + rr) * DIN_ + k0 + kq;
#pragma unroll
    for (int j = 0; j < 2; ++j)
      *(ushort8v*)&u_sb[rr][k0 + kq + 8 * j] = *(const ushort8v*)(xsrc + 8 * j);
    if (rr < 48) {
      if (rr < 36) {
        const float* wsrc = xpw + (long)nb * 36 * 128 + rr * 128 + k0 + kq;
#pragma unroll
        for (int j = 0; j < 4; ++j) {
          float4 v = *(const float4*)(wsrc + 4 * j);
          ushort4v u = {f2b(v.x), f2b(v.y), f2b(v.z), f2b(v.w)};
          *(ushort4v*)&wb[rr][kq + 4 * j] = u;
        }
      } else {
        ushort4v z = {0, 0, 0, 0};
#pragma unroll
        for (int j = 0; j < 4; ++j) *(ushort4v*)&wb[rr][kq + 4 * j] = z;
      }
    }
    __syncthreads();
#pragma unroll
    for (int ks = 0; ks < 2; ++ks) {
      bf16x8 a = *(const bf16x8*)&u_sb[wv * 16 + ql][k0 + ks * 32 + g * 8];
#pragma unroll
      for (int ct = 0; ct < 3; ++ct) {
        bf16x8 b = *(const bf16x8*)&wb[ct * 16 + ql][ks * 32 + g * 8];
        acc[ct] = __builtin_amdgcn_mfma_f32_16x16x32_bf16(a, b, acc[ct], 0, 0, 0);
      }
    }
  }
#pragma unroll
  for (int ct = 0; ct < 3; ++ct) {
    int col = ct * 16 + ql;
    if (col < 36) {
#pragma unroll
      for (int reg = 0; reg < 4; ++reg)
        xd_s[wv * 16 + g * 4 + reg][col] = acc[ct][reg];
    }
  }
  __syncthreads();
  {
    int r = t >> 2, sq = (t & 3) * 4;
    float4 bm4 = make_float4(xd_s[r][4 + sq], xd_s[r][5 + sq],
                             xd_s[r][6 + sq], xd_s[r][7 + sq]);
    *(float4*)&BMb[(row0 + r) * DS_ + sq] = bm4;
    *(float4*)&bm_s[r][sq] = bm4;
    float4 cm4 = make_float4(xd_s[r][20 + sq], xd_s[r][21 + sq],
                             xd_s[r][22 + sq], xd_s[r][23 + sq]);
    *(float4*)&CMb[(row0 + r) * DS_ + sq] = cm4;
  }
  {
    int r = t >> 2, dg = t & 3;
    float x0 = xd_s[r][0], x1 = xd_s[r][1], x2 = xd_s[r][2], x3 = xd_s[r][3];
    float* dst = DT + (row0 + r) * DIN_ + dg * 32;
#pragma unroll
    for (int j = 0; j < 8; ++j) {
      float o[4];
#pragma unroll
      for (int e = 0; e < 4; ++e) {
        int d = dg * 32 + j * 4 + e;
        float a = dtb_s[d] + x0 * dtw_s[d][0] + x1 * dtw_s[d][1] +
                  x2 * dtw_s[d][2] + x3 * dtw_s[d][3];
        o[e] = softplusf(a);
      }
      float4 o4 = make_float4(o[0], o[1], o[2], o[3]);
      *(float4*)(dst + j * 4) = o4;
      *(float4*)&dt_s[r][dg * 32 + j * 4] = o4;
    }
  }
  __syncthreads();
  {
    int dl = t >> 2, sg = t & 3;
#pragma unroll
    for (int dh = 0; dh < 2; ++dh) {
      int d = dh * 64 + dl;
      float A[4];
#pragma unroll
      for (int i = 0; i < 4; ++i)
        A[i] = -expf(alog[(nb * DIN_ + d) * DS_ + sg * 4 + i]);
      float h[4] = {0.f, 0.f, 0.f, 0.f};
      float ap[4] = {1.f, 1.f, 1.f, 1.f};
      for (int tt = 0; tt < LCH; ++tt) {
        float dtv = dt_s[tt][d];
        float uv  = b2f(u_sb[tt][d]);
        float cc = dtv * uv;
        float4 bm4 = *(const float4*)&bm_s[tt][sg * 4];
        float bmv[4] = {bm4.x, bm4.y, bm4.z, bm4.w};
#pragma unroll
        for (int i = 0; i < 4; ++i) {
          float dA = __expf(dtv * A[i]);
          h[i] = dA * h[i] + cc * bmv[i];
          ap[i] *= dA;
        }
      }
      long st = (long)chunk * NSTATE + ((nbb << 7) + d) * 16 + sg * 4;
      *(float4*)&Aprod[st] = make_float4(ap[0], ap[1], ap[2], ap[3]);
      *(float4*)&Hend[st]  = make_float4(h[0], h[1], h[2], h[3]);
    }
  }
}

// ---------- K5c: scan phase C — inline carry composition, emit y over DT ----------
__global__ __launch_bounds__(256) void k_scanC(float* __restrict__ DT,
                                               const unsigned short* __restrict__ U,
                                               const float* __restrict__ BMb,
                                               const float* __restrict__ CMb,
                                               const float* __restrict__ alog,
                                               const float* __restrict__ Dp,
                                               const float* __restrict__ Aprod,
                                               const float* __restrict__ Hend) {
  __shared__ float dt_s[64][64];
  __shared__ float u_s[64][64];
  __shared__ float bm_s[64][16];
  __shared__ float cm_s[64][16];
  int bx = blockIdx.x;
  int chunk = bx >> 5, rem = bx & 31, nbb = rem >> 1, dh = rem & 1;
  int nb = nbb >> 2;
  int t = threadIdx.x;
  int dl = t >> 2, sg = t & 3;
  int d = dh * 64 + dl;
  long base = (long)nbb * N_ + chunk * LCH;
#pragma unroll
  for (int j = 0; j < 4; ++j) {
    int f = t + 256 * j;
    int tt = f >> 4, dq = (f & 15) * 4;
    long src = (base + tt) * DIN_ + dh * 64 + dq;
    *(float4*)&dt_s[tt][dq] = *(const float4*)&DT[src];
    ushort4v u4 = *(const ushort4v*)&U[src];
    u_s[tt][dq + 0] = b2f(u4[0]);
    u_s[tt][dq + 1] = b2f(u4[1]);
    u_s[tt][dq + 2] = b2f(u4[2]);
    u_s[tt][dq + 3] = b2f(u4[3]);
  }
  {
    int tt = t >> 2, sq = (t & 3) * 4;
    *(float4*)&bm_s[tt][sq] = *(const float4*)&BMb[(base + tt) * DS_ + sq];
    *(float4*)&cm_s[tt][sq] = *(const float4*)&CMb[(base + tt) * DS_ + sq];
  }
  float A[4];
#pragma unroll
  for (int i = 0; i < 4; ++i)
    A[i] = -expf(alog[(nb * DIN_ + d) * DS_ + sg * 4 + i]);
  float Dv = Dp[nb * DIN_ + d];
  float h[4] = {0.f, 0.f, 0.f, 0.f};
  {
    long state4 = ((nbb << 7) + d) * 16 + sg * 4;
    for (int c = 0; c < chunk; ++c) {
      float4 a4 = *(const float4*)&Aprod[(long)c * NSTATE + state4];
      float4 e4 = *(const float4*)&Hend[(long)c * NSTATE + state4];
      h[0] = e4.x + a4.x * h[0];
      h[1] = e4.y + a4.y * h[1];
      h[2] = e4.z + a4.z * h[2];
      h[3] = e4.w + a4.w * h[3];
    }
  }
  __syncthreads();
  for (int tt = 0; tt < LCH; ++tt) {
    float dtv = dt_s[tt][dl];
    float uv  = u_s[tt][dl];
    float cc = dtv * uv;
    float4 bm4 = *(const float4*)&bm_s[tt][sg * 4];
    float4 cm4 = *(const float4*)&cm_s[tt][sg * 4];
    float bmv[4] = {bm4.x, bm4.y, bm4.z, bm4.w};
    float cmv[4] = {cm4.x, cm4.y, cm4.z, cm4.w};
    float p = 0.f;
#pragma unroll
    for (int i = 0; i < 4; ++i) {
      float dA = __expf(dtv * A[i]);
      h[i] = dA * h[i] + cc * bmv[i];
      p += h[i] * cmv[i];
    }
    p += __shfl_xor(p, 1, 64);
    p += __shfl_xor(p, 2, 64);
    if (sg == 0) DT[(base + tt) * DIN_ + d] = p + Dv * uv;
  }
}

// ---------- K6: out-proj (MFMA, 32-row tile): xm = (y*silu(z)) @ outw^T + skip*xn ----------
__global__ __launch_bounds__(256) void k_outproj_mfma(const float* __restrict__ Y,
                                                      const float* __restrict__ Zb,
                                                      const float* __restrict__ outw,
                                                      const float* __restrict__ xn,
                                                      const float* __restrict__ skip,
                                                      float* __restrict__ XMC) {
  __shared__ unsigned short xa[32][72];
  __shared__ unsigned short wb[64][72];
  int r0 = blockIdx.x * 32;
  int nb = blockIdx.y;
  int t = threadIdx.x;
  int w = t >> 6, lane = t & 63, g = lane >> 4, ql = lane & 15;
  int rg = w & 1, cp = w >> 1;
  const f32x4 zf = {0.f, 0.f, 0.f, 0.f};
  f32x4 acc[2] = {zf, zf};
  int ar = t >> 3, ak = (t & 7) * 8;
  int wr = t >> 2, wk = (t & 3) * 16;
  for (int k0 = 0; k0 < 128; k0 += 64) {
    __syncthreads();
    long row = (long)nb * 4096 + r0 + ar;
    const float* ysrc = Y + row * DIN_ + k0 + ak;
    const float* zsrc = Zb + row * DIN_ + k0 + ak;
#pragma unroll
    for (int j = 0; j < 2; ++j) {
      float4 yv = *(const float4*)(ysrc + 4 * j);
      float4 zv = *(const float4*)(zsrc + 4 * j);
      ushort4v u = {f2b(yv.x * siluf(zv.x)), f2b(yv.y * siluf(zv.y)),
                    f2b(yv.z * siluf(zv.z)), f2b(yv.w * siluf(zv.w))};
      *(ushort4v*)&xa[ar][ak + 4 * j] = u;
    }
    const float* wsrc = outw + ((long)nb * 64 + wr) * 128 + k0 + wk;
#pragma unroll
    for (int j = 0; j < 4; ++j) {
      float4 v = *(const float4*)(wsrc + 4 * j);
      ushort4v u = {f2b(v.x), f2b(v.y), f2b(v.z), f2b(v.w)};
      *(ushort4v*)&wb[wr][wk + 4 * j] = u;
    }
    __syncthreads();
#pragma unroll
    for (int ks = 0; ks < 2; ++ks) {
      bf16x8 a = *(const bf16x8*)&xa[rg * 16 + ql][ks * 32 + g * 8];
#pragma unroll
      for (int ct = 0; ct < 2; ++ct) {
        bf16x8 b = *(const bf16x8*)&wb[(cp * 2 + ct) * 16 + ql][ks * 32 + g * 8];
        acc[ct] = __builtin_amdgcn_mfma_f32_16x16x32_bf16(a, b, acc[ct], 0, 0, 0);
      }
    }
  }
  float sk = skip[0];
#pragma unroll
  for (int ct = 0; ct < 2; ++ct) {
    int col = (cp * 2 + ct) * 16 + ql;
#pragma unroll
    for (int reg = 0; reg < 4; ++reg) {
      int bn = r0 + rg * 16 + g * 4 + reg;
      long oc = (long)bn * C_ + nb * 64 + col;
      XMC[oc] = acc[ct][reg] + sk * xn[oc];
    }
  }
}

// ---------- K7: gate (512 blocks x 128 threads) ----------
__global__ __launch_bounds__(128) void k_gate(const float* __restrict__ XMC,
                                              const float* __restrict__ qdw_w,
                                              const float* __restrict__ qdw_b,
                                              const float* __restrict__ qpw_w,
                                              const float* __restrict__ qpw_b,
                                              float* __restrict__ G) {
  int t = threadIdx.x;
  int gid = (blockIdx.x * 128 + t) >> 4;     // b*N + n
  int cq = t & 3, p = (t >> 2) & 3;
  int b = gid >> 10, n = gid & 1023;
  float a = 0.f;
#pragma unroll
  for (int k = 0; k < 3; ++k) {
    int nn = n + k - 1;
    if (nn < 0 || nn >= N_) continue;
    const float* xr = XMC + ((long)b * N_ + nn) * C_ + p * 64 + cq * 16;
    const float* wr = qdw_w + (p * 64 + cq * 16) * 3 + k;
    float xv[16];
    *(float4*)&xv[0]  = *(const float4*)(xr);
    *(float4*)&xv[4]  = *(const float4*)(xr + 4);
    *(float4*)&xv[8]  = *(const float4*)(xr + 8);
    *(float4*)&xv[12] = *(const float4*)(xr + 12);
#pragma unroll
    for (int i = 0; i < 16; ++i) a += xv[i] * wr[i * 3];
  }
  a += __shfl_xor(a, 1, 64);
  a += __shfl_xor(a, 2, 64);
  float q1 = a + qdw_b[p];
  int lane = t & 63;
  float q1g[4];
#pragma unroll
  for (int pp = 0; pp < 4; ++pp) q1g[pp] = __shfl(q1, (lane & ~12) | (pp << 2), 64);
  int o = p;
  float r = qpw_b[o];
#pragma unroll
  for (int pp = 0; pp < 4; ++pp) r += qpw_w[o * 4 + pp] * q1g[pp];
  if (cq == 0) G[((long)b * 4 + o) * N_ + n] = sigmf(r);
}

// ---------- K8: xg (B,C,N) = g * xm — 32-n LDS tile transpose, 512 blocks ----------
__global__ __launch_bounds__(256) void k_xg(const float* __restrict__ XMC,
                                            const float* __restrict__ G,
                                            float* __restrict__ XG) {
  __shared__ float tile[64][33];
  int bx = blockIdx.x;
  int b = bx >> 7, ct = (bx >> 5) & 3, nt = bx & 31;
  int c0 = ct * 64, n0 = nt * 32;
  int t = threadIdx.x;
  {
    int cc = t & 63, nq = t >> 6;
#pragma unroll
    for (int j = 0; j < 8; ++j) {
      int nn = nq * 8 + j;
      tile[cc][nn] = XMC[((long)(b * N_ + n0 + nn)) * C_ + c0 + cc];
    }
  }
  __syncthreads();
  {
    int nl = t & 31, cq = t >> 5;
    float g = G[((long)(b * 4 + ct)) * N_ + n0 + nl];
#pragma unroll
    for (int j = 0; j < 8; ++j) {
      int cl = cq * 8 + j;
      XG[((long)(b * C_ + c0 + cl)) * N_ + n0 + nl] = g * tile[cl][nl];
    }
  }
}

// ---------- MFMA GEMM (32-n tile), channel-major, 3-tap dw conv fused ----------
template <int KD>
__global__ __launch_bounds__(256) void k_gemm_cm_dw(const float* __restrict__ inA,
                                                    const float* __restrict__ inB,
                                                    const float* __restrict__ dww,
                                                    const float* __restrict__ dwb,
                                                    const float* __restrict__ w,
                                                    const float* __restrict__ bias,
                                                    const float* __restrict__ residCM,
                                                    const float* __restrict__ residXCM,
                                                    float* __restrict__ outCM,
                                                    unsigned short* __restrict__ outRMb) {
  __shared__ unsigned short xa[32][72];  // [n][k]
  __shared__ unsigned short wb[64][72];  // [cout][k]
  int rb = blockIdx.x;
  int b = rb >> 5, n0 = (rb & 31) * 32;
  int c0 = blockIdx.y * 64;
  int t = threadIdx.x;
  int w8 = t >> 6, lane = t & 63, g = lane >> 4, ql = lane & 15;
  int rg = w8 & 1, cp = w8 >> 1;
  const f32x4 zf = {0.f, 0.f, 0.f, 0.f};
  f32x4 acc[2] = {zf, zf};
  int cr = t >> 2, nq = (t & 3) * 8;
  int wr = t >> 2, wk = (t & 3) * 16;
  for (int k0 = 0; k0 < KD; k0 += 64) {
    __syncthreads();
    {
      int k = k0 + cr;
      const float* src = (inB != nullptr && k >= 256)
                             ? inB + ((long)(b * 256 + k - 256)) * 1024
                             : inA + ((long)(b * 256 + k)) * 1024;
      float w0 = dww[k * 3], w1 = dww[k * 3 + 1], w2 = dww[k * 3 + 2], bv = dwb[k];
#pragma unroll
      for (int j = 0; j < 2; ++j) {
        int nb4 = n0 + nq + 4 * j;
        float4 v = *(const float4*)&src[nb4];
        float vm1 = (nb4 > 0) ? src[nb4 - 1] : 0.f;
        float vp4 = (nb4 + 4 < 1024) ? src[nb4 + 4] : 0.f;
        xa[nq + 4 * j + 0][cr] = f2b(bv + w0 * vm1 + w1 * v.x + w2 * v.y);
        xa[nq + 4 * j + 1][cr] = f2b(bv + w0 * v.x + w1 * v.y + w2 * v.z);
        xa[nq + 4 * j + 2][cr] = f2b(bv + w0 * v.y + w1 * v.z + w2 * v.w);
        xa[nq + 4 * j + 3][cr] = f2b(bv + w0 * v.z + w1 * v.w + w2 * vp4);
      }
    }
    const float* wsrc = w + (long)(c0 + wr) * KD + k0 + wk;
#pragma unroll
    for (int j = 0; j < 4; ++j) {
      float4 v = *(const float4*)(wsrc + 4 * j);
      ushort4v u = {f2b(v.x), f2b(v.y), f2b(v.z), f2b(v.w)};
      *(ushort4v*)&wb[wr][wk + 4 * j] = u;
    }
    __syncthreads();
#pragma unroll
    for (int ks = 0; ks < 2; ++ks) {
      bf16x8 a = *(const bf16x8*)&xa[rg * 16 + ql][ks * 32 + g * 8];
#pragma unroll
      for (int ct = 0; ct < 2; ++ct) {
        bf16x8 bfr = *(const bf16x8*)&wb[(cp * 2 + ct) * 16 + ql][ks * 32 + g * 8];
        acc[ct] = __builtin_amdgcn_mfma_f32_16x16x32_bf16(a, bfr, acc[ct], 0, 0, 0);
      }
    }
  }
#pragma unroll
  for (int ct = 0; ct < 2; ++ct) {
    int col = c0 + (cp * 2 + ct) * 16 + ql;
    float bv = bias[col];
    if (outCM) {
      long base = ((long)(b * 256 + col)) * 1024 + n0 + rg * 16 + g * 4;
      float4 r4 = *(const float4*)(residCM + base);
      float4 o = make_float4(acc[ct][0] + bv + r4.x, acc[ct][1] + bv + r4.y,
                             acc[ct][2] + bv + r4.z, acc[ct][3] + bv + r4.w);
      *(float4*)(outCM + base) = o;
    } else {
      int nbase = n0 + rg * 16 + g * 4;
      float4 r4 = *(const float4*)&residXCM[((long)(b * 256 + col)) * 1024 + nbase];
      float rv[4] = {r4.x, r4.y, r4.z, r4.w};
#pragma unroll
      for (int reg = 0; reg < 4; ++reg) {
        long row = (long)b * 1024 + nbase + reg;
        outRMb[row * 256 + col] = f2b(acc[ct][reg] + bv + rv[reg]);
      }
    }
  }
}

// ---------- K13: QKV GEMM — bf16 XM2 in, bf16 out ----------
__global__ __launch_bounds__(256) void k_gemm_qkv(const unsigned short* __restrict__ in,
                                                  const float* __restrict__ w,
                                                  const float* __restrict__ bias,
                                                  unsigned short* __restrict__ out) {
  __shared__ unsigned short xa[64][72];
  __shared__ unsigned short wb[64][72];
  int r0 = blockIdx.x * 64;
  int c0 = blockIdx.y * 64;
  int t = threadIdx.x;
  int wv = t >> 6, lane = t & 63, g = lane >> 4, ql = lane & 15;
  const f32x4 zf = {0.f, 0.f, 0.f, 0.f};
  f32x4 acc[4] = {zf, zf, zf, zf};
  int rr = t >> 2, kq = (t & 3) * 16;
  for (int k0 = 0; k0 < 256; k0 += 64) {
    __syncthreads();
    const unsigned short* xsrc = in + (long)(r0 + rr) * 256 + k0 + kq;
#pragma unroll
    for (int j = 0; j < 2; ++j)
      *(ushort8v*)&xa[rr][kq + 8 * j] = *(const ushort8v*)(xsrc + 8 * j);
    const float* wsrc = w + (long)(c0 + rr) * 256 + k0 + kq;
#pragma unroll
    for (int j = 0; j < 4; ++j) {
      float4 v = *(const float4*)(wsrc + 4 * j);
      ushort4v u = {f2b(v.x), f2b(v.y), f2b(v.z), f2b(v.w)};
      *(ushort4v*)&wb[rr][kq + 4 * j] = u;
    }
    __syncthreads();
#pragma unroll
    for (int ks = 0; ks < 2; ++ks) {
      bf16x8 a = *(const bf16x8*)&xa[wv * 16 + ql][ks * 32 + g * 8];
#pragma unroll
      for (int ct = 0; ct < 4; ++ct) {
        bf16x8 b = *(const bf16x8*)&wb[ct * 16 + ql][ks * 32 + g * 8];
        acc[ct] = __builtin_amdgcn_mfma_f32_16x16x32_bf16(a, b, acc[ct], 0, 0, 0);
      }
    }
  }
#pragma unroll
  for (int ct = 0; ct < 4; ++ct) {
    int col = c0 + ct * 16 + ql;
    float bv = bias[col];
#pragma unroll
    for (int reg = 0; reg < 4; ++reg) {
      long row = r0 + wv * 16 + g * 4 + reg;
      out[row * 768 + col] = f2b(acc[ct][reg] + bv);
    }
  }
}

// ---------- K15: attn-out GEMM (32-row tile) — bf16 in/out ----------
__global__ __launch_bounds__(256) void k_gemm_attnout(const unsigned short* __restrict__ inA,
                                                      const float* __restrict__ w,
                                                      const float* __restrict__ bias,
                                                      unsigned short* __restrict__ out) {
  __shared__ unsigned short xa[32][72];
  __shared__ unsigned short wb[64][72];
  int r0 = blockIdx.x * 32;
  int c0 = blockIdx.y * 64;
  int t = threadIdx.x;
  int w8 = t >> 6, lane = t & 63, g = lane >> 4, ql = lane & 15;
  int rg = w8 & 1, cp = w8 >> 1;
  const f32x4 zf = {0.f, 0.f, 0.f, 0.f};
  f32x4 acc[2] = {zf, zf};
  int ar = t >> 3, ak = (t & 7) * 8;
  int wr = t >> 2, wk = (t & 3) * 16;
  for (int k0 = 0; k0 < 256; k0 += 64) {
    __syncthreads();
    const unsigned short* xsrc = inA + (long)(r0 + ar) * 256 + k0 + ak;
    *(ushort8v*)&xa[ar][ak] = *(const ushort8v*)xsrc;
    const float* wsrc = w + (long)(c0 + wr) * 256 + k0 + wk;
#pragma unroll
    for (int j = 0; j < 4; ++j) {
      float4 v = *(const float4*)(wsrc + 4 * j);
      ushort4v u = {f2b(v.x), f2b(v.y), f2b(v.z), f2b(v.w)};
      *(ushort4v*)&wb[wr][wk + 4 * j] = u;
    }
    __syncthreads();
#pragma unroll
    for (int ks = 0; ks < 2; ++ks) {
      bf16x8 a = *(const bf16x8*)&xa[rg * 16 + ql][ks * 32 + g * 8];
#pragma unroll
      for (int ct = 0; ct < 2; ++ct) {
        bf16x8 b = *(const bf16x8*)&wb[(cp * 2 + ct) * 16 + ql][ks * 32 + g * 8];
        acc[ct] = __builtin_amdgcn_mfma_f32_16x16x32_bf16(a, b, acc[ct], 0, 0, 0);
      }
    }
  }
#pragma unroll
  for (int ct = 0; ct < 2; ++ct) {
    int col = c0 + (cp * 2 + ct) * 16 + ql;
    float bv = bias[col];
#pragma unroll
    for (int reg = 0; reg < 4; ++reg) {
      long row = r0 + rg * 16 + g * 4 + reg;
      out[row * 256 + col] = f2b(acc[ct][reg] + bv);
    }
  }
}

// ---------- K16: fc GEMM (32-row tile) with x_local row-conv fused ----------
__global__ __launch_bounds__(256) void k_gemm_fc(const unsigned short* __restrict__ XM2,
                                                 const unsigned short* __restrict__ XGL,
                                                 const float* __restrict__ lcw,
                                                 const float* __restrict__ lcb,
                                                 const float* __restrict__ w,
                                                 const float* __restrict__ bias,
                                                 float* __restrict__ out) {
  __shared__ unsigned short xa[32][72];
  __shared__ unsigned short wb[64][72];
  int r0 = blockIdx.x * 32;
  int c0 = blockIdx.y * 64;
  int t = threadIdx.x;
  int w8 = t >> 6, lane = t & 63, g = lane >> 4, ql = lane & 15;
  int rg = w8 & 1, cp = w8 >> 1;
  const f32x4 zf = {0.f, 0.f, 0.f, 0.f};
  f32x4 acc[2] = {zf, zf};
  int ar = t >> 3, ak = (t & 7) * 8;
  int wr = t >> 2, wk = (t & 3) * 16;
  for (int k0 = 0; k0 < 512; k0 += 64) {
    __syncthreads();
    int kk = k0 + ak;
    long row = r0 + ar;
    if (kk < 256) {
      int n = (int)(row & 1023);
      const unsigned short* pc = XM2 + row * 256 + kk;
      bool hm = n > 0, hp = n < 1023;
#pragma unroll
      for (int j = 0; j < 2; ++j) {
        ushort4v v4 = *(const ushort4v*)(pc + 4 * j);
        ushort4v zm = {0, 0, 0, 0};
        ushort4v vm4 = hm ? *(const ushort4v*)(pc - 256 + 4 * j) : zm;
        ushort4v vp4 = hp ? *(const ushort4v*)(pc + 256 + 4 * j) : zm;
        int c = kk + 4 * j;
#pragma unroll
        for (int e = 0; e < 4; ++e) {
          float vv = b2f(v4[e]);
          float vmv = hm ? b2f(vm4[e]) : 0.f;
          float vpv = hp ? b2f(vp4[e]) : 0.f;
          xa[ar][ak + 4 * j + e] = f2b(lcb[c + e] + lcw[(c + e) * 3] * vmv +
                                       lcw[(c + e) * 3 + 1] * vv +
                                       lcw[(c + e) * 3 + 2] * vpv);
        }
      }
    } else {
      const unsigned short* xsrc = XGL + row * 256 + (kk - 256);
      *(ushort8v*)&xa[ar][ak] = *(const ushort8v*)xsrc;
    }
    const float* wsrc = w + (long)(c0 + wr) * 512 + k0 + wk;
#pragma unroll
    for (int j = 0; j < 4; ++j) {
      float4 v = *(const float4*)(wsrc + 4 * j);
      ushort4v u = {f2b(v.x), f2b(v.y), f2b(v.z), f2b(v.w)};
      *(ushort4v*)&wb[wr][wk + 4 * j] = u;
    }
    __syncthreads();
#pragma unroll
    for (int ks = 0; ks < 2; ++ks) {
      bf16x8 a = *(const bf16x8*)&xa[rg * 16 + ql][ks * 32 + g * 8];
#pragma unroll
      for (int ct = 0; ct < 2; ++ct) {
        bf16x8 b = *(const bf16x8*)&wb[(cp * 2 + ct) * 16 + ql][ks * 32 + g * 8];
        acc[ct] = __builtin_amdgcn_mfma_f32_16x16x32_bf16(a, b, acc[ct], 0, 0, 0);
      }
    }
  }
#pragma unroll
  for (int ct = 0; ct < 2; ++ct) {
    int col = c0 + (cp * 2 + ct) * 16 + ql;
    float bv = bias[col];
#pragma unroll
    for (int reg = 0; reg < 4; ++reg) {
      long row = r0 + rg * 16 + g * 4 + reg;
      out[row * 256 + col] = acc[ct][reg] + bv;
    }
  }
}

// ---------- K14: MFMA bf16 flash attention (bf16 QKV input, bf16 O output) ----------
__global__ __launch_bounds__(256) void k_attn_mfma(const unsigned short* __restrict__ qkvb,
                                                   unsigned short* __restrict__ Ob) {
  __shared__ unsigned short K_lds[64 * 40];
  __shared__ unsigned short Vt_lds[32 * 72];
  __shared__ unsigned short P_lds[4][16 * 72];
  int bx = blockIdx.x;
  int bh = bx >> 4, qt = bx & 15;
  int b = bh >> 3, h = bh & 7;
  int t = threadIdx.x;
  int w = t >> 6, lane = t & 63;
  int g = lane >> 4, ql = lane & 15;
  const float qscale = 0.17677669529663687f * 1.44269504088896341f;  // 1/sqrt(32)*log2(e)

  bf16x8 q_frag = *(const bf16x8*)(qkvb + ((long)(b * N_ + qt * 64 + w * 16 + ql)) * 768 + h * HD_ + g * 8);
  float m = -1e30f, l = 0.f;
  f32x4 o_acc[2];
  const f32x4 zf = {0.f, 0.f, 0.f, 0.f};
  o_acc[0] = zf; o_acc[1] = zf;

  for (int kt = 0; kt < 16; ++kt) {
    __syncthreads();
    {
      int kr = t >> 2, d0 = (t & 3) * 8;
      const unsigned short* gp = qkvb + ((long)(b * N_ + kt * 64 + kr)) * 768 + 256 + h * HD_ + d0;
      ushort8v kv = *(const ushort8v*)gp;
      *(ushort8v*)&K_lds[kr * 40 + d0] = kv;
      ushort8v vv = *(const ushort8v*)(gp + 256);
#pragma unroll
      for (int i = 0; i < 8; ++i) Vt_lds[(d0 + i) * 72 + kr] = vv[i];
    }
    __syncthreads();
    f32x4 s_frag[4];
#pragma unroll
    for (int s = 0; s < 4; ++s) {
      bf16x8 k_frag = *(const bf16x8*)&K_lds[(s * 16 + ql) * 40 + g * 8];
      s_frag[s] = __builtin_amdgcn_mfma_f32_16x16x32_bf16(k_frag, q_frag, zf, 0, 0, 0);
    }
    float sv[16];
#pragma unroll
    for (int s = 0; s < 4; ++s)
#pragma unroll
      for (int r = 0; r < 4; ++r) sv[s * 4 + r] = s_frag[s][r] * qscale;
    float tmax = sv[0];
#pragma unroll
    for (int i = 1; i < 16; ++i) tmax = fmaxf(tmax, sv[i]);
    tmax = fmaxf(tmax, __shfl_xor(tmax, 16));
    tmax = fmaxf(tmax, __shfl_xor(tmax, 32));
    float mn = fmaxf(m, tmax);
    float corr = exp2f(m - mn);
    float psum = 0.f;
    unsigned short pb[16];
#pragma unroll
    for (int i = 0; i < 16; ++i) {
      float p = exp2f(sv[i] - mn);
      psum += p;
      pb[i] = f2b(p);
    }
    psum += __shfl_xor(psum, 16);
    psum += __shfl_xor(psum, 32);
    l = l * corr + psum;
    m = mn;
#pragma unroll
    for (int mt = 0; mt < 2; ++mt)
#pragma unroll
      for (int r = 0; r < 4; ++r) o_acc[mt][r] *= corr;
#pragma unroll
    for (int s = 0; s < 4; ++s) {
      ushort4v p4 = {pb[s * 4], pb[s * 4 + 1], pb[s * 4 + 2], pb[s * 4 + 3]};
      *(ushort4v*)&P_lds[w][ql * 72 + s * 16 + g * 4] = p4;
    }
#pragma unroll
    for (int c = 0; c < 2; ++c) {
      bf16x8 p_frag = *(const bf16x8*)&P_lds[w][ql * 72 + c * 32 + g * 8];
#pragma unroll
      for (int mt = 0; mt < 2; ++mt) {
        bf16x8 v_frag = *(const bf16x8*)&Vt_lds[(mt * 16 + ql) * 72 + c * 32 + g * 8];
        o_acc[mt] = __builtin_amdgcn_mfma_f32_16x16x32_bf16(v_frag, p_frag, o_acc[mt], 0, 0, 0);
      }
    }
  }
  float inv = 1.f / l;
  unsigned short* op = Ob + ((long)(b * N_ + qt * 64 + w * 16 + ql)) * C_ + h * HD_;
#pragma unroll
  for (int mt = 0; mt < 2; ++mt) {
    ushort4v o4 = {f2b(o_acc[mt][0] * inv), f2b(o_acc[mt][1] * inv),
                   f2b(o_acc[mt][2] * inv), f2b(o_acc[mt][3] * inv)};
    *(ushort4v*)(op + mt * 16 + g * 4) = o4;
  }
}

// ---------- K17: LN(lgn) + exact GELU -> (B,C,N), 8-n tiles, 512 blocks ----------
__global__ __launch_bounds__(256) void k_lngelu(const float* __restrict__ XO,
                                                const float* __restrict__ lw,
                                                const float* __restrict__ lb,
                                                float* __restrict__ XI) {
  __shared__ float tile[256][9];
  __shared__ float redp[32][8][2];
  __shared__ float stats[8][2];
  int bx = blockIdx.x;
  int b = bx >> 7, n0 = (bx & 127) * 8;
  int c = threadIdx.x;
#pragma unroll
  for (int j = 0; j < 8; ++j)
    tile[c][j] = XO[((long)(b * N_ + n0 + j)) * C_ + c];
  __syncthreads();
  {
    int n = c & 7, g = c >> 3;
    float a = 0.f, q = 0.f;
#pragma unroll
    for (int i = 0; i < 8; ++i) {
      float v = tile[g * 8 + i][n];
      a += v; q += v * v;
    }
    redp[g][n][0] = a; redp[g][n][1] = q;
  }
  __syncthreads();
  if (c < 8) {
    float a = 0.f, q = 0.f;
#pragma unroll
    for (int g2 = 0; g2 < 32; ++g2) { a += redp[g2][c][0]; q += redp[g2][c][1]; }
    float mu = a * (1.f / C_);
    float rs = rsqrtf(q * (1.f / C_) - mu * mu + 1e-5f);
    stats[c][0] = mu; stats[c][1] = rs;
  }
  __syncthreads();
  float wv = lw[c], bv = lb[c];
  float o[8];
#pragma unroll
  for (int j = 0; j < 8; ++j) {
    float x = (tile[c][j] - stats[j][0]) * stats[j][1] * wv + bv;
    o[j] = 0.5f * x * (1.f + erff(x * 0.70710678118654752f));
  }
  float* dst = &XI[((long)(b * C_ + c)) * N_ + n0];
#pragma unroll
  for (int j4 = 0; j4 < 2; ++j4)
    *(float4*)(dst + j4 * 4) = make_float4(o[4 * j4], o[4 * j4 + 1], o[4 * j4 + 2], o[4 * j4 + 3]);
}

// ---------- K18+K19 fused: ln over (H,W) + depthwise 3x3 per (b,c) plane ----------
__global__ __launch_bounds__(256) void k_lnhw_dwc(const float* __restrict__ XIin,
                                                  const float* __restrict__ w,
                                                  const float* __restrict__ bias,
                                                  float* __restrict__ XD) {
  __shared__ float pl[32][33];
  __shared__ float red[8];
  long base = (long)blockIdx.x * 1024;
  int c = blockIdx.x & 255;
  int t = threadIdx.x;
  float4 v = *(const float4*)&XIin[base + t * 4];
  float a = v.x + v.y + v.z + v.w;
  float q = v.x * v.x + v.y * v.y + v.z * v.z + v.w * v.w;
  float2 s = blockReduce2(a, q, red);
  float mu = s.x * (1.f / 1024.f);
  float rs = rsqrtf(s.y * (1.f / 1024.f) - mu * mu + 1e-5f);
  int hh = t >> 3, w0 = (t & 7) * 4;
  pl[hh][w0 + 0] = (v.x - mu) * rs;
  pl[hh][w0 + 1] = (v.y - mu) * rs;
  pl[hh][w0 + 2] = (v.z - mu) * rs;
  pl[hh][w0 + 3] = (v.w - mu) * rs;
  __syncthreads();
  float wk[9];
#pragma unroll
  for (int i = 0; i < 9; ++i) wk[i] = w[c * 9 + i];
  float bv = bias[c];
  float o[4];
#pragma unroll
  for (int j = 0; j < 4; ++j) {
    int ww = w0 + j;
    float acc = bv;
#pragma unroll
    for (int kh = 0; kh < 3; ++kh) {
      int h2 = hh + kh - 1;
      if (h2 < 0 || h2 >= 32) continue;
#pragma unroll
      for (int kw = 0; kw < 3; ++kw) {
        int w2 = ww + kw - 1;
        if (w2 < 0 || w2 >= 32) continue;
        acc += wk[kh * 3 + kw] * pl[h2][w2];
      }
    }
    o[j] = acc;
  }
  *(float4*)&XD[base + t * 4] = make_float4(o[0], o[1], o[2], o[3]);
}

// ---------- K20: fused final LN + projection (32-n row tiles, dim3(128,4)) ----------
__global__ __launch_bounds__(256) void k_lnproj(const float* __restrict__ XD,
                                                const float* __restrict__ nw,
                                                const float* __restrict__ nbias,
                                                const float* __restrict__ w,
                                                const float* __restrict__ bias,
                                                float* __restrict__ out) {
  __shared__ unsigned short xa[32][72];
  __shared__ unsigned short wb[64][72];
  __shared__ float ps[8][32], pq[8][32];
  __shared__ float mu_s[32], rs_s[32];
  int rb = blockIdx.x;
  int b = rb >> 5, n0 = (rb & 31) * 32;
  int c0 = blockIdx.y * 64;
  int t = threadIdx.x;
  {
    int nl = t & 31, cq = t >> 5;   // 8 groups x 32 channels
    const float* src = XD + ((long)(b * 256 + cq * 32)) * 1024 + n0 + nl;
    float s = 0.f, q = 0.f;
    for (int i = 0; i < 32; ++i) {
      float v = src[(long)i * 1024];
      s += v; q += v * v;
    }
    ps[cq][nl] = s; pq[cq][nl] = q;
  }
  __syncthreads();
  if (t < 32) {
    float s = 0.f, q = 0.f;
#pragma unroll
    for (int g2 = 0; g2 < 8; ++g2) { s += ps[g2][t]; q += pq[g2][t]; }
    float mu = s * (1.f / 256.f);
    float rs = rsqrtf(q * (1.f / 256.f) - mu * mu + 1e-5f);
    mu_s[t] = mu; rs_s[t] = rs;
  }
  int w8 = t >> 6, lane = t & 63, g = lane >> 4, ql = lane & 15;
  int rg = w8 & 1, cp = w8 >> 1;
  const f32x4 zf = {0.f, 0.f, 0.f, 0.f};
  f32x4 acc[2] = {zf, zf};
  int rr = t >> 2, nq = (t & 3) * 8;
  int wr = t >> 2, wk = (t & 3) * 16;
  for (int k0 = 0; k0 < 256; k0 += 64) {
    __syncthreads();
    {
      int ch = k0 + rr;
      const float* src = XD + ((long)(b * 256 + ch)) * 1024 + n0 + nq;
      float wv_ = nw[ch], bv_ = nbias[ch];
#pragma unroll
      for (int j = 0; j < 2; ++j) {
        float4 v = *(const float4*)(src + 4 * j);
        int n = nq + 4 * j;
        xa[n + 0][rr] = f2b((v.x - mu_s[n + 0]) * rs_s[n + 0] * wv_ + bv_);
        xa[n + 1][rr] = f2b((v.y - mu_s[n + 1]) * rs_s[n + 1] * wv_ + bv_);
        xa[n + 2][rr] = f2b((v.z - mu_s[n + 2]) * rs_s[n + 2] * wv_ + bv_);
        xa[n + 3][rr] = f2b((v.w - mu_s[n + 3]) * rs_s[n + 3] * wv_ + bv_);
      }
      const float* wsrc = w + (long)(c0 + wr) * 256 + k0 + wk;
#pragma unroll
      for (int j = 0; j < 4; ++j) {
        float4 v = *(const float4*)(wsrc + 4 * j);
        ushort4v u = {f2b(v.x), f2b(v.y), f2b(v.z), f2b(v.w)};
        *(ushort4v*)&wb[wr][wk + 4 * j] = u;
      }
    }
    __syncthreads();
#pragma unroll
    for (int ks = 0; ks < 2; ++ks) {
      bf16x8 a = *(const bf16x8*)&xa[rg * 16 + ql][ks * 32 + g * 8];
#pragma unroll
      for (int ct = 0; ct < 2; ++ct) {
        bf16x8 bfr = *(const bf16x8*)&wb[(cp * 2 + ct) * 16 + ql][ks * 32 + g * 8];
        acc[ct] = __builtin_amdgcn_mfma_f32_16x16x32_bf16(a, bfr, acc[ct], 0, 0, 0);
      }
    }
  }
#pragma unroll
  for (int ct = 0; ct < 2; ++ct) {
    int col = c0 + (cp * 2 + ct) * 16 + ql;
    float bv = bias[col];
    long basei = ((long)(b * 256 + col)) * 1024 + n0 + rg * 16 + g * 4;
    *(float4*)(out + basei) = make_float4(acc[ct][0] + bv, acc[ct][1] + bv,
                                          acc[ct][2] + bv, acc[ct][3] + bv);
  }
}

extern "C" void kernel_launch(void* const* d_in, const int* in_sizes, int n_in,
                              void* d_out, int out_size, void* d_ws, size_t ws_size,
                              hipStream_t stream) {
  const float* x        = (const float*)d_in[0];
  const float* norm_w   = (const float*)d_in[1];
  const float* norm_b   = (const float*)d_in[2];
  const float* skip     = (const float*)d_in[3];
  const float* m_inw    = (const float*)d_in[4];
  const float* m_convw  = (const float*)d_in[5];
  const float* m_convb  = (const float*)d_in[6];
  const float* m_xpw    = (const float*)d_in[7];
  const float* m_dtw    = (const float*)d_in[8];
  const float* m_dtb    = (const float*)d_in[9];
  const float* m_alog   = (const float*)d_in[10];
  const float* m_d      = (const float*)d_in[11];
  const float* m_outw   = (const float*)d_in[12];
  const float* qdw_w    = (const float*)d_in[13];
  const float* qdw_b    = (const float*)d_in[14];
  const float* qpw_w    = (const float*)d_in[15];
  const float* qpw_b    = (const float*)d_in[16];
  const float* rdw_w    = (const float*)d_in[17];
  const float* rdw_b    = (const float*)d_in[18];
  const float* rpw_w    = (const float*)d_in[19];
  const float* rpw_b    = (const float*)d_in[20];
  const float* fdw_w    = (const float*)d_in[21];
  const float* fdw_b    = (const float*)d_in[22];
  const float* fpw_w    = (const float*)d_in[23];
  const float* fpw_b    = (const float*)d_in[24];
  const float* lc_w     = (const float*)d_in[25];
  const float* lc_b     = (const float*)d_in[26];
  const float* attn_inw = (const float*)d_in[27];
  const float* attn_inb = (const float*)d_in[28];
  const float* attn_outw= (const float*)d_in[29];
  const float* attn_outb= (const float*)d_in[30];
  const float* lgn_w    = (const float*)d_in[31];
  const float* lgn_b    = (const float*)d_in[32];
  const float* fc_w     = (const float*)d_in[33];
  const float* fc_b     = (const float*)d_in[34];
  const float* dwc_w    = (const float*)d_in[35];
  const float* dwc_b    = (const float*)d_in[36];
  const float* proj_w   = (const float*)d_in[37];
  const float* proj_b   = (const float*)d_in[38];
  float* out = (float*)d_out;

  float* ws = (float*)d_ws;
  const size_t F = 1048576;  // B*N*C
  float* XN  = ws + 1 * F;
  unsigned short* UB = (unsigned short*)(ws + 2 * F);
  float* Z   = ws + 4 * F;
  float* DT  = ws + 6 * F;
  float* BM  = ws + 8 * F;
  float* CM  = ws + 8 * F + F / 4;
  float* XMC = ws + 8 * F + F / 2;
  float* SC_APROD = ws + 8 * F + F / 2;
  float* SC_HEND  = ws + 9 * F;
  float* G   = ws + 0 * F;
  float* XG  = ws + 2 * F;
  float* RB  = ws + 4 * F;
  unsigned short* XM2B = (unsigned short*)(ws + 5 * F);
  unsigned short* QKVB = (unsigned short*)(ws + 1 * F);
  unsigned short* OB   = (unsigned short*)(ws + 4 * F);
  unsigned short* XGLB = (unsigned short*)(ws + 6 * F);
  float* XO  = ws + 7 * F;
  float* XI  = ws + 8 * F;
  float* XD  = ws + 0 * F;
  (void)ws_size; (void)in_sizes; (void)n_in; (void)out_size;

  k_ln_t2<<<512, 256, 0, stream>>>(x, norm_w, norm_b, XN);
  k_inproj_conv<<<dim3(64, 16), 256, 0, stream>>>(XN, m_inw, m_convw, m_convb, UB, Z);
  k_xdbc_scanA<<<256, 256, 0, stream>>>(UB, m_xpw, m_dtw, m_dtb, m_alog,
                                        DT, BM, CM, SC_APROD, SC_HEND);
  k_scanC<<<512, 256, 0, stream>>>(DT, UB, BM, CM, m_alog, m_d, SC_APROD, SC_HEND);
  k_outproj_mfma<<<dim3(128, 4), 256, 0, stream>>>(DT, Z, m_outw, XN, skip, XMC);
  k_gate<<<512, 128, 0, stream>>>(XMC, qdw_w, qdw_b, qpw_w, qpw_b, G);
  k_xg<<<512, 256, 0, stream>>>(XMC, G, XG);
  k_gemm_cm_dw<256><<<dim3(128, 4), 256, 0, stream>>>(XG, nullptr, rdw_w, rdw_b,
                                                      rpw_w, rpw_b, XG, nullptr, RB, nullptr);
  k_gemm_cm_dw<512><<<dim3(128, 4), 256, 0, stream>>>(x, RB, fdw_w, fdw_b,
                                                      fpw_w, fpw_b, nullptr, x, nullptr, XM2B);
  k_gemm_qkv<<<dim3(64, 12), 256, 0, stream>>>(XM2B, attn_inw, attn_inb, QKVB);
  k_attn_mfma<<<512, 256, 0, stream>>>(QKVB, OB);
  k_gemm_attnout<<<dim3(128, 4), 256, 0, stream>>>(OB, attn_outw, attn_outb, XGLB);
  k_gemm_fc<<<dim3(128, 4), 256, 0, stream>>>(XM2B, XGLB, lc_w, lc_b, fc_w, fc_b, XO);
  k_lngelu<<<512, 256, 0, stream>>>(XO, lgn_w, lgn_b, XI);
  k_lnhw_dwc<<<1024, 256, 0, stream>>>(XI, dwc_w, dwc_b, XD);
  k_lnproj<<<dim3(128, 4), 256, 0, stream>>>(XD, norm_w, norm_b, proj_w, proj_b, out);
}

// Round 21
// 185.454 us; speedup vs baseline: 1.1058x; 1.0205x over previous
//
#include <hip/hip_runtime.h>
#include <math.h>

// MambaLiteUNet — round 20: bf16 XN/Z/XO/XI/XD intermediates (~96MB traffic cut;
// consumers already round or are linear). Occupancy structure from r17-19 kept.

namespace {
constexpr int NB_ = 4, DM_ = 64, DIN_ = 128, DS_ = 16, DTR_ = 4;
constexpr int C_ = 256, N_ = 1024, B_ = 4, HD_ = 32;
constexpr int NCH = 16, LCH = 64;          // scan: 16 time-chunks of 64
constexpr int NSTATE = 16 * 128 * 16;      // nbb * DIN * DS = 32768
}

typedef __attribute__((ext_vector_type(8))) short bf16x8;
typedef __attribute__((ext_vector_type(4))) float f32x4;
typedef __attribute__((ext_vector_type(8))) unsigned short ushort8v;
typedef __attribute__((ext_vector_type(4))) unsigned short ushort4v;

// ---------- helpers ----------
__device__ __forceinline__ unsigned short f2b(float f) {  // fp32 -> bf16 RNE
  unsigned int u = __float_as_uint(f);
  unsigned int r = u + 0x7FFFu + ((u >> 16) & 1u);
  return (unsigned short)(r >> 16);
}
__device__ __forceinline__ float b2f(unsigned short u) {
  return __uint_as_float(((unsigned int)u) << 16);
}

__device__ __forceinline__ float2 blockReduce2(float a, float b, float* red) {
#pragma unroll
  for (int m = 1; m < 64; m <<= 1) {
    a += __shfl_xor(a, m, 64);
    b += __shfl_xor(b, m, 64);
  }
  int w = threadIdx.x >> 6;
  if ((threadIdx.x & 63) == 0) { red[2 * w] = a; red[2 * w + 1] = b; }
  __syncthreads();
  float ra = red[0] + red[2] + red[4] + red[6];
  float rb = red[1] + red[3] + red[5] + red[7];
  return make_float2(ra, rb);
}

__device__ __forceinline__ float siluf(float x) { return x / (1.f + expf(-x)); }
__device__ __forceinline__ float sigmf(float x) { return 1.f / (1.f + expf(-x)); }
__device__ __forceinline__ float softplusf(float x) {
  return fmaxf(x, 0.f) + log1pf(expf(-fabsf(x)));
}

// ---------- K1: LN over C of (B,C,N) -> (B,N,C) bf16, 8-n tiles, 512 blocks ----------
__global__ __launch_bounds__(256) void k_ln_t2(const float* __restrict__ in,
                                               const float* __restrict__ w,
                                               const float* __restrict__ bias,
                                               unsigned short* __restrict__ out_ln) {
  __shared__ float tile[256][9];
  __shared__ float redp[32][8][2];
  __shared__ float stats[8][2];
  int bx = blockIdx.x;
  int b = bx >> 7, n0 = (bx & 127) * 8;
  int c = threadIdx.x;
  {
    const float* p = in + ((long)(b * C_ + c)) * N_ + n0;
#pragma unroll
    for (int j = 0; j < 8; ++j) tile[c][j] = p[j];
  }
  __syncthreads();
  {
    int n = c & 7, g = c >> 3;
    float a = 0.f, q = 0.f;
#pragma unroll
    for (int i = 0; i < 8; ++i) {
      float v = tile[g * 8 + i][n];
      a += v; q += v * v;
    }
    redp[g][n][0] = a; redp[g][n][1] = q;
  }
  __syncthreads();
  if (c < 8) {
    float a = 0.f, q = 0.f;
#pragma unroll
    for (int g2 = 0; g2 < 32; ++g2) { a += redp[g2][c][0]; q += redp[g2][c][1]; }
    float mu = a * (1.f / C_);
    float rs = rsqrtf(q * (1.f / C_) - mu * mu + 1e-5f);
    stats[c][0] = mu; stats[c][1] = rs;
  }
  __syncthreads();
  float wv = w[c], bv = bias[c];
#pragma unroll
  for (int j = 0; j < 8; ++j) {
    float v = tile[c][j];
    long o = ((long)(b * N_ + n0 + j)) * C_ + c;
    out_ln[o] = f2b((v - stats[j][0]) * stats[j][1] * wv + bv);
  }
}

// ---------- K2: mamba in-proj (MFMA) + fused causal conv + silu; bf16 XN in, U bf16, Z bf16 ----------
__global__ __launch_bounds__(256) void k_inproj_conv(const unsigned short* __restrict__ xn,
                                                     const float* __restrict__ inw,
                                                     const float* __restrict__ cw,
                                                     const float* __restrict__ cb,
                                                     unsigned short* __restrict__ U,
                                                     unsigned short* __restrict__ Z) {
  __shared__ unsigned short xa[64][72];
  __shared__ unsigned short wb[64][72];
  __shared__ float ut[67][65];
  int r0 = blockIdx.x * 64;
  int nb = blockIdx.y >> 2, q = blockIdx.y & 3, c0 = q * 64;
  int t = threadIdx.x;
  int wv = t >> 6, lane = t & 63, g = lane >> 4, ql = lane & 15;
  const f32x4 zf = {0.f, 0.f, 0.f, 0.f};
  f32x4 acc[4] = {zf, zf, zf, zf};
  int rr = t >> 2, kq = (t & 3) * 16;
  {
    const unsigned short* xsrc = xn + (long)(r0 + rr) * C_ + nb * 64 + kq;
#pragma unroll
    for (int j = 0; j < 2; ++j)
      *(ushort8v*)&xa[rr][kq + 8 * j] = *(const ushort8v*)(xsrc + 8 * j);
    const float* wsrc = inw + ((long)nb * 256 + c0 + rr) * 64 + kq;
#pragma unroll
    for (int j = 0; j < 4; ++j) {
      float4 v = *(const float4*)(wsrc + 4 * j);
      ushort4v u = {f2b(v.x), f2b(v.y), f2b(v.z), f2b(v.w)};
      *(ushort4v*)&wb[rr][kq + 4 * j] = u;
    }
  }
  __syncthreads();
#pragma unroll
  for (int ks = 0; ks < 2; ++ks) {
    bf16x8 a = *(const bf16x8*)&xa[wv * 16 + ql][ks * 32 + g * 8];
#pragma unroll
    for (int ct = 0; ct < 4; ++ct) {
      bf16x8 b = *(const bf16x8*)&wb[ct * 16 + ql][ks * 32 + g * 8];
      acc[ct] = __builtin_amdgcn_mfma_f32_16x16x32_bf16(a, b, acc[ct], 0, 0, 0);
    }
  }
  if (q < 2) {
#pragma unroll
    for (int ct = 0; ct < 4; ++ct)
#pragma unroll
      for (int reg = 0; reg < 4; ++reg)
        ut[3 + wv * 16 + g * 4 + reg][ct * 16 + ql] = acc[ct][reg];
    if (t < 192) {
      int hr = t >> 6, lc = t & 63;
      float hv = 0.f;
      if ((r0 & 1023) != 0) {
        const unsigned short* xrow = xn + (long)(r0 - 3 + hr) * C_ + nb * 64;
        const float* wrow = inw + ((long)nb * 256 + c0 + lc) * 64;
#pragma unroll 8
        for (int k = 0; k < 64; ++k) hv += b2f(xrow[k]) * wrow[k];
      }
      ut[hr][lc] = hv;
    }
    __syncthreads();
#pragma unroll
    for (int ct = 0; ct < 4; ++ct) {
      int lc = ct * 16 + ql;
      int d = c0 + lc;
      const float* cwp = cw + (nb * DIN_ + d) * 4;
      float w0 = cwp[0], w1 = cwp[1], w2 = cwp[2], w3 = cwp[3];
      float bv = cb[nb * DIN_ + d];
#pragma unroll
      for (int reg = 0; reg < 4; ++reg) {
        int lr = wv * 16 + g * 4 + reg;
        float a = bv + w3 * ut[3 + lr][lc] + w2 * ut[2 + lr][lc] +
                  w1 * ut[1 + lr][lc] + w0 * ut[lr][lc];
        long row = (long)nb * 4096 + r0 + lr;
        U[row * DIN_ + d] = f2b(siluf(a));
      }
    }
  } else {
#pragma unroll
    for (int ct = 0; ct < 4; ++ct) {
      int col = c0 - 128 + ct * 16 + ql;
#pragma unroll
      for (int reg = 0; reg < 4; ++reg) {
        long row = (long)nb * 4096 + r0 + wv * 16 + g * 4 + reg;
        Z[row * DIN_ + col] = f2b(acc[ct][reg]);
      }
    }
  }
}

// ---------- K4: xdbc (MFMA, bf16 U in) + dt/Bm/Cm epilogue + fused scan phase A ----------
__global__ __launch_bounds__(256) void k_xdbc_scanA(const unsigned short* __restrict__ U,
                                                    const float* __restrict__ xpw,
                                                    const float* __restrict__ dtw,
                                                    const float* __restrict__ dtb,
                                                    const float* __restrict__ alog,
                                                    float* __restrict__ DT,
                                                    float* __restrict__ BMb,
                                                    float* __restrict__ CMb,
                                                    float* __restrict__ Aprod,
                                                    float* __restrict__ Hend) {
  __shared__ unsigned short u_sb[64][136];
  __shared__ unsigned short wb[48][72];
  __shared__ float xd_s[64][40];
  __shared__ float dtw_s[128][4];
  __shared__ float dtb_s[128];
  __shared__ float dt_s[64][132];
  __shared__ float bm_s[64][20];
  int t = threadIdx.x;
  long row0 = (long)blockIdx.x * 64;
  int nb = blockIdx.x >> 6;
  int nbb = blockIdx.x >> 4, chunk = blockIdx.x & 15;
  for (int i = t; i < 512; i += 256) dtw_s[i >> 2][i & 3] = dtw[nb * 512 + i];
  if (t < 128) dtb_s[t] = dtb[nb * DIN_ + t];
  int wv = t >> 6, lane = t & 63, g = lane >> 4, ql = lane & 15;
  const f32x4 zf = {0.f, 0.f, 0.f, 0.f};
  f32x4 acc[3] = {zf, zf, zf};
  int rr = t >> 2, kq = (t & 3) * 16;
  for (int k0 = 0; k0 < 128; k0 += 64) {
    __syncthreads();
    const unsigned short* xsrc = U + (row0 + rr) * DIN_ + k0 + kq;
#pragma unroll
    for (int j = 0; j < 2; ++j)
      *(ushort8v*)&u_sb[rr][k0 + kq + 8 * j] = *(const ushort8v*)(xsrc + 8 * j);
    if (rr < 48) {
      if (rr < 36) {
        const float* wsrc = xpw + (long)nb * 36 * 128 + rr * 128 + k0 + kq;
#pragma unroll
        for (int j = 0; j < 4; ++j) {
          float4 v = *(const float4*)(wsrc + 4 * j);
          ushort4v u = {f2b(v.x), f2b(v.y), f2b(v.z), f2b(v.w)};
          *(ushort4v*)&wb[rr][kq + 4 * j] = u;
        }
      } else {
        ushort4v z = {0, 0, 0, 0};
#pragma unroll
        for (int j = 0; j < 4; ++j) *(ushort4v*)&wb[rr][kq + 4 * j] = z;
      }
    }
    __syncthreads();
#pragma unroll
    for (int ks = 0; ks < 2; ++ks) {
      bf16x8 a = *(const bf16x8*)&u_sb[wv * 16 + ql][k0 + ks * 32 + g * 8];
#pragma unroll
      for (int ct = 0; ct < 3; ++ct) {
        bf16x8 b = *(const bf16x8*)&wb[ct * 16 + ql][ks * 32 + g * 8];
        acc[ct] = __builtin_amdgcn_mfma_f32_16x16x32_bf16(a, b, acc[ct], 0, 0, 0);
      }
    }
  }
#pragma unroll
  for (int ct = 0; ct < 3; ++ct) {
    int col = ct * 16 + ql;
    if (col < 36) {
#pragma unroll
      for (int reg = 0; reg < 4; ++reg)
        xd_s[wv * 16 + g * 4 + reg][col] = acc[ct][reg];
    }
  }
  __syncthreads();
  {
    int r = t >> 2, sq = (t & 3) * 4;
    float4 bm4 = make_float4(xd_s[r][4 + sq], xd_s[r][5 + sq],
                             xd_s[r][6 + sq], xd_s[r][7 + sq]);
    *(float4*)&BMb[(row0 + r) * DS_ + sq] = bm4;
    *(float4*)&bm_s[r][sq] = bm4;
    float4 cm4 = make_float4(xd_s[r][20 + sq], xd_s[r][21 + sq],
                             xd_s[r][22 + sq], xd_s[r][23 + sq]);
    *(float4*)&CMb[(row0 + r) * DS_ + sq] = cm4;
  }
  {
    int r = t >> 2, dg = t & 3;
    float x0 = xd_s[r][0], x1 = xd_s[r][1], x2 = xd_s[r][2], x3 = xd_s[r][3];
    float* dst = DT + (row0 + r) * DIN_ + dg * 32;
#pragma unroll
    for (int j = 0; j < 8; ++j) {
      float o[4];
#pragma unroll
      for (int e = 0; e < 4; ++e) {
        int d = dg * 32 + j * 4 + e;
        float a = dtb_s[d] + x0 * dtw_s[d][0] + x1 * dtw_s[d][1] +
                  x2 * dtw_s[d][2] + x3 * dtw_s[d][3];
        o[e] = softplusf(a);
      }
      float4 o4 = make_float4(o[0], o[1], o[2], o[3]);
      *(float4*)(dst + j * 4) = o4;
      *(float4*)&dt_s[r][dg * 32 + j * 4] = o4;
    }
  }
  __syncthreads();
  {
    int dl = t >> 2, sg = t & 3;
#pragma unroll
    for (int dh = 0; dh < 2; ++dh) {
      int d = dh * 64 + dl;
      float A[4];
#pragma unroll
      for (int i = 0; i < 4; ++i)
        A[i] = -expf(alog[(nb * DIN_ + d) * DS_ + sg * 4 + i]);
      float h[4] = {0.f, 0.f, 0.f, 0.f};
      float ap[4] = {1.f, 1.f, 1.f, 1.f};
      for (int tt = 0; tt < LCH; ++tt) {
        float dtv = dt_s[tt][d];
        float uv  = b2f(u_sb[tt][d]);
        float cc = dtv * uv;
        float4 bm4 = *(const float4*)&bm_s[tt][sg * 4];
        float bmv[4] = {bm4.x, bm4.y, bm4.z, bm4.w};
#pragma unroll
        for (int i = 0; i < 4; ++i) {
          float dA = __expf(dtv * A[i]);
          h[i] = dA * h[i] + cc * bmv[i];
          ap[i] *= dA;
        }
      }
      long st = (long)chunk * NSTATE + ((nbb << 7) + d) * 16 + sg * 4;
      *(float4*)&Aprod[st] = make_float4(ap[0], ap[1], ap[2], ap[3]);
      *(float4*)&Hend[st]  = make_float4(h[0], h[1], h[2], h[3]);
    }
  }
}

// ---------- K5c: scan phase C — inline carry composition, emit y over DT ----------
__global__ __launch_bounds__(256) void k_scanC(float* __restrict__ DT,
                                               const unsigned short* __restrict__ U,
                                               const float* __restrict__ BMb,
                                               const float* __restrict__ CMb,
                                               const float* __restrict__ alog,
                                               const float* __restrict__ Dp,
                                               const float* __restrict__ Aprod,
                                               const float* __restrict__ Hend) {
  __shared__ float dt_s[64][64];
  __shared__ float u_s[64][64];
  __shared__ float bm_s[64][16];
  __shared__ float cm_s[64][16];
  int bx = blockIdx.x;
  int chunk = bx >> 5, rem = bx & 31, nbb = rem >> 1, dh = rem & 1;
  int nb = nbb >> 2;
  int t = threadIdx.x;
  int dl = t >> 2, sg = t & 3;
  int d = dh * 64 + dl;
  long base = (long)nbb * N_ + chunk * LCH;
#pragma unroll
  for (int j = 0; j < 4; ++j) {
    int f = t + 256 * j;
    int tt = f >> 4, dq = (f & 15) * 4;
    long src = (base + tt) * DIN_ + dh * 64 + dq;
    *(float4*)&dt_s[tt][dq] = *(const float4*)&DT[src];
    ushort4v u4 = *(const ushort4v*)&U[src];
    u_s[tt][dq + 0] = b2f(u4[0]);
    u_s[tt][dq + 1] = b2f(u4[1]);
    u_s[tt][dq + 2] = b2f(u4[2]);
    u_s[tt][dq + 3] = b2f(u4[3]);
  }
  {
    int tt = t >> 2, sq = (t & 3) * 4;
    *(float4*)&bm_s[tt][sq] = *(const float4*)&BMb[(base + tt) * DS_ + sq];
    *(float4*)&cm_s[tt][sq] = *(const float4*)&CMb[(base + tt) * DS_ + sq];
  }
  float A[4];
#pragma unroll
  for (int i = 0; i < 4; ++i)
    A[i] = -expf(alog[(nb * DIN_ + d) * DS_ + sg * 4 + i]);
  float Dv = Dp[nb * DIN_ + d];
  float h[4] = {0.f, 0.f, 0.f, 0.f};
  {
    long state4 = ((nbb << 7) + d) * 16 + sg * 4;
    for (int c = 0; c < chunk; ++c) {
      float4 a4 = *(const float4*)&Aprod[(long)c * NSTATE + state4];
      float4 e4 = *(const float4*)&Hend[(long)c * NSTATE + state4];
      h[0] = e4.x + a4.x * h[0];
      h[1] = e4.y + a4.y * h[1];
      h[2] = e4.z + a4.z * h[2];
      h[3] = e4.w + a4.w * h[3];
    }
  }
  __syncthreads();
  for (int tt = 0; tt < LCH; ++tt) {
    float dtv = dt_s[tt][dl];
    float uv  = u_s[tt][dl];
    float cc = dtv * uv;
    float4 bm4 = *(const float4*)&bm_s[tt][sg * 4];
    float4 cm4 = *(const float4*)&cm_s[tt][sg * 4];
    float bmv[4] = {bm4.x, bm4.y, bm4.z, bm4.w};
    float cmv[4] = {cm4.x, cm4.y, cm4.z, cm4.w};
    float p = 0.f;
#pragma unroll
    for (int i = 0; i < 4; ++i) {
      float dA = __expf(dtv * A[i]);
      h[i] = dA * h[i] + cc * bmv[i];
      p += h[i] * cmv[i];
    }
    p += __shfl_xor(p, 1, 64);
    p += __shfl_xor(p, 2, 64);
    if (sg == 0) DT[(base + tt) * DIN_ + d] = p + Dv * uv;
  }
}

// ---------- K6: out-proj (MFMA, 32-row tile): xm = (y*silu(z)) @ outw^T + skip*xn ----------
__global__ __launch_bounds__(256) void k_outproj_mfma(const float* __restrict__ Y,
                                                      const unsigned short* __restrict__ Zb,
                                                      const float* __restrict__ outw,
                                                      const unsigned short* __restrict__ xn,
                                                      const float* __restrict__ skip,
                                                      float* __restrict__ XMC) {
  __shared__ unsigned short xa[32][72];
  __shared__ unsigned short wb[64][72];
  int r0 = blockIdx.x * 32;
  int nb = blockIdx.y;
  int t = threadIdx.x;
  int w = t >> 6, lane = t & 63, g = lane >> 4, ql = lane & 15;
  int rg = w & 1, cp = w >> 1;
  const f32x4 zf = {0.f, 0.f, 0.f, 0.f};
  f32x4 acc[2] = {zf, zf};
  int ar = t >> 3, ak = (t & 7) * 8;
  int wr = t >> 2, wk = (t & 3) * 16;
  for (int k0 = 0; k0 < 128; k0 += 64) {
    __syncthreads();
    long row = (long)nb * 4096 + r0 + ar;
    const float* ysrc = Y + row * DIN_ + k0 + ak;
    const unsigned short* zsrc = Zb + row * DIN_ + k0 + ak;
#pragma unroll
    for (int j = 0; j < 2; ++j) {
      float4 yv = *(const float4*)(ysrc + 4 * j);
      ushort4v z4 = *(const ushort4v*)(zsrc + 4 * j);
      ushort4v u = {f2b(yv.x * siluf(b2f(z4[0]))), f2b(yv.y * siluf(b2f(z4[1]))),
                    f2b(yv.z * siluf(b2f(z4[2]))), f2b(yv.w * siluf(b2f(z4[3])))};
      *(ushort4v*)&xa[ar][ak + 4 * j] = u;
    }
    const float* wsrc = outw + ((long)nb * 64 + wr) * 128 + k0 + wk;
#pragma unroll
    for (int j = 0; j < 4; ++j) {
      float4 v = *(const float4*)(wsrc + 4 * j);
      ushort4v u = {f2b(v.x), f2b(v.y), f2b(v.z), f2b(v.w)};
      *(ushort4v*)&wb[wr][wk + 4 * j] = u;
    }
    __syncthreads();
#pragma unroll
    for (int ks = 0; ks < 2; ++ks) {
      bf16x8 a = *(const bf16x8*)&xa[rg * 16 + ql][ks * 32 + g * 8];
#pragma unroll
      for (int ct = 0; ct < 2; ++ct) {
        bf16x8 b = *(const bf16x8*)&wb[(cp * 2 + ct) * 16 + ql][ks * 32 + g * 8];
        acc[ct] = __builtin_amdgcn_mfma_f32_16x16x32_bf16(a, b, acc[ct], 0, 0, 0);
      }
    }
  }
  float sk = skip[0];
#pragma unroll
  for (int ct = 0; ct < 2; ++ct) {
    int col = (cp * 2 + ct) * 16 + ql;
#pragma unroll
    for (int reg = 0; reg < 4; ++reg) {
      int bn = r0 + rg * 16 + g * 4 + reg;
      long oc = (long)bn * C_ + nb * 64 + col;
      XMC[oc] = acc[ct][reg] + sk * b2f(xn[oc]);
    }
  }
}

// ---------- K7: gate (512 blocks x 128 threads) ----------
__global__ __launch_bounds__(128) void k_gate(const float* __restrict__ XMC,
                                              const float* __restrict__ qdw_w,
                                              const float* __restrict__ qdw_b,
                                              const float* __restrict__ qpw_w,
                                              const float* __restrict__ qpw_b,
                                              float* __restrict__ G) {
  int t = threadIdx.x;
  int gid = (blockIdx.x * 128 + t) >> 4;     // b*N + n
  int cq = t & 3, p = (t >> 2) & 3;
  int b = gid >> 10, n = gid & 1023;
  float a = 0.f;
#pragma unroll
  for (int k = 0; k < 3; ++k) {
    int nn = n + k - 1;
    if (nn < 0 || nn >= N_) continue;
    const float* xr = XMC + ((long)b * N_ + nn) * C_ + p * 64 + cq * 16;
    const float* wr = qdw_w + (p * 64 + cq * 16) * 3 + k;
    float xv[16];
    *(float4*)&xv[0]  = *(const float4*)(xr);
    *(float4*)&xv[4]  = *(const float4*)(xr + 4);
    *(float4*)&xv[8]  = *(const float4*)(xr + 8);
    *(float4*)&xv[12] = *(const float4*)(xr + 12);
#pragma unroll
    for (int i = 0; i < 16; ++i) a += xv[i] * wr[i * 3];
  }
  a += __shfl_xor(a, 1, 64);
  a += __shfl_xor(a, 2, 64);
  float q1 = a + qdw_b[p];
  int lane = t & 63;
  float q1g[4];
#pragma unroll
  for (int pp = 0; pp < 4; ++pp) q1g[pp] = __shfl(q1, (lane & ~12) | (pp << 2), 64);
  int o = p;
  float r = qpw_b[o];
#pragma unroll
  for (int pp = 0; pp < 4; ++pp) r += qpw_w[o * 4 + pp] * q1g[pp];
  if (cq == 0) G[((long)b * 4 + o) * N_ + n] = sigmf(r);
}

// ---------- K8: xg (B,C,N) = g * xm — 32-n LDS tile transpose, 512 blocks ----------
__global__ __launch_bounds__(256) void k_xg(const float* __restrict__ XMC,
                                            const float* __restrict__ G,
                                            float* __restrict__ XG) {
  __shared__ float tile[64][33];
  int bx = blockIdx.x;
  int b = bx >> 7, ct = (bx >> 5) & 3, nt = bx & 31;
  int c0 = ct * 64, n0 = nt * 32;
  int t = threadIdx.x;
  {
    int cc = t & 63, nq = t >> 6;
#pragma unroll
    for (int j = 0; j < 8; ++j) {
      int nn = nq * 8 + j;
      tile[cc][nn] = XMC[((long)(b * N_ + n0 + nn)) * C_ + c0 + cc];
    }
  }
  __syncthreads();
  {
    int nl = t & 31, cq = t >> 5;
    float g = G[((long)(b * 4 + ct)) * N_ + n0 + nl];
#pragma unroll
    for (int j = 0; j < 8; ++j) {
      int cl = cq * 8 + j;
      XG[((long)(b * C_ + c0 + cl)) * N_ + n0 + nl] = g * tile[cl][nl];
    }
  }
}

// ---------- MFMA GEMM (32-n tile), channel-major, 3-tap dw conv fused ----------
template <int KD>
__global__ __launch_bounds__(256) void k_gemm_cm_dw(const float* __restrict__ inA,
                                                    const float* __restrict__ inB,
                                                    const float* __restrict__ dww,
                                                    const float* __restrict__ dwb,
                                                    const float* __restrict__ w,
                                                    const float* __restrict__ bias,
                                                    const float* __restrict__ residCM,
                                                    const float* __restrict__ residXCM,
                                                    float* __restrict__ outCM,
                                                    unsigned short* __restrict__ outRMb) {
  __shared__ unsigned short xa[32][72];  // [n][k]
  __shared__ unsigned short wb[64][72];  // [cout][k]
  int rb = blockIdx.x;
  int b = rb >> 5, n0 = (rb & 31) * 32;
  int c0 = blockIdx.y * 64;
  int t = threadIdx.x;
  int w8 = t >> 6, lane = t & 63, g = lane >> 4, ql = lane & 15;
  int rg = w8 & 1, cp = w8 >> 1;
  const f32x4 zf = {0.f, 0.f, 0.f, 0.f};
  f32x4 acc[2] = {zf, zf};
  int cr = t >> 2, nq = (t & 3) * 8;
  int wr = t >> 2, wk = (t & 3) * 16;
  for (int k0 = 0; k0 < KD; k0 += 64) {
    __syncthreads();
    {
      int k = k0 + cr;
      const float* src = (inB != nullptr && k >= 256)
                             ? inB + ((long)(b * 256 + k - 256)) * 1024
                             : inA + ((long)(b * 256 + k)) * 1024;
      float w0 = dww[k * 3], w1 = dww[k * 3 + 1], w2 = dww[k * 3 + 2], bv = dwb[k];
#pragma unroll
      for (int j = 0; j < 2; ++j) {
        int nb4 = n0 + nq + 4 * j;
        float4 v = *(const float4*)&src[nb4];
        float vm1 = (nb4 > 0) ? src[nb4 - 1] : 0.f;
        float vp4 = (nb4 + 4 < 1024) ? src[nb4 + 4] : 0.f;
        xa[nq + 4 * j + 0][cr] = f2b(bv + w0 * vm1 + w1 * v.x + w2 * v.y);
        xa[nq + 4 * j + 1][cr] = f2b(bv + w0 * v.x + w1 * v.y + w2 * v.z);
        xa[nq + 4 * j + 2][cr] = f2b(bv + w0 * v.y + w1 * v.z + w2 * v.w);
        xa[nq + 4 * j + 3][cr] = f2b(bv + w0 * v.z + w1 * v.w + w2 * vp4);
      }
    }
    const float* wsrc = w + (long)(c0 + wr) * KD + k0 + wk;
#pragma unroll
    for (int j = 0; j < 4; ++j) {
      float4 v = *(const float4*)(wsrc + 4 * j);
      ushort4v u = {f2b(v.x), f2b(v.y), f2b(v.z), f2b(v.w)};
      *(ushort4v*)&wb[wr][wk + 4 * j] = u;
    }
    __syncthreads();
#pragma unroll
    for (int ks = 0; ks < 2; ++ks) {
      bf16x8 a = *(const bf16x8*)&xa[rg * 16 + ql][ks * 32 + g * 8];
#pragma unroll
      for (int ct = 0; ct < 2; ++ct) {
        bf16x8 bfr = *(const bf16x8*)&wb[(cp * 2 + ct) * 16 + ql][ks * 32 + g * 8];
        acc[ct] = __builtin_amdgcn_mfma_f32_16x16x32_bf16(a, bfr, acc[ct], 0, 0, 0);
      }
    }
  }
#pragma unroll
  for (int ct = 0; ct < 2; ++ct) {
    int col = c0 + (cp * 2 + ct) * 16 + ql;
    float bv = bias[col];
    if (outCM) {
      long base = ((long)(b * 256 + col)) * 1024 + n0 + rg * 16 + g * 4;
      float4 r4 = *(const float4*)(residCM + base);
      float4 o = make_float4(acc[ct][0] + bv + r4.x, acc[ct][1] + bv + r4.y,
                             acc[ct][2] + bv + r4.z, acc[ct][3] + bv + r4.w);
      *(float4*)(outCM + base) = o;
    } else {
      int nbase = n0 + rg * 16 + g * 4;
      float4 r4 = *(const float4*)&residXCM[((long)(b * 256 + col)) * 1024 + nbase];
      float rv[4] = {r4.x, r4.y, r4.z, r4.w};
#pragma unroll
      for (int reg = 0; reg < 4; ++reg) {
        long row = (long)b * 1024 + nbase + reg;
        outRMb[row * 256 + col] = f2b(acc[ct][reg] + bv + rv[reg]);
      }
    }
  }
}

// ---------- K13: QKV GEMM — bf16 XM2 in, bf16 out ----------
__global__ __launch_bounds__(256) void k_gemm_qkv(const unsigned short* __restrict__ in,
                                                  const float* __restrict__ w,
                                                  const float* __restrict__ bias,
                                                  unsigned short* __restrict__ out) {
  __shared__ unsigned short xa[64][72];
  __shared__ unsigned short wb[64][72];
  int r0 = blockIdx.x * 64;
  int c0 = blockIdx.y * 64;
  int t = threadIdx.x;
  int wv = t >> 6, lane = t & 63, g = lane >> 4, ql = lane & 15;
  const f32x4 zf = {0.f, 0.f, 0.f, 0.f};
  f32x4 acc[4] = {zf, zf, zf, zf};
  int rr = t >> 2, kq = (t & 3) * 16;
  for (int k0 = 0; k0 < 256; k0 += 64) {
    __syncthreads();
    const unsigned short* xsrc = in + (long)(r0 + rr) * 256 + k0 + kq;
#pragma unroll
    for (int j = 0; j < 2; ++j)
      *(ushort8v*)&xa[rr][kq + 8 * j] = *(const ushort8v*)(xsrc + 8 * j);
    const float* wsrc = w + (long)(c0 + rr) * 256 + k0 + kq;
#pragma unroll
    for (int j = 0; j < 4; ++j) {
      float4 v = *(const float4*)(wsrc + 4 * j);
      ushort4v u = {f2b(v.x), f2b(v.y), f2b(v.z), f2b(v.w)};
      *(ushort4v*)&wb[rr][kq + 4 * j] = u;
    }
    __syncthreads();
#pragma unroll
    for (int ks = 0; ks < 2; ++ks) {
      bf16x8 a = *(const bf16x8*)&xa[wv * 16 + ql][ks * 32 + g * 8];
#pragma unroll
      for (int ct = 0; ct < 4; ++ct) {
        bf16x8 b = *(const bf16x8*)&wb[ct * 16 + ql][ks * 32 + g * 8];
        acc[ct] = __builtin_amdgcn_mfma_f32_16x16x32_bf16(a, b, acc[ct], 0, 0, 0);
      }
    }
  }
#pragma unroll
  for (int ct = 0; ct < 4; ++ct) {
    int col = c0 + ct * 16 + ql;
    float bv = bias[col];
#pragma unroll
    for (int reg = 0; reg < 4; ++reg) {
      long row = r0 + wv * 16 + g * 4 + reg;
      out[row * 768 + col] = f2b(acc[ct][reg] + bv);
    }
  }
}

// ---------- K15: attn-out GEMM (32-row tile) — bf16 in/out ----------
__global__ __launch_bounds__(256) void k_gemm_attnout(const unsigned short* __restrict__ inA,
                                                      const float* __restrict__ w,
                                                      const float* __restrict__ bias,
                                                      unsigned short* __restrict__ out) {
  __shared__ unsigned short xa[32][72];
  __shared__ unsigned short wb[64][72];
  int r0 = blockIdx.x * 32;
  int c0 = blockIdx.y * 64;
  int t = threadIdx.x;
  int w8 = t >> 6, lane = t & 63, g = lane >> 4, ql = lane & 15;
  int rg = w8 & 1, cp = w8 >> 1;
  const f32x4 zf = {0.f, 0.f, 0.f, 0.f};
  f32x4 acc[2] = {zf, zf};
  int ar = t >> 3, ak = (t & 7) * 8;
  int wr = t >> 2, wk = (t & 3) * 16;
  for (int k0 = 0; k0 < 256; k0 += 64) {
    __syncthreads();
    const unsigned short* xsrc = inA + (long)(r0 + ar) * 256 + k0 + ak;
    *(ushort8v*)&xa[ar][ak] = *(const ushort8v*)xsrc;
    const float* wsrc = w + (long)(c0 + wr) * 256 + k0 + wk;
#pragma unroll
    for (int j = 0; j < 4; ++j) {
      float4 v = *(const float4*)(wsrc + 4 * j);
      ushort4v u = {f2b(v.x), f2b(v.y), f2b(v.z), f2b(v.w)};
      *(ushort4v*)&wb[wr][wk + 4 * j] = u;
    }
    __syncthreads();
#pragma unroll
    for (int ks = 0; ks < 2; ++ks) {
      bf16x8 a = *(const bf16x8*)&xa[rg * 16 + ql][ks * 32 + g * 8];
#pragma unroll
      for (int ct = 0; ct < 2; ++ct) {
        bf16x8 b = *(const bf16x8*)&wb[(cp * 2 + ct) * 16 + ql][ks * 32 + g * 8];
        acc[ct] = __builtin_amdgcn_mfma_f32_16x16x32_bf16(a, b, acc[ct], 0, 0, 0);
      }
    }
  }
#pragma unroll
  for (int ct = 0; ct < 2; ++ct) {
    int col = c0 + (cp * 2 + ct) * 16 + ql;
    float bv = bias[col];
#pragma unroll
    for (int reg = 0; reg < 4; ++reg) {
      long row = r0 + rg * 16 + g * 4 + reg;
      out[row * 256 + col] = f2b(acc[ct][reg] + bv);
    }
  }
}

// ---------- K16: fc GEMM (32-row tile) with x_local row-conv fused; bf16 XO out ----------
__global__ __launch_bounds__(256) void k_gemm_fc(const unsigned short* __restrict__ XM2,
                                                 const unsigned short* __restrict__ XGL,
                                                 const float* __restrict__ lcw,
                                                 const float* __restrict__ lcb,
                                                 const float* __restrict__ w,
                                                 const float* __restrict__ bias,
                                                 unsigned short* __restrict__ out) {
  __shared__ unsigned short xa[32][72];
  __shared__ unsigned short wb[64][72];
  int r0 = blockIdx.x * 32;
  int c0 = blockIdx.y * 64;
  int t = threadIdx.x;
  int w8 = t >> 6, lane = t & 63, g = lane >> 4, ql = lane & 15;
  int rg = w8 & 1, cp = w8 >> 1;
  const f32x4 zf = {0.f, 0.f, 0.f, 0.f};
  f32x4 acc[2] = {zf, zf};
  int ar = t >> 3, ak = (t & 7) * 8;
  int wr = t >> 2, wk = (t & 3) * 16;
  for (int k0 = 0; k0 < 512; k0 += 64) {
    __syncthreads();
    int kk = k0 + ak;
    long row = r0 + ar;
    if (kk < 256) {
      int n = (int)(row & 1023);
      const unsigned short* pc = XM2 + row * 256 + kk;
      bool hm = n > 0, hp = n < 1023;
#pragma unroll
      for (int j = 0; j < 2; ++j) {
        ushort4v v4 = *(const ushort4v*)(pc + 4 * j);
        ushort4v zm = {0, 0, 0, 0};
        ushort4v vm4 = hm ? *(const ushort4v*)(pc - 256 + 4 * j) : zm;
        ushort4v vp4 = hp ? *(const ushort4v*)(pc + 256 + 4 * j) : zm;
        int c = kk + 4 * j;
#pragma unroll
        for (int e = 0; e < 4; ++e) {
          float vv = b2f(v4[e]);
          float vmv = hm ? b2f(vm4[e]) : 0.f;
          float vpv = hp ? b2f(vp4[e]) : 0.f;
          xa[ar][ak + 4 * j + e] = f2b(lcb[c + e] + lcw[(c + e) * 3] * vmv +
                                       lcw[(c + e) * 3 + 1] * vv +
                                       lcw[(c + e) * 3 + 2] * vpv);
        }
      }
    } else {
      const unsigned short* xsrc = XGL + row * 256 + (kk - 256);
      *(ushort8v*)&xa[ar][ak] = *(const ushort8v*)xsrc;
    }
    const float* wsrc = w + (long)(c0 + wr) * 512 + k0 + wk;
#pragma unroll
    for (int j = 0; j < 4; ++j) {
      float4 v = *(const float4*)(wsrc + 4 * j);
      ushort4v u = {f2b(v.x), f2b(v.y), f2b(v.z), f2b(v.w)};
      *(ushort4v*)&wb[wr][wk + 4 * j] = u;
    }
    __syncthreads();
#pragma unroll
    for (int ks = 0; ks < 2; ++ks) {
      bf16x8 a = *(const bf16x8*)&xa[rg * 16 + ql][ks * 32 + g * 8];
#pragma unroll
      for (int ct = 0; ct < 2; ++ct) {
        bf16x8 b = *(const bf16x8*)&wb[(cp * 2 + ct) * 16 + ql][ks * 32 + g * 8];
        acc[ct] = __builtin_amdgcn_mfma_f32_16x16x32_bf16(a, b, acc[ct], 0, 0, 0);
      }
    }
  }
#pragma unroll
  for (int ct = 0; ct < 2; ++ct) {
    int col = c0 + (cp * 2 + ct) * 16 + ql;
    float bv = bias[col];
#pragma unroll
    for (int reg = 0; reg < 4; ++reg) {
      long row = r0 + rg * 16 + g * 4 + reg;
      out[row * 256 + col] = f2b(acc[ct][reg] + bv);
    }
  }
}

// ---------- K14: MFMA bf16 flash attention (bf16 QKV input, bf16 O output) ----------
__global__ __launch_bounds__(256) void k_attn_mfma(const unsigned short* __restrict__ qkvb,
                                                   unsigned short* __restrict__ Ob) {
  __shared__ unsigned short K_lds[64 * 40];
  __shared__ unsigned short Vt_lds[32 * 72];
  __shared__ unsigned short P_lds[4][16 * 72];
  int bx = blockIdx.x;
  int bh = bx >> 4, qt = bx & 15;
  int b = bh >> 3, h = bh & 7;
  int t = threadIdx.x;
  int w = t >> 6, lane = t & 63;
  int g = lane >> 4, ql = lane & 15;
  const float qscale = 0.17677669529663687f * 1.44269504088896341f;  // 1/sqrt(32)*log2(e)

  bf16x8 q_frag = *(const bf16x8*)(qkvb + ((long)(b * N_ + qt * 64 + w * 16 + ql)) * 768 + h * HD_ + g * 8);
  float m = -1e30f, l = 0.f;
  f32x4 o_acc[2];
  const f32x4 zf = {0.f, 0.f, 0.f, 0.f};
  o_acc[0] = zf; o_acc[1] = zf;

  for (int kt = 0; kt < 16; ++kt) {
    __syncthreads();
    {
      int kr = t >> 2, d0 = (t & 3) * 8;
      const unsigned short* gp = qkvb + ((long)(b * N_ + kt * 64 + kr)) * 768 + 256 + h * HD_ + d0;
      ushort8v kv = *(const ushort8v*)gp;
      *(ushort8v*)&K_lds[kr * 40 + d0] = kv;
      ushort8v vv = *(const ushort8v*)(gp + 256);
#pragma unroll
      for (int i = 0; i < 8; ++i) Vt_lds[(d0 + i) * 72 + kr] = vv[i];
    }
    __syncthreads();
    f32x4 s_frag[4];
#pragma unroll
    for (int s = 0; s < 4; ++s) {
      bf16x8 k_frag = *(const bf16x8*)&K_lds[(s * 16 + ql) * 40 + g * 8];
      s_frag[s] = __builtin_amdgcn_mfma_f32_16x16x32_bf16(k_frag, q_frag, zf, 0, 0, 0);
    }
    float sv[16];
#pragma unroll
    for (int s = 0; s < 4; ++s)
#pragma unroll
      for (int r = 0; r < 4; ++r) sv[s * 4 + r] = s_frag[s][r] * qscale;
    float tmax = sv[0];
#pragma unroll
    for (int i = 1; i < 16; ++i) tmax = fmaxf(tmax, sv[i]);
    tmax = fmaxf(tmax, __shfl_xor(tmax, 16));
    tmax = fmaxf(tmax, __shfl_xor(tmax, 32));
    float mn = fmaxf(m, tmax);
    float corr = exp2f(m - mn);
    float psum = 0.f;
    unsigned short pb[16];
#pragma unroll
    for (int i = 0; i < 16; ++i) {
      float p = exp2f(sv[i] - mn);
      psum += p;
      pb[i] = f2b(p);
    }
    psum += __shfl_xor(psum, 16);
    psum += __shfl_xor(psum, 32);
    l = l * corr + psum;
    m = mn;
#pragma unroll
    for (int mt = 0; mt < 2; ++mt)
#pragma unroll
      for (int r = 0; r < 4; ++r) o_acc[mt][r] *= corr;
#pragma unroll
    for (int s = 0; s < 4; ++s) {
      ushort4v p4 = {pb[s * 4], pb[s * 4 + 1], pb[s * 4 + 2], pb[s * 4 + 3]};
      *(ushort4v*)&P_lds[w][ql * 72 + s * 16 + g * 4] = p4;
    }
#pragma unroll
    for (int c = 0; c < 2; ++c) {
      bf16x8 p_frag = *(const bf16x8*)&P_lds[w][ql * 72 + c * 32 + g * 8];
#pragma unroll
      for (int mt = 0; mt < 2; ++mt) {
        bf16x8 v_frag = *(const bf16x8*)&Vt_lds[(mt * 16 + ql) * 72 + c * 32 + g * 8];
        o_acc[mt] = __builtin_amdgcn_mfma_f32_16x16x32_bf16(v_frag, p_frag, o_acc[mt], 0, 0, 0);
      }
    }
  }
  float inv = 1.f / l;
  unsigned short* op = Ob + ((long)(b * N_ + qt * 64 + w * 16 + ql)) * C_ + h * HD_;
#pragma unroll
  for (int mt = 0; mt < 2; ++mt) {
    ushort4v o4 = {f2b(o_acc[mt][0] * inv), f2b(o_acc[mt][1] * inv),
                   f2b(o_acc[mt][2] * inv), f2b(o_acc[mt][3] * inv)};
    *(ushort4v*)(op + mt * 16 + g * 4) = o4;
  }
}

// ---------- K17: LN(lgn) + exact GELU -> (B,C,N) bf16, 8-n tiles, 512 blocks ----------
__global__ __launch_bounds__(256) void k_lngelu(const unsigned short* __restrict__ XO,
                                                const float* __restrict__ lw,
                                                const float* __restrict__ lb,
                                                unsigned short* __restrict__ XI) {
  __shared__ float tile[256][9];
  __shared__ float redp[32][8][2];
  __shared__ float stats[8][2];
  int bx = blockIdx.x;
  int b = bx >> 7, n0 = (bx & 127) * 8;
  int c = threadIdx.x;
#pragma unroll
  for (int j = 0; j < 8; ++j)
    tile[c][j] = b2f(XO[((long)(b * N_ + n0 + j)) * C_ + c]);
  __syncthreads();
  {
    int n = c & 7, g = c >> 3;
    float a = 0.f, q = 0.f;
#pragma unroll
    for (int i = 0; i < 8; ++i) {
      float v = tile[g * 8 + i][n];
      a += v; q += v * v;
    }
    redp[g][n][0] = a; redp[g][n][1] = q;
  }
  __syncthreads();
  if (c < 8) {
    float a = 0.f, q = 0.f;
#pragma unroll
    for (int g2 = 0; g2 < 32; ++g2) { a += redp[g2][c][0]; q += redp[g2][c][1]; }
    float mu = a * (1.f / C_);
    float rs = rsqrtf(q * (1.f / C_) - mu * mu + 1e-5f);
    stats[c][0] = mu; stats[c][1] = rs;
  }
  __syncthreads();
  float wv = lw[c], bv = lb[c];
  float o[8];
#pragma unroll
  for (int j = 0; j < 8; ++j) {
    float x = (tile[c][j] - stats[j][0]) * stats[j][1] * wv + bv;
    o[j] = 0.5f * x * (1.f + erff(x * 0.70710678118654752f));
  }
  unsigned short* dst = &XI[((long)(b * C_ + c)) * N_ + n0];
#pragma unroll
  for (int j4 = 0; j4 < 2; ++j4) {
    ushort4v o4 = {f2b(o[4 * j4]), f2b(o[4 * j4 + 1]), f2b(o[4 * j4 + 2]), f2b(o[4 * j4 + 3])};
    *(ushort4v*)(dst + j4 * 4) = o4;
  }
}

// ---------- K18+K19 fused: ln over (H,W) + depthwise 3x3 per (b,c) plane; bf16 in/out ----------
__global__ __launch_bounds__(256) void k_lnhw_dwc(const unsigned short* __restrict__ XIin,
                                                  const float* __restrict__ w,
                                                  const float* __restrict__ bias,
                                                  unsigned short* __restrict__ XD) {
  __shared__ float pl[32][33];
  __shared__ float red[8];
  long base = (long)blockIdx.x * 1024;
  int c = blockIdx.x & 255;
  int t = threadIdx.x;
  ushort4v v4 = *(const ushort4v*)&XIin[base + t * 4];
  float vx = b2f(v4[0]), vy = b2f(v4[1]), vz = b2f(v4[2]), vw = b2f(v4[3]);
  float a = vx + vy + vz + vw;
  float q = vx * vx + vy * vy + vz * vz + vw * vw;
  float2 s = blockReduce2(a, q, red);
  float mu = s.x * (1.f / 1024.f);
  float rs = rsqrtf(s.y * (1.f / 1024.f) - mu * mu + 1e-5f);
  int hh = t >> 3, w0 = (t & 7) * 4;
  pl[hh][w0 + 0] = (vx - mu) * rs;
  pl[hh][w0 + 1] = (vy - mu) * rs;
  pl[hh][w0 + 2] = (vz - mu) * rs;
  pl[hh][w0 + 3] = (vw - mu) * rs;
  __syncthreads();
  float wk[9];
#pragma unroll
  for (int i = 0; i < 9; ++i) wk[i] = w[c * 9 + i];
  float bv = bias[c];
  float o[4];
#pragma unroll
  for (int j = 0; j < 4; ++j) {
    int ww = w0 + j;
    float acc = bv;
#pragma unroll
    for (int kh = 0; kh < 3; ++kh) {
      int h2 = hh + kh - 1;
      if (h2 < 0 || h2 >= 32) continue;
#pragma unroll
      for (int kw = 0; kw < 3; ++kw) {
        int w2 = ww + kw - 1;
        if (w2 < 0 || w2 >= 32) continue;
        acc += wk[kh * 3 + kw] * pl[h2][w2];
      }
    }
    o[j] = acc;
  }
  ushort4v o4 = {f2b(o[0]), f2b(o[1]), f2b(o[2]), f2b(o[3])};
  *(ushort4v*)&XD[base + t * 4] = o4;
}

// ---------- K20: fused final LN + projection (32-n row tiles, dim3(128,4)); bf16 XD in ----------
__global__ __launch_bounds__(256) void k_lnproj(const unsigned short* __restrict__ XD,
                                                const float* __restrict__ nw,
                                                const float* __restrict__ nbias,
                                                const float* __restrict__ w,
                                                const float* __restrict__ bias,
                                                float* __restrict__ out) {
  __shared__ unsigned short xa[32][72];
  __shared__ unsigned short wb[64][72];
  __shared__ float ps[8][32], pq[8][32];
  __shared__ float mu_s[32], rs_s[32];
  int rb = blockIdx.x;
  int b = rb >> 5, n0 = (rb & 31) * 32;
  int c0 = blockIdx.y * 64;
  int t = threadIdx.x;
  {
    int nl = t & 31, cq = t >> 5;   // 8 groups x 32 channels
    const unsigned short* src = XD + ((long)(b * 256 + cq * 32)) * 1024 + n0 + nl;
    float s = 0.f, q = 0.f;
    for (int i = 0; i < 32; ++i) {
      float v = b2f(src[(long)i * 1024]);
      s += v; q += v * v;
    }
    ps[cq][nl] = s; pq[cq][nl] = q;
  }
  __syncthreads();
  if (t < 32) {
    float s = 0.f, q = 0.f;
#pragma unroll
    for (int g2 = 0; g2 < 8; ++g2) { s += ps[g2][t]; q += pq[g2][t]; }
    float mu = s * (1.f / 256.f);
    float rs = rsqrtf(q * (1.f / 256.f) - mu * mu + 1e-5f);
    mu_s[t] = mu; rs_s[t] = rs;
  }
  int w8 = t >> 6, lane = t & 63, g = lane >> 4, ql = lane & 15;
  int rg = w8 & 1, cp = w8 >> 1;
  const f32x4 zf = {0.f, 0.f, 0.f, 0.f};
  f32x4 acc[2] = {zf, zf};
  int rr = t >> 2, nq = (t & 3) * 8;
  int wr = t >> 2, wk = (t & 3) * 16;
  for (int k0 = 0; k0 < 256; k0 += 64) {
    __syncthreads();
    {
      int ch = k0 + rr;
      const unsigned short* src = XD + ((long)(b * 256 + ch)) * 1024 + n0 + nq;
      float wv_ = nw[ch], bv_ = nbias[ch];
      ushort8v v8 = *(const ushort8v*)src;
#pragma unroll
      for (int e = 0; e < 8; ++e) {
        int n = nq + e;
        xa[n][rr] = f2b((b2f(v8[e]) - mu_s[n]) * rs_s[n] * wv_ + bv_);
      }
      const float* wsrc = w + (long)(c0 + wr) * 256 + k0 + wk;
#pragma unroll
      for (int j = 0; j < 4; ++j) {
        float4 v = *(const float4*)(wsrc + 4 * j);
        ushort4v u = {f2b(v.x), f2b(v.y), f2b(v.z), f2b(v.w)};
        *(ushort4v*)&wb[wr][wk + 4 * j] = u;
      }
    }
    __syncthreads();
#pragma unroll
    for (int ks = 0; ks < 2; ++ks) {
      bf16x8 a = *(const bf16x8*)&xa[rg * 16 + ql][ks * 32 + g * 8];
#pragma unroll
      for (int ct = 0; ct < 2; ++ct) {
        bf16x8 bfr = *(const bf16x8*)&wb[(cp * 2 + ct) * 16 + ql][ks * 32 + g * 8];
        acc[ct] = __builtin_amdgcn_mfma_f32_16x16x32_bf16(a, bfr, acc[ct], 0, 0, 0);
      }
    }
  }
#pragma unroll
  for (int ct = 0; ct < 2; ++ct) {
    int col = c0 + (cp * 2 + ct) * 16 + ql;
    float bv = bias[col];
    long basei = ((long)(b * 256 + col)) * 1024 + n0 + rg * 16 + g * 4;
    *(float4*)(out + basei) = make_float4(acc[ct][0] + bv, acc[ct][1] + bv,
                                          acc[ct][2] + bv, acc[ct][3] + bv);
  }
}

extern "C" void kernel_launch(void* const* d_in, const int* in_sizes, int n_in,
                              void* d_out, int out_size, void* d_ws, size_t ws_size,
                              hipStream_t stream) {
  const float* x        = (const float*)d_in[0];
  const float* norm_w   = (const float*)d_in[1];
  const float* norm_b   = (const float*)d_in[2];
  const float* skip     = (const float*)d_in[3];
  const float* m_inw    = (const float*)d_in[4];
  const float* m_convw  = (const float*)d_in[5];
  const float* m_convb  = (const float*)d_in[6];
  const float* m_xpw    = (const float*)d_in[7];
  const float* m_dtw    = (const float*)d_in[8];
  const float* m_dtb    = (const float*)d_in[9];
  const float* m_alog   = (const float*)d_in[10];
  const float* m_d      = (const float*)d_in[11];
  const float* m_outw   = (const float*)d_in[12];
  const float* qdw_w    = (const float*)d_in[13];
  const float* qdw_b    = (const float*)d_in[14];
  const float* qpw_w    = (const float*)d_in[15];
  const float* qpw_b    = (const float*)d_in[16];
  const float* rdw_w    = (const float*)d_in[17];
  const float* rdw_b    = (const float*)d_in[18];
  const float* rpw_w    = (const float*)d_in[19];
  const float* rpw_b    = (const float*)d_in[20];
  const float* fdw_w    = (const float*)d_in[21];
  const float* fdw_b    = (const float*)d_in[22];
  const float* fpw_w    = (const float*)d_in[23];
  const float* fpw_b    = (const float*)d_in[24];
  const float* lc_w     = (const float*)d_in[25];
  const float* lc_b     = (const float*)d_in[26];
  const float* attn_inw = (const float*)d_in[27];
  const float* attn_inb = (const float*)d_in[28];
  const float* attn_outw= (const float*)d_in[29];
  const float* attn_outb= (const float*)d_in[30];
  const float* lgn_w    = (const float*)d_in[31];
  const float* lgn_b    = (const float*)d_in[32];
  const float* fc_w     = (const float*)d_in[33];
  const float* fc_b     = (const float*)d_in[34];
  const float* dwc_w    = (const float*)d_in[35];
  const float* dwc_b    = (const float*)d_in[36];
  const float* proj_w   = (const float*)d_in[37];
  const float* proj_b   = (const float*)d_in[38];
  float* out = (float*)d_out;

  float* ws = (float*)d_ws;
  const size_t F = 1048576;  // B*N*C
  unsigned short* XNB = (unsigned short*)(ws + 1 * F);   // bf16 XN
  unsigned short* UB  = (unsigned short*)(ws + 2 * F);   // bf16 U
  unsigned short* ZB  = (unsigned short*)(ws + 4 * F);   // bf16 Z
  float* DT  = ws + 6 * F;
  float* BM  = ws + 8 * F;
  float* CM  = ws + 8 * F + F / 4;
  float* XMC = ws + 8 * F + F / 2;
  float* SC_APROD = ws + 8 * F + F / 2;
  float* SC_HEND  = ws + 9 * F;
  float* G   = ws + 0 * F;
  float* XG  = ws + 2 * F;                               // U dead after scanC
  float* RB  = ws + 4 * F + F / 2;                       // Z (bf16, 0.5F) dead after outproj; keep clear of ZB
  unsigned short* XM2B = (unsigned short*)(ws + 5 * F + F / 2);
  unsigned short* QKVB = (unsigned short*)(ws + 1 * F);  // XN dead after outproj
  unsigned short* OB   = (unsigned short*)(ws + 4 * F);  // ZB dead after outproj
  unsigned short* XGLB = (unsigned short*)(ws + 6 * F);  // DT dead after outproj
  unsigned short* XOB  = (unsigned short*)(ws + 7 * F);  // bf16 XO
  unsigned short* XIB  = (unsigned short*)(ws + 8 * F);  // bf16 XI (SC_HEND dead)
  unsigned short* XDB  = (unsigned short*)(ws + 0 * F);  // bf16 XD (G dead)
  (void)ws_size; (void)in_sizes; (void)n_in; (void)out_size;

  k_ln_t2<<<512, 256, 0, stream>>>(x, norm_w, norm_b, XNB);
  k_inproj_conv<<<dim3(64, 16), 256, 0, stream>>>(XNB, m_inw, m_convw, m_convb, UB, ZB);
  k_xdbc_scanA<<<256, 256, 0, stream>>>(UB, m_xpw, m_dtw, m_dtb, m_alog,
                                        DT, BM, CM, SC_APROD, SC_HEND);
  k_scanC<<<512, 256, 0, stream>>>(DT, UB, BM, CM, m_alog, m_d, SC_APROD, SC_HEND);
  k_outproj_mfma<<<dim3(128, 4), 256, 0, stream>>>(DT, ZB, m_outw, XNB, skip, XMC);
  k_gate<<<512, 128, 0, stream>>>(XMC, qdw_w, qdw_b, qpw_w, qpw_b, G);
  k_xg<<<512, 256, 0, stream>>>(XMC, G, XG);
  k_gemm_cm_dw<256><<<dim3(128, 4), 256, 0, stream>>>(XG, nullptr, rdw_w, rdw_b,
                                                      rpw_w, rpw_b, XG, nullptr, RB, nullptr);
  k_gemm_cm_dw<512><<<dim3(128, 4), 256, 0, stream>>>(x, RB, fdw_w, fdw_b,
                                                      fpw_w, fpw_b, nullptr, x, nullptr, XM2B);
  k_gemm_qkv<<<dim3(64, 12), 256, 0, stream>>>(XM2B, attn_inw, attn_inb, QKVB);
  k_attn_mfma<<<512, 256, 0, stream>>>(QKVB, OB);
  k_gemm_attnout<<<dim3(128, 4), 256, 0, stream>>>(OB, attn_outw, attn_outb, XGLB);
  k_gemm_fc<<<dim3(128, 4), 256, 0, stream>>>(XM2B, XGLB, lc_w, lc_b, fc_w, fc_b, XOB);
  k_lngelu<<<512, 256, 0, stream>>>(XOB, lgn_w, lgn_b, XIB);
  k_lnhw_dwc<<<1024, 256, 0, stream>>>(XIB, dwc_w, dwc_b, XDB);
  k_lnproj<<<dim3(128, 4), 256, 0, stream>>>(XDB, norm_w, norm_b, proj_w, proj_b, out);
}

// Round 22
// 184.617 us; speedup vs baseline: 1.1108x; 1.0045x over previous
//
#include <hip/hip_runtime.h>
#include <math.h>

// MambaLiteUNet — round 22: correct gate+xg fusion (full-channel 16-n-tile blocks;
// gate computed once per n, bit-identical order; XMC read once). 16 -> 15 kernels.

namespace {
constexpr int NB_ = 4, DM_ = 64, DIN_ = 128, DS_ = 16, DTR_ = 4;
constexpr int C_ = 256, N_ = 1024, B_ = 4, HD_ = 32;
constexpr int NCH = 16, LCH = 64;          // scan: 16 time-chunks of 64
constexpr int NSTATE = 16 * 128 * 16;      // nbb * DIN * DS = 32768
}

typedef __attribute__((ext_vector_type(8))) short bf16x8;
typedef __attribute__((ext_vector_type(4))) float f32x4;
typedef __attribute__((ext_vector_type(8))) unsigned short ushort8v;
typedef __attribute__((ext_vector_type(4))) unsigned short ushort4v;

// ---------- helpers ----------
__device__ __forceinline__ unsigned short f2b(float f) {  // fp32 -> bf16 RNE
  unsigned int u = __float_as_uint(f);
  unsigned int r = u + 0x7FFFu + ((u >> 16) & 1u);
  return (unsigned short)(r >> 16);
}
__device__ __forceinline__ float b2f(unsigned short u) {
  return __uint_as_float(((unsigned int)u) << 16);
}

__device__ __forceinline__ float2 blockReduce2(float a, float b, float* red) {
#pragma unroll
  for (int m = 1; m < 64; m <<= 1) {
    a += __shfl_xor(a, m, 64);
    b += __shfl_xor(b, m, 64);
  }
  int w = threadIdx.x >> 6;
  if ((threadIdx.x & 63) == 0) { red[2 * w] = a; red[2 * w + 1] = b; }
  __syncthreads();
  float ra = red[0] + red[2] + red[4] + red[6];
  float rb = red[1] + red[3] + red[5] + red[7];
  return make_float2(ra, rb);
}

__device__ __forceinline__ float siluf(float x) { return x / (1.f + expf(-x)); }
__device__ __forceinline__ float sigmf(float x) { return 1.f / (1.f + expf(-x)); }
__device__ __forceinline__ float softplusf(float x) {
  return fmaxf(x, 0.f) + log1pf(expf(-fabsf(x)));
}

// ---------- K1: LN over C of (B,C,N) -> (B,N,C) bf16, 8-n tiles, 512 blocks ----------
__global__ __launch_bounds__(256) void k_ln_t2(const float* __restrict__ in,
                                               const float* __restrict__ w,
                                               const float* __restrict__ bias,
                                               unsigned short* __restrict__ out_ln) {
  __shared__ float tile[256][9];
  __shared__ float redp[32][8][2];
  __shared__ float stats[8][2];
  int bx = blockIdx.x;
  int b = bx >> 7, n0 = (bx & 127) * 8;
  int c = threadIdx.x;
  {
    const float* p = in + ((long)(b * C_ + c)) * N_ + n0;
#pragma unroll
    for (int j = 0; j < 8; ++j) tile[c][j] = p[j];
  }
  __syncthreads();
  {
    int n = c & 7, g = c >> 3;
    float a = 0.f, q = 0.f;
#pragma unroll
    for (int i = 0; i < 8; ++i) {
      float v = tile[g * 8 + i][n];
      a += v; q += v * v;
    }
    redp[g][n][0] = a; redp[g][n][1] = q;
  }
  __syncthreads();
  if (c < 8) {
    float a = 0.f, q = 0.f;
#pragma unroll
    for (int g2 = 0; g2 < 32; ++g2) { a += redp[g2][c][0]; q += redp[g2][c][1]; }
    float mu = a * (1.f / C_);
    float rs = rsqrtf(q * (1.f / C_) - mu * mu + 1e-5f);
    stats[c][0] = mu; stats[c][1] = rs;
  }
  __syncthreads();
  float wv = w[c], bv = bias[c];
#pragma unroll
  for (int j = 0; j < 8; ++j) {
    float v = tile[c][j];
    long o = ((long)(b * N_ + n0 + j)) * C_ + c;
    out_ln[o] = f2b((v - stats[j][0]) * stats[j][1] * wv + bv);
  }
}

// ---------- K2: mamba in-proj (MFMA) + fused causal conv + silu; bf16 XN in, U bf16, Z bf16 ----------
__global__ __launch_bounds__(256) void k_inproj_conv(const unsigned short* __restrict__ xn,
                                                     const float* __restrict__ inw,
                                                     const float* __restrict__ cw,
                                                     const float* __restrict__ cb,
                                                     unsigned short* __restrict__ U,
                                                     unsigned short* __restrict__ Z) {
  __shared__ unsigned short xa[64][72];
  __shared__ unsigned short wb[64][72];
  __shared__ float ut[67][65];
  int r0 = blockIdx.x * 64;
  int nb = blockIdx.y >> 2, q = blockIdx.y & 3, c0 = q * 64;
  int t = threadIdx.x;
  int wv = t >> 6, lane = t & 63, g = lane >> 4, ql = lane & 15;
  const f32x4 zf = {0.f, 0.f, 0.f, 0.f};
  f32x4 acc[4] = {zf, zf, zf, zf};
  int rr = t >> 2, kq = (t & 3) * 16;
  {
    const unsigned short* xsrc = xn + (long)(r0 + rr) * C_ + nb * 64 + kq;
#pragma unroll
    for (int j = 0; j < 2; ++j)
      *(ushort8v*)&xa[rr][kq + 8 * j] = *(const ushort8v*)(xsrc + 8 * j);
    const float* wsrc = inw + ((long)nb * 256 + c0 + rr) * 64 + kq;
#pragma unroll
    for (int j = 0; j < 4; ++j) {
      float4 v = *(const float4*)(wsrc + 4 * j);
      ushort4v u = {f2b(v.x), f2b(v.y), f2b(v.z), f2b(v.w)};
      *(ushort4v*)&wb[rr][kq + 4 * j] = u;
    }
  }
  __syncthreads();
#pragma unroll
  for (int ks = 0; ks < 2; ++ks) {
    bf16x8 a = *(const bf16x8*)&xa[wv * 16 + ql][ks * 32 + g * 8];
#pragma unroll
    for (int ct = 0; ct < 4; ++ct) {
      bf16x8 b = *(const bf16x8*)&wb[ct * 16 + ql][ks * 32 + g * 8];
      acc[ct] = __builtin_amdgcn_mfma_f32_16x16x32_bf16(a, b, acc[ct], 0, 0, 0);
    }
  }
  if (q < 2) {
#pragma unroll
    for (int ct = 0; ct < 4; ++ct)
#pragma unroll
      for (int reg = 0; reg < 4; ++reg)
        ut[3 + wv * 16 + g * 4 + reg][ct * 16 + ql] = acc[ct][reg];
    if (t < 192) {
      int hr = t >> 6, lc = t & 63;
      float hv = 0.f;
      if ((r0 & 1023) != 0) {
        const unsigned short* xrow = xn + (long)(r0 - 3 + hr) * C_ + nb * 64;
        const float* wrow = inw + ((long)nb * 256 + c0 + lc) * 64;
#pragma unroll 8
        for (int k = 0; k < 64; ++k) hv += b2f(xrow[k]) * wrow[k];
      }
      ut[hr][lc] = hv;
    }
    __syncthreads();
#pragma unroll
    for (int ct = 0; ct < 4; ++ct) {
      int lc = ct * 16 + ql;
      int d = c0 + lc;
      const float* cwp = cw + (nb * DIN_ + d) * 4;
      float w0 = cwp[0], w1 = cwp[1], w2 = cwp[2], w3 = cwp[3];
      float bv = cb[nb * DIN_ + d];
#pragma unroll
      for (int reg = 0; reg < 4; ++reg) {
        int lr = wv * 16 + g * 4 + reg;
        float a = bv + w3 * ut[3 + lr][lc] + w2 * ut[2 + lr][lc] +
                  w1 * ut[1 + lr][lc] + w0 * ut[lr][lc];
        long row = (long)nb * 4096 + r0 + lr;
        U[row * DIN_ + d] = f2b(siluf(a));
      }
    }
  } else {
#pragma unroll
    for (int ct = 0; ct < 4; ++ct) {
      int col = c0 - 128 + ct * 16 + ql;
#pragma unroll
      for (int reg = 0; reg < 4; ++reg) {
        long row = (long)nb * 4096 + r0 + wv * 16 + g * 4 + reg;
        Z[row * DIN_ + col] = f2b(acc[ct][reg]);
      }
    }
  }
}

// ---------- K4: xdbc (MFMA, bf16 U in) + dt/Bm/Cm epilogue + fused scan phase A ----------
__global__ __launch_bounds__(256) void k_xdbc_scanA(const unsigned short* __restrict__ U,
                                                    const float* __restrict__ xpw,
                                                    const float* __restrict__ dtw,
                                                    const float* __restrict__ dtb,
                                                    const float* __restrict__ alog,
                                                    float* __restrict__ DT,
                                                    float* __restrict__ BMb,
                                                    float* __restrict__ CMb,
                                                    float* __restrict__ Aprod,
                                                    float* __restrict__ Hend) {
  __shared__ unsigned short u_sb[64][136];
  __shared__ unsigned short wb[48][72];
  __shared__ float xd_s[64][40];
  __shared__ float dtw_s[128][4];
  __shared__ float dtb_s[128];
  __shared__ float dt_s[64][132];
  __shared__ float bm_s[64][20];
  int t = threadIdx.x;
  long row0 = (long)blockIdx.x * 64;
  int nb = blockIdx.x >> 6;
  int nbb = blockIdx.x >> 4, chunk = blockIdx.x & 15;
  for (int i = t; i < 512; i += 256) dtw_s[i >> 2][i & 3] = dtw[nb * 512 + i];
  if (t < 128) dtb_s[t] = dtb[nb * DIN_ + t];
  int wv = t >> 6, lane = t & 63, g = lane >> 4, ql = lane & 15;
  const f32x4 zf = {0.f, 0.f, 0.f, 0.f};
  f32x4 acc[3] = {zf, zf, zf};
  int rr = t >> 2, kq = (t & 3) * 16;
  for (int k0 = 0; k0 < 128; k0 += 64) {
    __syncthreads();
    const unsigned short* xsrc = U + (row0 + rr) * DIN_ + k0 + kq;
#pragma unroll
    for (int j = 0; j < 2; ++j)
      *(ushort8v*)&u_sb[rr][k0 + kq + 8 * j] = *(const ushort8v*)(xsrc + 8 * j);
    if (rr < 48) {
      if (rr < 36) {
        const float* wsrc = xpw + (long)nb * 36 * 128 + rr * 128 + k0 + kq;
#pragma unroll
        for (int j = 0; j < 4; ++j) {
          float4 v = *(const float4*)(wsrc + 4 * j);
          ushort4v u = {f2b(v.x), f2b(v.y), f2b(v.z), f2b(v.w)};
          *(ushort4v*)&wb[rr][kq + 4 * j] = u;
        }
      } else {
        ushort4v z = {0, 0, 0, 0};
#pragma unroll
        for (int j = 0; j < 4; ++j) *(ushort4v*)&wb[rr][kq + 4 * j] = z;
      }
    }
    __syncthreads();
#pragma unroll
    for (int ks = 0; ks < 2; ++ks) {
      bf16x8 a = *(const bf16x8*)&u_sb[wv * 16 + ql][k0 + ks * 32 + g * 8];
#pragma unroll
      for (int ct = 0; ct < 3; ++ct) {
        bf16x8 b = *(const bf16x8*)&wb[ct * 16 + ql][ks * 32 + g * 8];
        acc[ct] = __builtin_amdgcn_mfma_f32_16x16x32_bf16(a, b, acc[ct], 0, 0, 0);
      }
    }
  }
#pragma unroll
  for (int ct = 0; ct < 3; ++ct) {
    int col = ct * 16 + ql;
    if (col < 36) {
#pragma unroll
      for (int reg = 0; reg < 4; ++reg)
        xd_s[wv * 16 + g * 4 + reg][col] = acc[ct][reg];
    }
  }
  __syncthreads();
  {
    int r = t >> 2, sq = (t & 3) * 4;
    float4 bm4 = make_float4(xd_s[r][4 + sq], xd_s[r][5 + sq],
                             xd_s[r][6 + sq], xd_s[r][7 + sq]);
    *(float4*)&BMb[(row0 + r) * DS_ + sq] = bm4;
    *(float4*)&bm_s[r][sq] = bm4;
    float4 cm4 = make_float4(xd_s[r][20 + sq], xd_s[r][21 + sq],
                             xd_s[r][22 + sq], xd_s[r][23 + sq]);
    *(float4*)&CMb[(row0 + r) * DS_ + sq] = cm4;
  }
  {
    int r = t >> 2, dg = t & 3;
    float x0 = xd_s[r][0], x1 = xd_s[r][1], x2 = xd_s[r][2], x3 = xd_s[r][3];
    float* dst = DT + (row0 + r) * DIN_ + dg * 32;
#pragma unroll
    for (int j = 0; j < 8; ++j) {
      float o[4];
#pragma unroll
      for (int e = 0; e < 4; ++e) {
        int d = dg * 32 + j * 4 + e;
        float a = dtb_s[d] + x0 * dtw_s[d][0] + x1 * dtw_s[d][1] +
                  x2 * dtw_s[d][2] + x3 * dtw_s[d][3];
        o[e] = softplusf(a);
      }
      float4 o4 = make_float4(o[0], o[1], o[2], o[3]);
      *(float4*)(dst + j * 4) = o4;
      *(float4*)&dt_s[r][dg * 32 + j * 4] = o4;
    }
  }
  __syncthreads();
  {
    int dl = t >> 2, sg = t & 3;
#pragma unroll
    for (int dh = 0; dh < 2; ++dh) {
      int d = dh * 64 + dl;
      float A[4];
#pragma unroll
      for (int i = 0; i < 4; ++i)
        A[i] = -expf(alog[(nb * DIN_ + d) * DS_ + sg * 4 + i]);
      float h[4] = {0.f, 0.f, 0.f, 0.f};
      float ap[4] = {1.f, 1.f, 1.f, 1.f};
      for (int tt = 0; tt < LCH; ++tt) {
        float dtv = dt_s[tt][d];
        float uv  = b2f(u_sb[tt][d]);
        float cc = dtv * uv;
        float4 bm4 = *(const float4*)&bm_s[tt][sg * 4];
        float bmv[4] = {bm4.x, bm4.y, bm4.z, bm4.w};
#pragma unroll
        for (int i = 0; i < 4; ++i) {
          float dA = __expf(dtv * A[i]);
          h[i] = dA * h[i] + cc * bmv[i];
          ap[i] *= dA;
        }
      }
      long st = (long)chunk * NSTATE + ((nbb << 7) + d) * 16 + sg * 4;
      *(float4*)&Aprod[st] = make_float4(ap[0], ap[1], ap[2], ap[3]);
      *(float4*)&Hend[st]  = make_float4(h[0], h[1], h[2], h[3]);
    }
  }
}

// ---------- K5c: scan phase C — inline carry composition, emit y over DT ----------
__global__ __launch_bounds__(256) void k_scanC(float* __restrict__ DT,
                                               const unsigned short* __restrict__ U,
                                               const float* __restrict__ BMb,
                                               const float* __restrict__ CMb,
                                               const float* __restrict__ alog,
                                               const float* __restrict__ Dp,
                                               const float* __restrict__ Aprod,
                                               const float* __restrict__ Hend) {
  __shared__ float dt_s[64][64];
  __shared__ float u_s[64][64];
  __shared__ float bm_s[64][16];
  __shared__ float cm_s[64][16];
  int bx = blockIdx.x;
  int chunk = bx >> 5, rem = bx & 31, nbb = rem >> 1, dh = rem & 1;
  int nb = nbb >> 2;
  int t = threadIdx.x;
  int dl = t >> 2, sg = t & 3;
  int d = dh * 64 + dl;
  long base = (long)nbb * N_ + chunk * LCH;
#pragma unroll
  for (int j = 0; j < 4; ++j) {
    int f = t + 256 * j;
    int tt = f >> 4, dq = (f & 15) * 4;
    long src = (base + tt) * DIN_ + dh * 64 + dq;
    *(float4*)&dt_s[tt][dq] = *(const float4*)&DT[src];
    ushort4v u4 = *(const ushort4v*)&U[src];
    u_s[tt][dq + 0] = b2f(u4[0]);
    u_s[tt][dq + 1] = b2f(u4[1]);
    u_s[tt][dq + 2] = b2f(u4[2]);
    u_s[tt][dq + 3] = b2f(u4[3]);
  }
  {
    int tt = t >> 2, sq = (t & 3) * 4;
    *(float4*)&bm_s[tt][sq] = *(const float4*)&BMb[(base + tt) * DS_ + sq];
    *(float4*)&cm_s[tt][sq] = *(const float4*)&CMb[(base + tt) * DS_ + sq];
  }
  float A[4];
#pragma unroll
  for (int i = 0; i < 4; ++i)
    A[i] = -expf(alog[(nb * DIN_ + d) * DS_ + sg * 4 + i]);
  float Dv = Dp[nb * DIN_ + d];
  float h[4] = {0.f, 0.f, 0.f, 0.f};
  {
    long state4 = ((nbb << 7) + d) * 16 + sg * 4;
    for (int c = 0; c < chunk; ++c) {
      float4 a4 = *(const float4*)&Aprod[(long)c * NSTATE + state4];
      float4 e4 = *(const float4*)&Hend[(long)c * NSTATE + state4];
      h[0] = e4.x + a4.x * h[0];
      h[1] = e4.y + a4.y * h[1];
      h[2] = e4.z + a4.z * h[2];
      h[3] = e4.w + a4.w * h[3];
    }
  }
  __syncthreads();
  for (int tt = 0; tt < LCH; ++tt) {
    float dtv = dt_s[tt][dl];
    float uv  = u_s[tt][dl];
    float cc = dtv * uv;
    float4 bm4 = *(const float4*)&bm_s[tt][sg * 4];
    float4 cm4 = *(const float4*)&cm_s[tt][sg * 4];
    float bmv[4] = {bm4.x, bm4.y, bm4.z, bm4.w};
    float cmv[4] = {cm4.x, cm4.y, cm4.z, cm4.w};
    float p = 0.f;
#pragma unroll
    for (int i = 0; i < 4; ++i) {
      float dA = __expf(dtv * A[i]);
      h[i] = dA * h[i] + cc * bmv[i];
      p += h[i] * cmv[i];
    }
    p += __shfl_xor(p, 1, 64);
    p += __shfl_xor(p, 2, 64);
    if (sg == 0) DT[(base + tt) * DIN_ + d] = p + Dv * uv;
  }
}

// ---------- K6: out-proj (MFMA, 32-row tile): xm = (y*silu(z)) @ outw^T + skip*xn ----------
__global__ __launch_bounds__(256) void k_outproj_mfma(const float* __restrict__ Y,
                                                      const unsigned short* __restrict__ Zb,
                                                      const float* __restrict__ outw,
                                                      const unsigned short* __restrict__ xn,
                                                      const float* __restrict__ skip,
                                                      float* __restrict__ XMC) {
  __shared__ unsigned short xa[32][72];
  __shared__ unsigned short wb[64][72];
  int r0 = blockIdx.x * 32;
  int nb = blockIdx.y;
  int t = threadIdx.x;
  int w = t >> 6, lane = t & 63, g = lane >> 4, ql = lane & 15;
  int rg = w & 1, cp = w >> 1;
  const f32x4 zf = {0.f, 0.f, 0.f, 0.f};
  f32x4 acc[2] = {zf, zf};
  int ar = t >> 3, ak = (t & 7) * 8;
  int wr = t >> 2, wk = (t & 3) * 16;
  for (int k0 = 0; k0 < 128; k0 += 64) {
    __syncthreads();
    long row = (long)nb * 4096 + r0 + ar;
    const float* ysrc = Y + row * DIN_ + k0 + ak;
    const unsigned short* zsrc = Zb + row * DIN_ + k0 + ak;
#pragma unroll
    for (int j = 0; j < 2; ++j) {
      float4 yv = *(const float4*)(ysrc + 4 * j);
      ushort4v z4 = *(const ushort4v*)(zsrc + 4 * j);
      ushort4v u = {f2b(yv.x * siluf(b2f(z4[0]))), f2b(yv.y * siluf(b2f(z4[1]))),
                    f2b(yv.z * siluf(b2f(z4[2]))), f2b(yv.w * siluf(b2f(z4[3])))};
      *(ushort4v*)&xa[ar][ak + 4 * j] = u;
    }
    const float* wsrc = outw + ((long)nb * 64 + wr) * 128 + k0 + wk;
#pragma unroll
    for (int j = 0; j < 4; ++j) {
      float4 v = *(const float4*)(wsrc + 4 * j);
      ushort4v u = {f2b(v.x), f2b(v.y), f2b(v.z), f2b(v.w)};
      *(ushort4v*)&wb[wr][wk + 4 * j] = u;
    }
    __syncthreads();
#pragma unroll
    for (int ks = 0; ks < 2; ++ks) {
      bf16x8 a = *(const bf16x8*)&xa[rg * 16 + ql][ks * 32 + g * 8];
#pragma unroll
      for (int ct = 0; ct < 2; ++ct) {
        bf16x8 b = *(const bf16x8*)&wb[(cp * 2 + ct) * 16 + ql][ks * 32 + g * 8];
        acc[ct] = __builtin_amdgcn_mfma_f32_16x16x32_bf16(a, b, acc[ct], 0, 0, 0);
      }
    }
  }
  float sk = skip[0];
#pragma unroll
  for (int ct = 0; ct < 2; ++ct) {
    int col = (cp * 2 + ct) * 16 + ql;
#pragma unroll
    for (int reg = 0; reg < 4; ++reg) {
      int bn = r0 + rg * 16 + g * 4 + reg;
      long oc = (long)bn * C_ + nb * 64 + col;
      XMC[oc] = acc[ct][reg] + sk * b2f(xn[oc]);
    }
  }
}

// ---------- K7+K8 fused: gate (once per n, full-channel tile) + xg transpose-apply ----------
// grid: B * 64 tiles of 16 n. Block loads XMC rows [n0-1, n0+16] x 256 ch into LDS,
// computes gate exactly once per n (same accumulation order as standalone k_gate),
// then writes XG = g * xm channel-major.
__global__ __launch_bounds__(256) void k_gatexg(const float* __restrict__ XMC,
                                                const float* __restrict__ qdw_w,
                                                const float* __restrict__ qdw_b,
                                                const float* __restrict__ qpw_w,
                                                const float* __restrict__ qpw_b,
                                                float* __restrict__ XG) {
  __shared__ float tile[256][19];   // [c][j], j=0..17 -> rows n0-1 .. n0+16
  __shared__ float gg[16][4];
  int bx = blockIdx.x;
  int b = bx >> 6, nt = bx & 63, n0 = nt * 16;
  int t = threadIdx.x;
  {
    int c = t;
#pragma unroll 6
    for (int j = 0; j < 18; ++j) {
      int nn = n0 - 1 + j;
      tile[c][j] = (nn >= 0 && nn < N_) ? XMC[((long)(b * N_ + nn)) * C_ + c] : 0.f;
    }
  }
  __syncthreads();
  {
    int n = t >> 4, p = (t >> 2) & 3, cq = t & 3;
    float a = 0.f;
#pragma unroll
    for (int k = 0; k < 3; ++k) {
      int nn = n0 + n + k - 1;
      if (nn < 0 || nn >= N_) continue;
      int j = n + k;
      const float* wr = qdw_w + (p * 64 + cq * 16) * 3 + k;
      int cbase = p * 64 + cq * 16;
#pragma unroll
      for (int i = 0; i < 16; ++i) a += tile[cbase + i][j] * wr[i * 3];
    }
    a += __shfl_xor(a, 1, 64);
    a += __shfl_xor(a, 2, 64);
    float q1 = a + qdw_b[p];
    int lane = t & 63;
    float q1g[4];
#pragma unroll
    for (int pp = 0; pp < 4; ++pp) q1g[pp] = __shfl(q1, (lane & ~15) | (pp << 2), 64);
    float r = qpw_b[p];
#pragma unroll
    for (int pp = 0; pp < 4; ++pp) r += qpw_w[p * 4 + pp] * q1g[pp];
    if (cq == 0) gg[n][p] = sigmf(r);
  }
  __syncthreads();
  {
    int cb = t >> 2, nq = (t & 3) * 4;
#pragma unroll
    for (int rep = 0; rep < 4; ++rep) {
      int c = cb + rep * 64;
      int p = c >> 6;
      float4 o;
      o.x = gg[nq + 0][p] * tile[c][1 + nq + 0];
      o.y = gg[nq + 1][p] * tile[c][1 + nq + 1];
      o.z = gg[nq + 2][p] * tile[c][1 + nq + 2];
      o.w = gg[nq + 3][p] * tile[c][1 + nq + 3];
      *(float4*)&XG[((long)(b * C_ + c)) * N_ + n0 + nq] = o;
    }
  }
}

// ---------- MFMA GEMM (32-n tile), channel-major, 3-tap dw conv fused ----------
template <int KD>
__global__ __launch_bounds__(256) void k_gemm_cm_dw(const float* __restrict__ inA,
                                                    const float* __restrict__ inB,
                                                    const float* __restrict__ dww,
                                                    const float* __restrict__ dwb,
                                                    const float* __restrict__ w,
                                                    const float* __restrict__ bias,
                                                    const float* __restrict__ residCM,
                                                    const float* __restrict__ residXCM,
                                                    float* __restrict__ outCM,
                                                    unsigned short* __restrict__ outRMb) {
  __shared__ unsigned short xa[32][72];  // [n][k]
  __shared__ unsigned short wb[64][72];  // [cout][k]
  int rb = blockIdx.x;
  int b = rb >> 5, n0 = (rb & 31) * 32;
  int c0 = blockIdx.y * 64;
  int t = threadIdx.x;
  int w8 = t >> 6, lane = t & 63, g = lane >> 4, ql = lane & 15;
  int rg = w8 & 1, cp = w8 >> 1;
  const f32x4 zf = {0.f, 0.f, 0.f, 0.f};
  f32x4 acc[2] = {zf, zf};
  int cr = t >> 2, nq = (t & 3) * 8;
  int wr = t >> 2, wk = (t & 3) * 16;
  for (int k0 = 0; k0 < KD; k0 += 64) {
    __syncthreads();
    {
      int k = k0 + cr;
      const float* src = (inB != nullptr && k >= 256)
                             ? inB + ((long)(b * 256 + k - 256)) * 1024
                             : inA + ((long)(b * 256 + k)) * 1024;
      float w0 = dww[k * 3], w1 = dww[k * 3 + 1], w2 = dww[k * 3 + 2], bv = dwb[k];
#pragma unroll
      for (int j = 0; j < 2; ++j) {
        int nb4 = n0 + nq + 4 * j;
        float4 v = *(const float4*)&src[nb4];
        float vm1 = (nb4 > 0) ? src[nb4 - 1] : 0.f;
        float vp4 = (nb4 + 4 < 1024) ? src[nb4 + 4] : 0.f;
        xa[nq + 4 * j + 0][cr] = f2b(bv + w0 * vm1 + w1 * v.x + w2 * v.y);
        xa[nq + 4 * j + 1][cr] = f2b(bv + w0 * v.x + w1 * v.y + w2 * v.z);
        xa[nq + 4 * j + 2][cr] = f2b(bv + w0 * v.y + w1 * v.z + w2 * v.w);
        xa[nq + 4 * j + 3][cr] = f2b(bv + w0 * v.z + w1 * v.w + w2 * vp4);
      }
    }
    const float* wsrc = w + (long)(c0 + wr) * KD + k0 + wk;
#pragma unroll
    for (int j = 0; j < 4; ++j) {
      float4 v = *(const float4*)(wsrc + 4 * j);
      ushort4v u = {f2b(v.x), f2b(v.y), f2b(v.z), f2b(v.w)};
      *(ushort4v*)&wb[wr][wk + 4 * j] = u;
    }
    __syncthreads();
#pragma unroll
    for (int ks = 0; ks < 2; ++ks) {
      bf16x8 a = *(const bf16x8*)&xa[rg * 16 + ql][ks * 32 + g * 8];
#pragma unroll
      for (int ct = 0; ct < 2; ++ct) {
        bf16x8 bfr = *(const bf16x8*)&wb[(cp * 2 + ct) * 16 + ql][ks * 32 + g * 8];
        acc[ct] = __builtin_amdgcn_mfma_f32_16x16x32_bf16(a, bfr, acc[ct], 0, 0, 0);
      }
    }
  }
#pragma unroll
  for (int ct = 0; ct < 2; ++ct) {
    int col = c0 + (cp * 2 + ct) * 16 + ql;
    float bv = bias[col];
    if (outCM) {
      long base = ((long)(b * 256 + col)) * 1024 + n0 + rg * 16 + g * 4;
      float4 r4 = *(const float4*)(residCM + base);
      float4 o = make_float4(acc[ct][0] + bv + r4.x, acc[ct][1] + bv + r4.y,
                             acc[ct][2] + bv + r4.z, acc[ct][3] + bv + r4.w);
      *(float4*)(outCM + base) = o;
    } else {
      int nbase = n0 + rg * 16 + g * 4;
      float4 r4 = *(const float4*)&residXCM[((long)(b * 256 + col)) * 1024 + nbase];
      float rv[4] = {r4.x, r4.y, r4.z, r4.w};
#pragma unroll
      for (int reg = 0; reg < 4; ++reg) {
        long row = (long)b * 1024 + nbase + reg;
        outRMb[row * 256 + col] = f2b(acc[ct][reg] + bv + rv[reg]);
      }
    }
  }
}

// ---------- K13: QKV GEMM — bf16 XM2 in, bf16 out ----------
__global__ __launch_bounds__(256) void k_gemm_qkv(const unsigned short* __restrict__ in,
                                                  const float* __restrict__ w,
                                                  const float* __restrict__ bias,
                                                  unsigned short* __restrict__ out) {
  __shared__ unsigned short xa[64][72];
  __shared__ unsigned short wb[64][72];
  int r0 = blockIdx.x * 64;
  int c0 = blockIdx.y * 64;
  int t = threadIdx.x;
  int wv = t >> 6, lane = t & 63, g = lane >> 4, ql = lane & 15;
  const f32x4 zf = {0.f, 0.f, 0.f, 0.f};
  f32x4 acc[4] = {zf, zf, zf, zf};
  int rr = t >> 2, kq = (t & 3) * 16;
  for (int k0 = 0; k0 < 256; k0 += 64) {
    __syncthreads();
    const unsigned short* xsrc = in + (long)(r0 + rr) * 256 + k0 + kq;
#pragma unroll
    for (int j = 0; j < 2; ++j)
      *(ushort8v*)&xa[rr][kq + 8 * j] = *(const ushort8v*)(xsrc + 8 * j);
    const float* wsrc = w + (long)(c0 + rr) * 256 + k0 + kq;
#pragma unroll
    for (int j = 0; j < 4; ++j) {
      float4 v = *(const float4*)(wsrc + 4 * j);
      ushort4v u = {f2b(v.x), f2b(v.y), f2b(v.z), f2b(v.w)};
      *(ushort4v*)&wb[rr][kq + 4 * j] = u;
    }
    __syncthreads();
#pragma unroll
    for (int ks = 0; ks < 2; ++ks) {
      bf16x8 a = *(const bf16x8*)&xa[wv * 16 + ql][ks * 32 + g * 8];
#pragma unroll
      for (int ct = 0; ct < 4; ++ct) {
        bf16x8 b = *(const bf16x8*)&wb[ct * 16 + ql][ks * 32 + g * 8];
        acc[ct] = __builtin_amdgcn_mfma_f32_16x16x32_bf16(a, b, acc[ct], 0, 0, 0);
      }
    }
  }
#pragma unroll
  for (int ct = 0; ct < 4; ++ct) {
    int col = c0 + ct * 16 + ql;
    float bv = bias[col];
#pragma unroll
    for (int reg = 0; reg < 4; ++reg) {
      long row = r0 + wv * 16 + g * 4 + reg;
      out[row * 768 + col] = f2b(acc[ct][reg] + bv);
    }
  }
}

// ---------- K15: attn-out GEMM (32-row tile) — bf16 in/out ----------
__global__ __launch_bounds__(256) void k_gemm_attnout(const unsigned short* __restrict__ inA,
                                                      const float* __restrict__ w,
                                                      const float* __restrict__ bias,
                                                      unsigned short* __restrict__ out) {
  __shared__ unsigned short xa[32][72];
  __shared__ unsigned short wb[64][72];
  int r0 = blockIdx.x * 32;
  int c0 = blockIdx.y * 64;
  int t = threadIdx.x;
  int w8 = t >> 6, lane = t & 63, g = lane >> 4, ql = lane & 15;
  int rg = w8 & 1, cp = w8 >> 1;
  const f32x4 zf = {0.f, 0.f, 0.f, 0.f};
  f32x4 acc[2] = {zf, zf};
  int ar = t >> 3, ak = (t & 7) * 8;
  int wr = t >> 2, wk = (t & 3) * 16;
  for (int k0 = 0; k0 < 256; k0 += 64) {
    __syncthreads();
    const unsigned short* xsrc = inA + (long)(r0 + ar) * 256 + k0 + ak;
    *(ushort8v*)&xa[ar][ak] = *(const ushort8v*)xsrc;
    const float* wsrc = w + (long)(c0 + wr) * 256 + k0 + wk;
#pragma unroll
    for (int j = 0; j < 4; ++j) {
      float4 v = *(const float4*)(wsrc + 4 * j);
      ushort4v u = {f2b(v.x), f2b(v.y), f2b(v.z), f2b(v.w)};
      *(ushort4v*)&wb[wr][wk + 4 * j] = u;
    }
    __syncthreads();
#pragma unroll
    for (int ks = 0; ks < 2; ++ks) {
      bf16x8 a = *(const bf16x8*)&xa[rg * 16 + ql][ks * 32 + g * 8];
#pragma unroll
      for (int ct = 0; ct < 2; ++ct) {
        bf16x8 b = *(const bf16x8*)&wb[(cp * 2 + ct) * 16 + ql][ks * 32 + g * 8];
        acc[ct] = __builtin_amdgcn_mfma_f32_16x16x32_bf16(a, b, acc[ct], 0, 0, 0);
      }
    }
  }
#pragma unroll
  for (int ct = 0; ct < 2; ++ct) {
    int col = c0 + (cp * 2 + ct) * 16 + ql;
    float bv = bias[col];
#pragma unroll
    for (int reg = 0; reg < 4; ++reg) {
      long row = r0 + rg * 16 + g * 4 + reg;
      out[row * 256 + col] = f2b(acc[ct][reg] + bv);
    }
  }
}

// ---------- K16: fc GEMM (32-row tile) with x_local row-conv fused; bf16 XO out ----------
__global__ __launch_bounds__(256) void k_gemm_fc(const unsigned short* __restrict__ XM2,
                                                 const unsigned short* __restrict__ XGL,
                                                 const float* __restrict__ lcw,
                                                 const float* __restrict__ lcb,
                                                 const float* __restrict__ w,
                                                 const float* __restrict__ bias,
                                                 unsigned short* __restrict__ out) {
  __shared__ unsigned short xa[32][72];
  __shared__ unsigned short wb[64][72];
  int r0 = blockIdx.x * 32;
  int c0 = blockIdx.y * 64;
  int t = threadIdx.x;
  int w8 = t >> 6, lane = t & 63, g = lane >> 4, ql = lane & 15;
  int rg = w8 & 1, cp = w8 >> 1;
  const f32x4 zf = {0.f, 0.f, 0.f, 0.f};
  f32x4 acc[2] = {zf, zf};
  int ar = t >> 3, ak = (t & 7) * 8;
  int wr = t >> 2, wk = (t & 3) * 16;
  for (int k0 = 0; k0 < 512; k0 += 64) {
    __syncthreads();
    int kk = k0 + ak;
    long row = r0 + ar;
    if (kk < 256) {
      int n = (int)(row & 1023);
      const unsigned short* pc = XM2 + row * 256 + kk;
      bool hm = n > 0, hp = n < 1023;
#pragma unroll
      for (int j = 0; j < 2; ++j) {
        ushort4v v4 = *(const ushort4v*)(pc + 4 * j);
        ushort4v zm = {0, 0, 0, 0};
        ushort4v vm4 = hm ? *(const ushort4v*)(pc - 256 + 4 * j) : zm;
        ushort4v vp4 = hp ? *(const ushort4v*)(pc + 256 + 4 * j) : zm;
        int c = kk + 4 * j;
#pragma unroll
        for (int e = 0; e < 4; ++e) {
          float vv = b2f(v4[e]);
          float vmv = hm ? b2f(vm4[e]) : 0.f;
          float vpv = hp ? b2f(vp4[e]) : 0.f;
          xa[ar][ak + 4 * j + e] = f2b(lcb[c + e] + lcw[(c + e) * 3] * vmv +
                                       lcw[(c + e) * 3 + 1] * vv +
                                       lcw[(c + e) * 3 + 2] * vpv);
        }
      }
    } else {
      const unsigned short* xsrc = XGL + row * 256 + (kk - 256);
      *(ushort8v*)&xa[ar][ak] = *(const ushort8v*)xsrc;
    }
    const float* wsrc = w + (long)(c0 + wr) * 512 + k0 + wk;
#pragma unroll
    for (int j = 0; j < 4; ++j) {
      float4 v = *(const float4*)(wsrc + 4 * j);
      ushort4v u = {f2b(v.x), f2b(v.y), f2b(v.z), f2b(v.w)};
      *(ushort4v*)&wb[wr][wk + 4 * j] = u;
    }
    __syncthreads();
#pragma unroll
    for (int ks = 0; ks < 2; ++ks) {
      bf16x8 a = *(const bf16x8*)&xa[rg * 16 + ql][ks * 32 + g * 8];
#pragma unroll
      for (int ct = 0; ct < 2; ++ct) {
        bf16x8 b = *(const bf16x8*)&wb[(cp * 2 + ct) * 16 + ql][ks * 32 + g * 8];
        acc[ct] = __builtin_amdgcn_mfma_f32_16x16x32_bf16(a, b, acc[ct], 0, 0, 0);
      }
    }
  }
#pragma unroll
  for (int ct = 0; ct < 2; ++ct) {
    int col = c0 + (cp * 2 + ct) * 16 + ql;
    float bv = bias[col];
#pragma unroll
    for (int reg = 0; reg < 4; ++reg) {
      long row = r0 + rg * 16 + g * 4 + reg;
      out[row * 256 + col] = f2b(acc[ct][reg] + bv);
    }
  }
}

// ---------- K14: MFMA bf16 flash attention (bf16 QKV input, bf16 O output) ----------
__global__ __launch_bounds__(256) void k_attn_mfma(const unsigned short* __restrict__ qkvb,
                                                   unsigned short* __restrict__ Ob) {
  __shared__ unsigned short K_lds[64 * 40];
  __shared__ unsigned short Vt_lds[32 * 72];
  __shared__ unsigned short P_lds[4][16 * 72];
  int bx = blockIdx.x;
  int bh = bx >> 4, qt = bx & 15;
  int b = bh >> 3, h = bh & 7;
  int t = threadIdx.x;
  int w = t >> 6, lane = t & 63;
  int g = lane >> 4, ql = lane & 15;
  const float qscale = 0.17677669529663687f * 1.44269504088896341f;  // 1/sqrt(32)*log2(e)

  bf16x8 q_frag = *(const bf16x8*)(qkvb + ((long)(b * N_ + qt * 64 + w * 16 + ql)) * 768 + h * HD_ + g * 8);
  float m = -1e30f, l = 0.f;
  f32x4 o_acc[2];
  const f32x4 zf = {0.f, 0.f, 0.f, 0.f};
  o_acc[0] = zf; o_acc[1] = zf;

  for (int kt = 0; kt < 16; ++kt) {
    __syncthreads();
    {
      int kr = t >> 2, d0 = (t & 3) * 8;
      const unsigned short* gp = qkvb + ((long)(b * N_ + kt * 64 + kr)) * 768 + 256 + h * HD_ + d0;
      ushort8v kv = *(const ushort8v*)gp;
      *(ushort8v*)&K_lds[kr * 40 + d0] = kv;
      ushort8v vv = *(const ushort8v*)(gp + 256);
#pragma unroll
      for (int i = 0; i < 8; ++i) Vt_lds[(d0 + i) * 72 + kr] = vv[i];
    }
    __syncthreads();
    f32x4 s_frag[4];
#pragma unroll
    for (int s = 0; s < 4; ++s) {
      bf16x8 k_frag = *(const bf16x8*)&K_lds[(s * 16 + ql) * 40 + g * 8];
      s_frag[s] = __builtin_amdgcn_mfma_f32_16x16x32_bf16(k_frag, q_frag, zf, 0, 0, 0);
    }
    float sv[16];
#pragma unroll
    for (int s = 0; s < 4; ++s)
#pragma unroll
      for (int r = 0; r < 4; ++r) sv[s * 4 + r] = s_frag[s][r] * qscale;
    float tmax = sv[0];
#pragma unroll
    for (int i = 1; i < 16; ++i) tmax = fmaxf(tmax, sv[i]);
    tmax = fmaxf(tmax, __shfl_xor(tmax, 16));
    tmax = fmaxf(tmax, __shfl_xor(tmax, 32));
    float mn = fmaxf(m, tmax);
    float corr = exp2f(m - mn);
    float psum = 0.f;
    unsigned short pb[16];
#pragma unroll
    for (int i = 0; i < 16; ++i) {
      float p = exp2f(sv[i] - mn);
      psum += p;
      pb[i] = f2b(p);
    }
    psum += __shfl_xor(psum, 16);
    psum += __shfl_xor(psum, 32);
    l = l * corr + psum;
    m = mn;
#pragma unroll
    for (int mt = 0; mt < 2; ++mt)
#pragma unroll
      for (int r = 0; r < 4; ++r) o_acc[mt][r] *= corr;
#pragma unroll
    for (int s = 0; s < 4; ++s) {
      ushort4v p4 = {pb[s * 4], pb[s * 4 + 1], pb[s * 4 + 2], pb[s * 4 + 3]};
      *(ushort4v*)&P_lds[w][ql * 72 + s * 16 + g * 4] = p4;
    }
#pragma unroll
    for (int c = 0; c < 2; ++c) {
      bf16x8 p_frag = *(const bf16x8*)&P_lds[w][ql * 72 + c * 32 + g * 8];
#pragma unroll
      for (int mt = 0; mt < 2; ++mt) {
        bf16x8 v_frag = *(const bf16x8*)&Vt_lds[(mt * 16 + ql) * 72 + c * 32 + g * 8];
        o_acc[mt] = __builtin_amdgcn_mfma_f32_16x16x32_bf16(v_frag, p_frag, o_acc[mt], 0, 0, 0);
      }
    }
  }
  float inv = 1.f / l;
  unsigned short* op = Ob + ((long)(b * N_ + qt * 64 + w * 16 + ql)) * C_ + h * HD_;
#pragma unroll
  for (int mt = 0; mt < 2; ++mt) {
    ushort4v o4 = {f2b(o_acc[mt][0] * inv), f2b(o_acc[mt][1] * inv),
                   f2b(o_acc[mt][2] * inv), f2b(o_acc[mt][3] * inv)};
    *(ushort4v*)(op + mt * 16 + g * 4) = o4;
  }
}

// ---------- K17: LN(lgn) + exact GELU -> (B,C,N) bf16, 8-n tiles, 512 blocks ----------
__global__ __launch_bounds__(256) void k_lngelu(const unsigned short* __restrict__ XO,
                                                const float* __restrict__ lw,
                                                const float* __restrict__ lb,
                                                unsigned short* __restrict__ XI) {
  __shared__ float tile[256][9];
  __shared__ float redp[32][8][2];
  __shared__ float stats[8][2];
  int bx = blockIdx.x;
  int b = bx >> 7, n0 = (bx & 127) * 8;
  int c = threadIdx.x;
#pragma unroll
  for (int j = 0; j < 8; ++j)
    tile[c][j] = b2f(XO[((long)(b * N_ + n0 + j)) * C_ + c]);
  __syncthreads();
  {
    int n = c & 7, g = c >> 3;
    float a = 0.f, q = 0.f;
#pragma unroll
    for (int i = 0; i < 8; ++i) {
      float v = tile[g * 8 + i][n];
      a += v; q += v * v;
    }
    redp[g][n][0] = a; redp[g][n][1] = q;
  }
  __syncthreads();
  if (c < 8) {
    float a = 0.f, q = 0.f;
#pragma unroll
    for (int g2 = 0; g2 < 32; ++g2) { a += redp[g2][c][0]; q += redp[g2][c][1]; }
    float mu = a * (1.f / C_);
    float rs = rsqrtf(q * (1.f / C_) - mu * mu + 1e-5f);
    stats[c][0] = mu; stats[c][1] = rs;
  }
  __syncthreads();
  float wv = lw[c], bv = lb[c];
  float o[8];
#pragma unroll
  for (int j = 0; j < 8; ++j) {
    float x = (tile[c][j] - stats[j][0]) * stats[j][1] * wv + bv;
    o[j] = 0.5f * x * (1.f + erff(x * 0.70710678118654752f));
  }
  unsigned short* dst = &XI[((long)(b * C_ + c)) * N_ + n0];
#pragma unroll
  for (int j4 = 0; j4 < 2; ++j4) {
    ushort4v o4 = {f2b(o[4 * j4]), f2b(o[4 * j4 + 1]), f2b(o[4 * j4 + 2]), f2b(o[4 * j4 + 3])};
    *(ushort4v*)(dst + j4 * 4) = o4;
  }
}

// ---------- K18+K19 fused: ln over (H,W) + depthwise 3x3 per (b,c) plane; bf16 in/out ----------
__global__ __launch_bounds__(256) void k_lnhw_dwc(const unsigned short* __restrict__ XIin,
                                                  const float* __restrict__ w,
                                                  const float* __restrict__ bias,
                                                  unsigned short* __restrict__ XD) {
  __shared__ float pl[32][33];
  __shared__ float red[8];
  long base = (long)blockIdx.x * 1024;
  int c = blockIdx.x & 255;
  int t = threadIdx.x;
  ushort4v v4 = *(const ushort4v*)&XIin[base + t * 4];
  float vx = b2f(v4[0]), vy = b2f(v4[1]), vz = b2f(v4[2]), vw = b2f(v4[3]);
  float a = vx + vy + vz + vw;
  float q = vx * vx + vy * vy + vz * vz + vw * vw;
  float2 s = blockReduce2(a, q, red);
  float mu = s.x * (1.f / 1024.f);
  float rs = rsqrtf(s.y * (1.f / 1024.f) - mu * mu + 1e-5f);
  int hh = t >> 3, w0 = (t & 7) * 4;
  pl[hh][w0 + 0] = (vx - mu) * rs;
  pl[hh][w0 + 1] = (vy - mu) * rs;
  pl[hh][w0 + 2] = (vz - mu) * rs;
  pl[hh][w0 + 3] = (vw - mu) * rs;
  __syncthreads();
  float wk[9];
#pragma unroll
  for (int i = 0; i < 9; ++i) wk[i] = w[c * 9 + i];
  float bv = bias[c];
  float o[4];
#pragma unroll
  for (int j = 0; j < 4; ++j) {
    int ww = w0 + j;
    float acc = bv;
#pragma unroll
    for (int kh = 0; kh < 3; ++kh) {
      int h2 = hh + kh - 1;
      if (h2 < 0 || h2 >= 32) continue;
#pragma unroll
      for (int kw = 0; kw < 3; ++kw) {
        int w2 = ww + kw - 1;
        if (w2 < 0 || w2 >= 32) continue;
        acc += wk[kh * 3 + kw] * pl[h2][w2];
      }
    }
    o[j] = acc;
  }
  ushort4v o4 = {f2b(o[0]), f2b(o[1]), f2b(o[2]), f2b(o[3])};
  *(ushort4v*)&XD[base + t * 4] = o4;
}

// ---------- K20: fused final LN + projection (32-n row tiles, dim3(128,4)); bf16 XD in ----------
__global__ __launch_bounds__(256) void k_lnproj(const unsigned short* __restrict__ XD,
                                                const float* __restrict__ nw,
                                                const float* __restrict__ nbias,
                                                const float* __restrict__ w,
                                                const float* __restrict__ bias,
                                                float* __restrict__ out) {
  __shared__ unsigned short xa[32][72];
  __shared__ unsigned short wb[64][72];
  __shared__ float ps[8][32], pq[8][32];
  __shared__ float mu_s[32], rs_s[32];
  int rb = blockIdx.x;
  int b = rb >> 5, n0 = (rb & 31) * 32;
  int c0 = blockIdx.y * 64;
  int t = threadIdx.x;
  {
    int nl = t & 31, cq = t >> 5;   // 8 groups x 32 channels
    const unsigned short* src = XD + ((long)(b * 256 + cq * 32)) * 1024 + n0 + nl;
    float s = 0.f, q = 0.f;
    for (int i = 0; i < 32; ++i) {
      float v = b2f(src[(long)i * 1024]);
      s += v; q += v * v;
    }
    ps[cq][nl] = s; pq[cq][nl] = q;
  }
  __syncthreads();
  if (t < 32) {
    float s = 0.f, q = 0.f;
#pragma unroll
    for (int g2 = 0; g2 < 8; ++g2) { s += ps[g2][t]; q += pq[g2][t]; }
    float mu = s * (1.f / 256.f);
    float rs = rsqrtf(q * (1.f / 256.f) - mu * mu + 1e-5f);
    mu_s[t] = mu; rs_s[t] = rs;
  }
  int w8 = t >> 6, lane = t & 63, g = lane >> 4, ql = lane & 15;
  int rg = w8 & 1, cp = w8 >> 1;
  const f32x4 zf = {0.f, 0.f, 0.f, 0.f};
  f32x4 acc[2] = {zf, zf};
  int rr = t >> 2, nq = (t & 3) * 8;
  int wr = t >> 2, wk = (t & 3) * 16;
  for (int k0 = 0; k0 < 256; k0 += 64) {
    __syncthreads();
    {
      int ch = k0 + rr;
      const unsigned short* src = XD + ((long)(b * 256 + ch)) * 1024 + n0 + nq;
      float wv_ = nw[ch], bv_ = nbias[ch];
      ushort8v v8 = *(const ushort8v*)src;
#pragma unroll
      for (int e = 0; e < 8; ++e) {
        int n = nq + e;
        xa[n][rr] = f2b((b2f(v8[e]) - mu_s[n]) * rs_s[n] * wv_ + bv_);
      }
      const float* wsrc = w + (long)(c0 + wr) * 256 + k0 + wk;
#pragma unroll
      for (int j = 0; j < 4; ++j) {
        float4 v = *(const float4*)(wsrc + 4 * j);
        ushort4v u = {f2b(v.x), f2b(v.y), f2b(v.z), f2b(v.w)};
        *(ushort4v*)&wb[wr][wk + 4 * j] = u;
      }
    }
    __syncthreads();
#pragma unroll
    for (int ks = 0; ks < 2; ++ks) {
      bf16x8 a = *(const bf16x8*)&xa[rg * 16 + ql][ks * 32 + g * 8];
#pragma unroll
      for (int ct = 0; ct < 2; ++ct) {
        bf16x8 bfr = *(const bf16x8*)&wb[(cp * 2 + ct) * 16 + ql][ks * 32 + g * 8];
        acc[ct] = __builtin_amdgcn_mfma_f32_16x16x32_bf16(a, bfr, acc[ct], 0, 0, 0);
      }
    }
  }
#pragma unroll
  for (int ct = 0; ct < 2; ++ct) {
    int col = c0 + (cp * 2 + ct) * 16 + ql;
    float bv = bias[col];
    long basei = ((long)(b * 256 + col)) * 1024 + n0 + rg * 16 + g * 4;
    *(float4*)(out + basei) = make_float4(acc[ct][0] + bv, acc[ct][1] + bv,
                                          acc[ct][2] + bv, acc[ct][3] + bv);
  }
}

extern "C" void kernel_launch(void* const* d_in, const int* in_sizes, int n_in,
                              void* d_out, int out_size, void* d_ws, size_t ws_size,
                              hipStream_t stream) {
  const float* x        = (const float*)d_in[0];
  const float* norm_w   = (const float*)d_in[1];
  const float* norm_b   = (const float*)d_in[2];
  const float* skip     = (const float*)d_in[3];
  const float* m_inw    = (const float*)d_in[4];
  const float* m_convw  = (const float*)d_in[5];
  const float* m_convb  = (const float*)d_in[6];
  const float* m_xpw    = (const float*)d_in[7];
  const float* m_dtw    = (const float*)d_in[8];
  const float* m_dtb    = (const float*)d_in[9];
  const float* m_alog   = (const float*)d_in[10];
  const float* m_d      = (const float*)d_in[11];
  const float* m_outw   = (const float*)d_in[12];
  const float* qdw_w    = (const float*)d_in[13];
  const float* qdw_b    = (const float*)d_in[14];
  const float* qpw_w    = (const float*)d_in[15];
  const float* qpw_b    = (const float*)d_in[16];
  const float* rdw_w    = (const float*)d_in[17];
  const float* rdw_b    = (const float*)d_in[18];
  const float* rpw_w    = (const float*)d_in[19];
  const float* rpw_b    = (const float*)d_in[20];
  const float* fdw_w    = (const float*)d_in[21];
  const float* fdw_b    = (const float*)d_in[22];
  const float* fpw_w    = (const float*)d_in[23];
  const float* fpw_b    = (const float*)d_in[24];
  const float* lc_w     = (const float*)d_in[25];
  const float* lc_b     = (const float*)d_in[26];
  const float* attn_inw = (const float*)d_in[27];
  const float* attn_inb = (const float*)d_in[28];
  const float* attn_outw= (const float*)d_in[29];
  const float* attn_outb= (const float*)d_in[30];
  const float* lgn_w    = (const float*)d_in[31];
  const float* lgn_b    = (const float*)d_in[32];
  const float* fc_w     = (const float*)d_in[33];
  const float* fc_b     = (const float*)d_in[34];
  const float* dwc_w    = (const float*)d_in[35];
  const float* dwc_b    = (const float*)d_in[36];
  const float* proj_w   = (const float*)d_in[37];
  const float* proj_b   = (const float*)d_in[38];
  float* out = (float*)d_out;

  float* ws = (float*)d_ws;
  const size_t F = 1048576;  // B*N*C
  unsigned short* XNB = (unsigned short*)(ws + 1 * F);   // bf16 XN
  unsigned short* UB  = (unsigned short*)(ws + 2 * F);   // bf16 U
  unsigned short* ZB  = (unsigned short*)(ws + 4 * F);   // bf16 Z
  float* DT  = ws + 6 * F;
  float* BM  = ws + 8 * F;
  float* CM  = ws + 8 * F + F / 4;
  float* XMC = ws + 8 * F + F / 2;
  float* SC_APROD = ws + 8 * F + F / 2;
  float* SC_HEND  = ws + 9 * F;
  float* XG  = ws + 2 * F;                               // U dead after scanC
  float* RB  = ws + 4 * F + F / 2;                       // clear of ZB (bf16, 0.5F)
  unsigned short* XM2B = (unsigned short*)(ws + 5 * F + F / 2);
  unsigned short* QKVB = (unsigned short*)(ws + 1 * F);  // XN dead after outproj
  unsigned short* OB   = (unsigned short*)(ws + 4 * F);  // ZB dead after outproj
  unsigned short* XGLB = (unsigned short*)(ws + 6 * F);  // DT dead after outproj
  unsigned short* XOB  = (unsigned short*)(ws + 7 * F);  // bf16 XO
  unsigned short* XIB  = (unsigned short*)(ws + 8 * F);  // bf16 XI (SC_HEND dead)
  unsigned short* XDB  = (unsigned short*)(ws + 0 * F);  // bf16 XD
  (void)ws_size; (void)in_sizes; (void)n_in; (void)out_size;

  k_ln_t2<<<512, 256, 0, stream>>>(x, norm_w, norm_b, XNB);
  k_inproj_conv<<<dim3(64, 16), 256, 0, stream>>>(XNB, m_inw, m_convw, m_convb, UB, ZB);
  k_xdbc_scanA<<<256, 256, 0, stream>>>(UB, m_xpw, m_dtw, m_dtb, m_alog,
                                        DT, BM, CM, SC_APROD, SC_HEND);
  k_scanC<<<512, 256, 0, stream>>>(DT, UB, BM, CM, m_alog, m_d, SC_APROD, SC_HEND);
  k_outproj_mfma<<<dim3(128, 4), 256, 0, stream>>>(DT, ZB, m_outw, XNB, skip, XMC);
  k_gatexg<<<256, 256, 0, stream>>>(XMC, qdw_w, qdw_b, qpw_w, qpw_b, XG);
  k_gemm_cm_dw<256><<<dim3(128, 4), 256, 0, stream>>>(XG, nullptr, rdw_w, rdw_b,
                                                      rpw_w, rpw_b, XG, nullptr, RB, nullptr);
  k_gemm_cm_dw<512><<<dim3(128, 4), 256, 0, stream>>>(x, RB, fdw_w, fdw_b,
                                                      fpw_w, fpw_b, nullptr, x, nullptr, XM2B);
  k_gemm_qkv<<<dim3(64, 12), 256, 0, stream>>>(XM2B, attn_inw, attn_inb, QKVB);
  k_attn_mfma<<<512, 256, 0, stream>>>(QKVB, OB);
  k_gemm_attnout<<<dim3(128, 4), 256, 0, stream>>>(OB, attn_outw, attn_outb, XGLB);
  k_gemm_fc<<<dim3(128, 4), 256, 0, stream>>>(XM2B, XGLB, lc_w, lc_b, fc_w, fc_b, XOB);
  k_lngelu<<<512, 256, 0, stream>>>(XOB, lgn_w, lgn_b, XIB);
  k_lnhw_dwc<<<1024, 256, 0, stream>>>(XIB, dwc_w, dwc_b, XDB);
  k_lnproj<<<dim3(128, 4), 256, 0, stream>>>(XDB, norm_w, norm_b, proj_w, proj_b, out);
}